// Round 4
// baseline (4789.946 us; speedup 1.0000x reference)
//
#include <hip/hip_runtime.h>
#include <math.h>

// ---------------- problem sizes ----------------
#define BATCH   1024
#define NCAND   100000
#define DM      128
#define DB      256
#define NNUM    64
#define CTXS    96
#define ECH     25000        // candidate-encoder M chunk (4 chunks)
#define TROWS   256          // t-net batch rows per chunk (4 chunks)
#define TP      (TROWS*CTXS) // 24576 pairs per t-net chunk
#define RCH     128          // sims row chunk (8 chunks)
#define EMCAP   8192         // emitted-candidate cap per row

// ---------------- workspace offsets (in floats) ----------------
#define WT_IN       0u
#define WT_E1       8192u
#define WT_E2       40960u
#define WT_K        73728u
#define WT_T1       90112u
#define WT_T2       122880u
#define WT_P1       155648u
#define WT_P2       188416u
#define OFF_CANDK   221184u      // 100000*128
#define OFF_CANDN   13021184u    // 100000
#define OFF_KB      13121184u    // 1024*128
#define OFF_XB      13253280u    // 1024*128
#define OFF_X2B     13384352u    // 1024*128
#define OFF_LNB     13515424u    // 1024*128
#define OFF_HB      13646496u    // 1024*256
#define OFF_XPRED   13908640u    // 1024*128
#define OFF_XFIN    14039712u    // 1024*128
#define OFF_KBT     14170784u    // 8*128*128 (kb transposed per chunk)
#define OFF_PROBS   15743648u    // 1024*96
#define OFF_TIDX    15841952u    // 1024*96 (int)
#define OFF_YG      15940256u    // 1024*96
#define OFF_SX      16038560u    // enc X (25000*128) / t-net T2 / sims buffer start
#define OFF_SX2     19238560u    // enc X2
#define OFF_SH      22438560u    // enc H / t-net TH
#define OFF_SLN     28838560u    // enc LN / t-net diff / select-phase emit buffers
#define OFF_EV      28838560u    // 128*8192 emitted values   (select phase only)
#define OFF_EI      29887136u    // 128*8192 emitted idx (int)
#define OFF_GCNT    30935712u    // 128 uint
#define OFF_GTHR    30935840u    // 128 float thresholds

// ---------------- weight transpose prep ----------------
__global__ void __launch_bounds__(256) k_transpose(
    const float* __restrict__ w0, const float* __restrict__ w1,
    const float* __restrict__ w2, const float* __restrict__ w3,
    const float* __restrict__ w4, const float* __restrict__ w5,
    const float* __restrict__ w6, const float* __restrict__ w7,
    float* __restrict__ dst)
{
  const float* src[8] = {w0,w1,w2,w3,w4,w5,w6,w7};
  const int nn[8]  = {128,256,128,128,256,128,256,128};
  const int kkv[8] = { 64,128,256,128,128,256,128,256};
  const int off[8] = {0,8192,40960,73728,90112,122880,155648,188416};
  int stride = gridDim.x*blockDim.x;
  int t0 = blockIdx.x*blockDim.x + threadIdx.x;
#pragma unroll
  for (int m = 0; m < 8; ++m) {
    int total = nn[m]*kkv[m];
    for (int i = t0; i < total; i += stride) {
      int k = i / nn[m];
      int n = i - k*nn[m];
      dst[off[m] + i] = src[m][n*kkv[m] + k];
    }
  }
}

// kb [1024][128] -> kbT [8 chunks][128 k][128 r]
__global__ void __launch_bounds__(256) k_transpose_kb(
    const float* __restrict__ kb, float* __restrict__ kbT)
{
  int i = blockIdx.x*256 + threadIdx.x;   // 131072 total
  int ch = i >> 14, rem = i & 16383;
  int k = rem >> 7, r = rem & 127;
  kbT[i] = kb[(size_t)(ch*128 + r)*128 + k];
}

// ---------------- generic fp32 GEMM ----------------
template<int N, bool RELU, bool RESID, bool NORM>
__global__ void __launch_bounds__(256) k_gemm(
    const float* __restrict__ A, const float* __restrict__ WT,
    const float* __restrict__ bias, const float* __restrict__ resid,
    float* __restrict__ C, float* __restrict__ nrm,
    int M, int K)
{
  constexpr int G = N/64;
  __shared__ __align__(16) float sA[64*33];
  __shared__ __align__(16) float sW[32*N];
  __shared__ float sNorm[64];
  const int tid = threadIdx.x;
  const int r0 = blockIdx.x*64;
  const int tr = tid >> 4, tc = tid & 15;
  float acc[4][G*4];
#pragma unroll
  for (int i = 0; i < 4; ++i)
#pragma unroll
    for (int j = 0; j < G*4; ++j) acc[i][j] = 0.f;

  for (int kc = 0; kc < K; kc += 32) {
    for (int i = tid; i < 64*32; i += 256) {
      int r = i >> 5, kk = i & 31;
      int gr = r0 + r;
      sA[r*33 + kk] = (gr < M) ? A[(size_t)gr*K + kc + kk] : 0.f;
    }
    for (int i = tid; i < 32*N; i += 256) sW[i] = WT[(size_t)kc*N + i];
    __syncthreads();
    for (int kk = 0; kk < 32; ++kk) {
      float a0 = sA[(tr*4+0)*33+kk];
      float a1 = sA[(tr*4+1)*33+kk];
      float a2 = sA[(tr*4+2)*33+kk];
      float a3 = sA[(tr*4+3)*33+kk];
#pragma unroll
      for (int g = 0; g < G; ++g) {
        float4 w = *(const float4*)&sW[kk*N + g*64 + tc*4];
        acc[0][g*4+0] += a0*w.x; acc[0][g*4+1] += a0*w.y; acc[0][g*4+2] += a0*w.z; acc[0][g*4+3] += a0*w.w;
        acc[1][g*4+0] += a1*w.x; acc[1][g*4+1] += a1*w.y; acc[1][g*4+2] += a1*w.z; acc[1][g*4+3] += a1*w.w;
        acc[2][g*4+0] += a2*w.x; acc[2][g*4+1] += a2*w.y; acc[2][g*4+2] += a2*w.z; acc[2][g*4+3] += a2*w.w;
        acc[3][g*4+0] += a3*w.x; acc[3][g*4+1] += a3*w.y; acc[3][g*4+2] += a3*w.z; acc[3][g*4+3] += a3*w.w;
      }
    }
    __syncthreads();
  }

  float rowsq[4] = {0.f,0.f,0.f,0.f};
#pragma unroll
  for (int i = 0; i < 4; ++i) {
    int r = r0 + tr*4 + i;
    if (r < M) {
#pragma unroll
      for (int g = 0; g < G; ++g) {
        int col = g*64 + tc*4;
        float v0 = acc[i][g*4+0], v1 = acc[i][g*4+1], v2 = acc[i][g*4+2], v3 = acc[i][g*4+3];
        if (bias) { v0 += bias[col+0]; v1 += bias[col+1]; v2 += bias[col+2]; v3 += bias[col+3]; }
        if constexpr (RELU) { v0 = fmaxf(v0,0.f); v1 = fmaxf(v1,0.f); v2 = fmaxf(v2,0.f); v3 = fmaxf(v3,0.f); }
        if constexpr (RESID) {
          float4 rv = *(const float4*)&resid[(size_t)r*N + col];
          v0 += rv.x; v1 += rv.y; v2 += rv.z; v3 += rv.w;
        }
        float4 o4; o4.x = v0; o4.y = v1; o4.z = v2; o4.w = v3;
        *(float4*)&C[(size_t)r*N + col] = o4;
        if constexpr (NORM) rowsq[i] += v0*v0 + v1*v1 + v2*v2 + v3*v3;
      }
    }
  }
  if constexpr (NORM) {
    if (tid < 64) sNorm[tid] = 0.f;
    __syncthreads();
#pragma unroll
    for (int i = 0; i < 4; ++i) atomicAdd(&sNorm[tr*4+i], rowsq[i]);
    __syncthreads();
    if (tid < 64 && r0 + tid < M) nrm[r0 + tid] = sNorm[tid];
  }
}

// ---------------- LayerNorm (wave-per-row) ----------------
__global__ void __launch_bounds__(256) k_ln(
    const float* __restrict__ x, const float* __restrict__ g, const float* __restrict__ b,
    float* __restrict__ o, int M)
{
  const int lane = threadIdx.x & 63, w = threadIdx.x >> 6;
  int rb = blockIdx.x*32 + w*8;
  for (int it = 0; it < 8; ++it) {
    int r = rb + it;
    if (r >= M) return;
    float a = x[(size_t)r*128 + lane];
    float c = x[(size_t)r*128 + 64 + lane];
    float s = a + c;
    for (int o2 = 32; o2; o2 >>= 1) s += __shfl_xor(s, o2);
    float mu = s * (1.f/128.f);
    float da = a - mu, dc = c - mu;
    float v = da*da + dc*dc;
    for (int o2 = 32; o2; o2 >>= 1) v += __shfl_xor(v, o2);
    float rs = rsqrtf(v*(1.f/128.f) + 1e-5f);
    o[(size_t)r*128 + lane]      = da*rs*g[lane]    + b[lane];
    o[(size_t)r*128 + 64 + lane] = dc*rs*g[lane+64] + b[lane+64];
  }
}

// ---------------- sims GEMM v3: 64 cands x 128 batch-rows per block ----------------
// sims[r][c] = 2*dot(kb[r], candk[c]) - candn[c]
// A = candk rows (M-dim = candidates), B = kbT [k][r]. acc[4 cands][8 rows].
__global__ void __launch_bounds__(256) k_sims_gemm(
    const float* __restrict__ kbT,    // [128][128] (k-major) for this chunk
    const float* __restrict__ candk,  // [NCAND][128]
    const float* __restrict__ candn,  // [NCAND]
    float* __restrict__ sims)         // [128][NCAND]
{
  __shared__ __align__(16) float sA[64*33];   // [cand][k] padded
  __shared__ __align__(16) float sB[32*128];  // [k][batchrow]
  const int tid = threadIdx.x;
  const int c0 = blockIdx.x * 64;
  const int tr = tid & 15;    // cand quad: cands c0 + tr*4 .. +3
  const int tc = tid >> 4;    // batchrow group: rows tc*4..+3 and 64+tc*4..+3

  float acc[4][8];
#pragma unroll
  for (int i = 0; i < 4; ++i)
#pragma unroll
    for (int j = 0; j < 8; ++j) acc[i][j] = 0.f;

  for (int kc = 0; kc < 128; kc += 32) {
    // stage A: 64 cand rows x 32 k (float4 loads)
    for (int i = tid; i < 512; i += 256) {
      int r = i >> 3, k4 = i & 7;
      int gc = c0 + r;
      float4 a;
      if (gc < NCAND) a = *(const float4*)&candk[(size_t)gc*128 + kc + k4*4];
      else { a.x = a.y = a.z = a.w = 0.f; }
      sA[r*33 + k4*4 + 0] = a.x;
      sA[r*33 + k4*4 + 1] = a.y;
      sA[r*33 + k4*4 + 2] = a.z;
      sA[r*33 + k4*4 + 3] = a.w;
    }
    // stage B: kbT slice [32][128], fully coalesced
    for (int i = tid; i < 1024; i += 256)
      *(float4*)&sB[i*4] = *(const float4*)&kbT[kc*128 + i*4];
    __syncthreads();
    for (int kk = 0; kk < 32; ++kk) {
      float a0 = sA[(tr*4+0)*33+kk];
      float a1 = sA[(tr*4+1)*33+kk];
      float a2 = sA[(tr*4+2)*33+kk];
      float a3 = sA[(tr*4+3)*33+kk];
      float4 b0 = *(const float4*)&sB[kk*128 + tc*4];
      float4 b1 = *(const float4*)&sB[kk*128 + 64 + tc*4];
      acc[0][0]+=a0*b0.x; acc[0][1]+=a0*b0.y; acc[0][2]+=a0*b0.z; acc[0][3]+=a0*b0.w;
      acc[0][4]+=a0*b1.x; acc[0][5]+=a0*b1.y; acc[0][6]+=a0*b1.z; acc[0][7]+=a0*b1.w;
      acc[1][0]+=a1*b0.x; acc[1][1]+=a1*b0.y; acc[1][2]+=a1*b0.z; acc[1][3]+=a1*b0.w;
      acc[1][4]+=a1*b1.x; acc[1][5]+=a1*b1.y; acc[1][6]+=a1*b1.z; acc[1][7]+=a1*b1.w;
      acc[2][0]+=a2*b0.x; acc[2][1]+=a2*b0.y; acc[2][2]+=a2*b0.z; acc[2][3]+=a2*b0.w;
      acc[2][4]+=a2*b1.x; acc[2][5]+=a2*b1.y; acc[2][6]+=a2*b1.z; acc[2][7]+=a2*b1.w;
      acc[3][0]+=a3*b0.x; acc[3][1]+=a3*b0.y; acc[3][2]+=a3*b0.z; acc[3][3]+=a3*b0.w;
      acc[3][4]+=a3*b1.x; acc[3][5]+=a3*b1.y; acc[3][6]+=a3*b1.z; acc[3][7]+=a3*b1.w;
    }
    __syncthreads();
  }

  const bool valid = (c0 + tr*4) < NCAND;   // NCAND%4==0 -> quad all-or-nothing
  float4 cn;
  cn.x = cn.y = cn.z = cn.w = 0.f;
  if (valid) cn = *(const float4*)&candn[c0 + tr*4];
#pragma unroll
  for (int j = 0; j < 8; ++j) {
    int b = (j >> 2)*64 + tc*4 + (j & 3);
    if (valid) {
      float4 o;
      o.x = 2.f*acc[0][j] - cn.x;
      o.y = 2.f*acc[1][j] - cn.y;
      o.z = 2.f*acc[2][j] - cn.z;
      o.w = 2.f*acc[3][j] - cn.w;
      *(float4*)&sims[(size_t)b*NCAND + c0 + tr*4] = o;
    }
  }
}

// ---------------- select stage 1: per-row threshold from 1562-sample ----------------
// threshold = 24th largest of a stride-64 sample => E[#above] ~ 1536 (of 100k).
__global__ void __launch_bounds__(256) k_sample(
    const float* __restrict__ sims, float* __restrict__ gthr, unsigned* __restrict__ gcnt)
{
  __shared__ float sv[1562];
  __shared__ float wv[4]; __shared__ int wp[4];
  const int tid = threadIdx.x, row = blockIdx.x;
  const float* S = sims + (size_t)row*NCAND;
  for (int i = tid; i < 1562; i += 256) sv[i] = S[i*64];
  __syncthreads();
  float thr = 0.f;
  for (int rd = 0; rd < 24; ++rd) {
    float best = -__builtin_inff(); int bp = 0;
    for (int t = tid; t < 1562; t += 256) {
      float v = sv[t];
      if (v > best) { best = v; bp = t; }
    }
    for (int o = 32; o; o >>= 1) {
      float ob = __shfl_xor(best, o); int obp = __shfl_xor(bp, o);
      if (ob > best) { best = ob; bp = obp; }
    }
    if ((tid & 63) == 0) { wv[tid>>6] = best; wp[tid>>6] = bp; }
    __syncthreads();
    if (tid == 0) {
      float bb = wv[0]; int pp = wp[0];
      for (int w2 = 1; w2 < 4; ++w2) if (wv[w2] > bb) { bb = wv[w2]; pp = wp[w2]; }
      sv[pp] = -__builtin_inff();
      wv[0] = bb;                       // broadcast round winner
    }
    __syncthreads();
    if (rd == 23) thr = wv[0];
    __syncthreads();
  }
  if (tid == 0) { gthr[row] = thr; gcnt[row] = 0u; }
}

// ---------------- select stage 2: emit all v >= thr ----------------
__global__ void __launch_bounds__(256) k_emit(
    const float* __restrict__ sims, const float* __restrict__ gthr,
    unsigned* __restrict__ gcnt, float* __restrict__ ev, int* __restrict__ ei)
{
  const int tid = threadIdx.x;
  const int row = blockIdx.y;
  const int base = blockIdx.x * 12500;       // 8 blocks/row
  const float thr = gthr[row];
  const float* S = sims + (size_t)row*NCAND + base;
  float* EV = ev + (size_t)row*EMCAP;
  int*   EI = ei + (size_t)row*EMCAP;
  for (int i = tid; i < 3125; i += 256) {
    float4 v = *(const float4*)&S[i*4];
    if (v.x >= thr) { unsigned p = atomicAdd(&gcnt[row], 1u); if (p < EMCAP) { EV[p] = v.x; EI[p] = base + i*4 + 0; } }
    if (v.y >= thr) { unsigned p = atomicAdd(&gcnt[row], 1u); if (p < EMCAP) { EV[p] = v.y; EI[p] = base + i*4 + 1; } }
    if (v.z >= thr) { unsigned p = atomicAdd(&gcnt[row], 1u); if (p < EMCAP) { EV[p] = v.z; EI[p] = base + i*4 + 2; } }
    if (v.w >= thr) { unsigned p = atomicAdd(&gcnt[row], 1u); if (p < EMCAP) { EV[p] = v.w; EI[p] = base + i*4 + 3; } }
  }
}

// ---------------- select stage 3: exact top-96 of emitted + softmax + gathers ----------------
__global__ void __launch_bounds__(256) k_final(
    const float* __restrict__ ev, const int* __restrict__ ei,
    const unsigned* __restrict__ gcnt, const float* __restrict__ cand_y,
    float* __restrict__ probs, int* __restrict__ tidxg, float* __restrict__ ygath,
    int r0)
{
  __shared__ float sv[EMCAP];
  __shared__ unsigned hist[1024];
  __shared__ float tv[512]; __shared__ int ti[512];
  __shared__ float selv[96]; __shared__ int seli[96];
  __shared__ unsigned cnts[2];
  __shared__ float wv[4]; __shared__ int wp[4];
  __shared__ float wmin[4], wmax[4];
  __shared__ float s_lo, s_inv;
  __shared__ int sb_s, above_s;
  __shared__ float smax_s, ssum_s;

  const int tid = threadIdx.x, row = blockIdx.x;
  const int n = (int)min(gcnt[row], (unsigned)EMCAP);
  const float* EV = ev + (size_t)row*EMCAP;
  const int*   EI = ei + (size_t)row*EMCAP;

  if (tid < 96) { selv[tid] = -1e30f; seli[tid] = 0; }
  for (int i = tid; i < 1024; i += 256) hist[i] = 0;
  if (tid < 2) cnts[tid] = 0;

  float lmax = -__builtin_inff(), lmin = __builtin_inff();
  for (int i = tid; i < n; i += 256) {
    float v = EV[i]; sv[i] = v;
    lmax = fmaxf(lmax, v); lmin = fminf(lmin, v);
  }
  for (int o = 32; o; o >>= 1) {
    lmax = fmaxf(lmax, __shfl_xor(lmax, o));
    lmin = fminf(lmin, __shfl_xor(lmin, o));
  }
  if ((tid & 63) == 0) { wmax[tid>>6] = lmax; wmin[tid>>6] = lmin; }
  __syncthreads();
  if (tid == 0) {
    float hi = wmax[0], lo = wmin[0];
    for (int w2 = 1; w2 < 4; ++w2) { hi = fmaxf(hi, wmax[w2]); lo = fminf(lo, wmin[w2]); }
    float rng = hi - lo;
    s_lo = lo; s_inv = (rng > 0.f) ? (1024.f/rng) : 0.f;
  }
  __syncthreads();
  const float lo = s_lo, inv = s_inv;

  for (int i = tid; i < n; i += 256) {
    int b = min(max((int)((sv[i]-lo)*inv), 0), 1023);
    atomicAdd(&hist[b], 1u);
  }
  __syncthreads();
  if (tid == 0) {
    unsigned cum = 0; int b = 1023;
    for (; b >= 1; --b) { if (cum + hist[b] >= 96u) break; cum += hist[b]; }
    sb_s = b; above_s = (int)cum;
  }
  __syncthreads();
  const int sb = sb_s, above = above_s;

  for (int i = tid; i < n; i += 256) {
    float v = sv[i];
    int b = min(max((int)((v-lo)*inv), 0), 1023);
    if (b > sb) {
      unsigned p = atomicAdd(&cnts[0], 1u);
      if (p < 96u) { selv[p] = v; seli[p] = EI[i]; }
    } else if (b == sb) {
      unsigned p = atomicAdd(&cnts[1], 1u);
      if (p < 512u) { tv[p] = v; ti[p] = EI[i]; }
    }
  }
  __syncthreads();
  const int need = 96 - above;
  const int tcnt = (int)min(cnts[1], 512u);
  for (int rd = 0; rd < need; ++rd) {
    float best = -__builtin_inff(); int bp = -1;
    for (int t = tid; t < tcnt; t += 256) {
      float v = tv[t];
      if (v > best) { best = v; bp = t; }
    }
    for (int o = 32; o; o >>= 1) {
      float ob = __shfl_xor(best, o); int obp = __shfl_xor(bp, o);
      if (ob > best) { best = ob; bp = obp; }
    }
    if ((tid & 63) == 0) { wv[tid>>6] = best; wp[tid>>6] = bp; }
    __syncthreads();
    if (tid == 0) {
      float bb = wv[0]; int pp = wp[0];
      for (int w2 = 1; w2 < 4; ++w2) if (wv[w2] > bb) { bb = wv[w2]; pp = wp[w2]; }
      if (pp >= 0) { selv[above + rd] = bb; seli[above + rd] = ti[pp]; tv[pp] = -__builtin_inff(); }
    }
    __syncthreads();
  }

  if (tid == 0) {
    float m = selv[0];
    for (int i = 1; i < 96; ++i) m = fmaxf(m, selv[i]);
    smax_s = m;
  }
  __syncthreads();
  if (tid < 96) selv[tid] = expf(selv[tid] - smax_s);
  __syncthreads();
  if (tid == 0) {
    float s = 0.f;
    for (int i = 0; i < 96; ++i) s += selv[i];
    ssum_s = s;
  }
  __syncthreads();
  if (tid < 96) {
    int gr = r0 + row;
    int gi = seli[tid];
    probs[(size_t)gr*96 + tid] = selv[tid]/ssum_s;
    tidxg[(size_t)gr*96 + tid] = gi;
    ygath[(size_t)gr*96 + tid] = cand_y[gi];
  }
}

// ---------------- t-net gather: diff = k_b - cand_k[idx] ----------------
__global__ void __launch_bounds__(256) k_gather_diff(
    const float* __restrict__ kb, const float* __restrict__ candk,
    const int* __restrict__ tidxg, float* __restrict__ diff, int p0)
{
  int f = blockIdx.x*256 + threadIdx.x;
  int pl = f >> 7, d = f & 127;
  int gp = p0 + pl;
  int bb = gp / 96;
  int idx = tidxg[gp];
  diff[f] = kb[(size_t)bb*128 + d] - candk[(size_t)idx*128 + d];
}

// ---------------- context accumulation + residual add ----------------
__global__ void __launch_bounds__(128) k_ctx(
    const float* __restrict__ probs, const float* __restrict__ ygath,
    const float* __restrict__ t2, const float* __restrict__ x2b,
    const float* __restrict__ w_le, const float* __restrict__ b_le,
    float* __restrict__ xfinal, int b0)
{
  int bb = b0 + blockIdx.x;
  int d = threadIdx.x;
  float wle = w_le[d], ble = b_le[d];
  float acc = 0.f;
  int base = (bb - b0)*96;
  for (int c = 0; c < 96; ++c) {
    float p = probs[(size_t)bb*96 + c];
    float y = ygath[(size_t)bb*96 + c];
    acc += p*(y*wle + ble + t2[(size_t)(base + c)*128 + d]);
  }
  xfinal[(size_t)bb*128 + d] = x2b[(size_t)bb*128 + d] + acc;
}

// ---------------- head ----------------
__global__ void __launch_bounds__(256) k_head(
    const float* __restrict__ x, const float* __restrict__ g, const float* __restrict__ b,
    const float* __restrict__ Wh, const float* __restrict__ bh,
    float* __restrict__ out, int M)
{
  const int lane = threadIdx.x & 63, w = threadIdx.x >> 6;
  int rb = blockIdx.x*32 + w*8;
  for (int it = 0; it < 8; ++it) {
    int r = rb + it;
    if (r >= M) return;
    float a = x[(size_t)r*128 + lane];
    float c = x[(size_t)r*128 + 64 + lane];
    float s = a + c;
    for (int o = 32; o; o >>= 1) s += __shfl_xor(s, o);
    float mu = s*(1.f/128.f);
    float da = a - mu, dc = c - mu;
    float v = da*da + dc*dc;
    for (int o = 32; o; o >>= 1) v += __shfl_xor(v, o);
    float rs = rsqrtf(v*(1.f/128.f) + 1e-5f);
    float l0 = fmaxf(da*rs*g[lane]    + b[lane],    0.f);
    float l1 = fmaxf(dc*rs*g[lane+64] + b[lane+64], 0.f);
    float p0 = l0*Wh[lane]     + l1*Wh[64+lane];
    float p1 = l0*Wh[128+lane] + l1*Wh[192+lane];
    for (int o = 32; o; o >>= 1) { p0 += __shfl_xor(p0, o); p1 += __shfl_xor(p1, o); }
    if (lane == 0) { out[r*2 + 0] = p0 + bh[0]; out[r*2 + 1] = p1 + bh[1]; }
  }
}

// ---------------- launcher ----------------
extern "C" void kernel_launch(void* const* d_in, const int* in_sizes, int n_in,
                              void* d_out, int out_size, void* d_ws, size_t ws_size,
                              hipStream_t stream) {
  const float* x_num   = (const float*)d_in[0];
  const float* cand_x  = (const float*)d_in[1];
  const float* cand_y  = (const float*)d_in[2];
  const float* W_in    = (const float*)d_in[3];
  const float* b_in    = (const float*)d_in[4];
  const float* enc_W1  = (const float*)d_in[5];
  const float* enc_b1  = (const float*)d_in[6];
  const float* enc_W2  = (const float*)d_in[7];
  const float* enc_b2  = (const float*)d_in[8];
  const float* mix_g   = (const float*)d_in[9];
  const float* mix_b   = (const float*)d_in[10];
  const float* W_k     = (const float*)d_in[11];
  const float* b_k     = (const float*)d_in[12];
  const float* w_le    = (const float*)d_in[13];
  const float* b_le    = (const float*)d_in[14];
  const float* W_t1    = (const float*)d_in[15];
  const float* b_t1    = (const float*)d_in[16];
  const float* W_t2    = (const float*)d_in[17];
  const float* pred_g  = (const float*)d_in[18];
  const float* pred_b  = (const float*)d_in[19];
  const float* pred_W1 = (const float*)d_in[20];
  const float* pred_b1 = (const float*)d_in[21];
  const float* pred_W2 = (const float*)d_in[22];
  const float* pred_b2 = (const float*)d_in[23];
  const float* head_g  = (const float*)d_in[24];
  const float* head_b  = (const float*)d_in[25];
  const float* W_head  = (const float*)d_in[26];
  const float* b_head  = (const float*)d_in[27];

  float* ws  = (float*)d_ws;
  float* out = (float*)d_out;

  float*    wt     = ws;
  float*    candk  = ws + OFF_CANDK;
  float*    candn  = ws + OFF_CANDN;
  float*    kb     = ws + OFF_KB;
  float*    xb     = ws + OFF_XB;
  float*    x2b    = ws + OFF_X2B;
  float*    lnb    = ws + OFF_LNB;
  float*    hb     = ws + OFF_HB;
  float*    xpred  = ws + OFF_XPRED;
  float*    xfin   = ws + OFF_XFIN;
  float*    kbT    = ws + OFF_KBT;
  float*    probs  = ws + OFF_PROBS;
  int*      tidxg  = (int*)(ws + OFF_TIDX);
  float*    ygath  = ws + OFF_YG;
  float*    sx     = ws + OFF_SX;
  float*    sx2    = ws + OFF_SX2;
  float*    sh     = ws + OFF_SH;
  float*    sln    = ws + OFF_SLN;
  float*    simsbuf = ws + OFF_SX;     // 128*100000 floats (overlaps enc scratch)
  float*    ev     = ws + OFF_EV;      // select-phase only (overlaps sln region)
  int*      ei     = (int*)(ws + OFF_EI);
  unsigned* gcnt   = (unsigned*)(ws + OFF_GCNT);
  float*    gthr   = ws + OFF_GTHR;

  // 1) weight transposes
  k_transpose<<<256, 256, 0, stream>>>(W_in, enc_W1, enc_W2, W_k, W_t1, W_t2, pred_W1, pred_W2, wt);

  // 2) batch encoder
  k_gemm<128,false,false,false><<<16, 256, 0, stream>>>(x_num, wt+WT_IN, b_in,   nullptr, xb,  nullptr, BATCH, 64);
  k_gemm<256,true ,false,false><<<16, 256, 0, stream>>>(xb,    wt+WT_E1, enc_b1, nullptr, hb,  nullptr, BATCH, 128);
  k_gemm<128,false,true ,false><<<16, 256, 0, stream>>>(hb,    wt+WT_E2, enc_b2, xb,      x2b, nullptr, BATCH, 256);
  k_ln<<<(BATCH+31)/32, 256, 0, stream>>>(x2b, mix_g, mix_b, lnb, BATCH);
  k_gemm<128,false,false,false><<<16, 256, 0, stream>>>(lnb,   wt+WT_K,  b_k,    nullptr, kb,  nullptr, BATCH, 128);
  k_transpose_kb<<<512, 256, 0, stream>>>(kb, kbT);

  // 3) candidate encoder, 4 chunks of 25000
  for (int ch = 0; ch < 4; ++ch) {
    const float* a0 = cand_x + (size_t)ch*ECH*64;
    float* ck = candk + (size_t)ch*ECH*128;
    float* cn = candn + (size_t)ch*ECH;
    int grid = (ECH + 63)/64;
    k_gemm<128,false,false,false><<<grid, 256, 0, stream>>>(a0,  wt+WT_IN, b_in,   nullptr, sx,  nullptr, ECH, 64);
    k_gemm<256,true ,false,false><<<grid, 256, 0, stream>>>(sx,  wt+WT_E1, enc_b1, nullptr, sh,  nullptr, ECH, 128);
    k_gemm<128,false,true ,false><<<grid, 256, 0, stream>>>(sh,  wt+WT_E2, enc_b2, sx,      sx2, nullptr, ECH, 256);
    k_ln<<<(ECH+31)/32, 256, 0, stream>>>(sx2, mix_g, mix_b, sln, ECH);
    k_gemm<128,false,false,true ><<<grid, 256, 0, stream>>>(sln, wt+WT_K,  b_k,    nullptr, ck,  cn,      ECH, 128);
  }

  // 4) sims + exact top-96, 8 row chunks of 128
  for (int ch = 0; ch < 8; ++ch) {
    k_sims_gemm<<<(NCAND+63)/64, 256, 0, stream>>>(
        kbT + (size_t)ch*128*128, candk, candn, simsbuf);
    k_sample<<<RCH, 256, 0, stream>>>(simsbuf, gthr, gcnt);
    k_emit<<<dim3(8, RCH), 256, 0, stream>>>(simsbuf, gthr, gcnt, ev, ei);
    k_final<<<RCH, 256, 0, stream>>>(ev, ei, gcnt, cand_y, probs, tidxg, ygath, ch*RCH);
  }

  // 5) t-net, 4 chunks of 256 batch rows
  for (int tc = 0; tc < 4; ++tc) {
    int p0 = tc*TP, b0 = tc*TROWS;
    k_gather_diff<<<(TP*128)/256, 256, 0, stream>>>(kb, candk, tidxg, sln, p0);
    k_gemm<256,true ,false,false><<<TP/64, 256, 0, stream>>>(sln, wt+WT_T1, b_t1, nullptr, sh, nullptr, TP, 128);
    k_gemm<128,false,false,false><<<TP/64, 256, 0, stream>>>(sh,  wt+WT_T2, nullptr, nullptr, sx, nullptr, TP, 256);
    k_ctx<<<TROWS, 128, 0, stream>>>(probs, ygath, sx, x2b, w_le, b_le, xfin, b0);
  }

  // 6) predictor block + head
  k_ln<<<(BATCH+31)/32, 256, 0, stream>>>(xfin, pred_g, pred_b, lnb, BATCH);
  k_gemm<256,true ,false,false><<<16, 256, 0, stream>>>(lnb, wt+WT_P1, pred_b1, nullptr, hb,    nullptr, BATCH, 128);
  k_gemm<128,false,true ,false><<<16, 256, 0, stream>>>(hb,  wt+WT_P2, pred_b2, xfin,    xpred, nullptr, BATCH, 256);
  k_head<<<(BATCH+31)/32, 256, 0, stream>>>(xpred, head_g, head_b, W_head, b_head, out, BATCH);
}

// Round 5
// 2333.174 us; speedup vs baseline: 2.0530x; 2.0530x over previous
//
#include <hip/hip_runtime.h>
#include <math.h>

// ---------------- problem sizes ----------------
#define BATCH   1024
#define NCAND   100000
#define DM      128
#define DB      256
#define NNUM    64
#define CTXS    96
#define ECH     25000        // candidate-encoder M chunk (4 chunks)
#define TROWS   256          // t-net batch rows per chunk (4 chunks)
#define TP      (TROWS*CTXS) // 24576 pairs per t-net chunk
#define RCH     128          // sims row chunk (8 chunks)
#define EMCAP   8192         // emitted-candidate cap per row
#define BCAP    1024         // per-block emit cap (E~192, 58 sigma)

// ---------------- workspace offsets (in floats) ----------------
#define WT_IN       0u
#define WT_E1       8192u
#define WT_E2       40960u
#define WT_K        73728u
#define WT_T1       90112u
#define WT_T2       122880u
#define WT_P1       155648u
#define WT_P2       188416u
#define OFF_CANDK   221184u      // 100000*128
#define OFF_CANDN   13021184u    // 100000
#define OFF_KB      13121184u    // 1024*128
#define OFF_XB      13253280u    // 1024*128
#define OFF_X2B     13384352u    // 1024*128
#define OFF_LNB     13515424u    // 1024*128
#define OFF_HB      13646496u    // 1024*256
#define OFF_XPRED   13908640u    // 1024*128
#define OFF_XFIN    14039712u    // 1024*128
#define OFF_KBT     14170784u    // 8*128*128 (kb transposed per chunk)
#define OFF_PROBS   15743648u    // 1024*96
#define OFF_TIDX    15841952u    // 1024*96 (int)
#define OFF_YG      15940256u    // 1024*96
#define OFF_SX      16038560u    // enc X (25000*128) / t-net T2 / sims buffer start
#define OFF_SX2     19238560u    // enc X2
#define OFF_SH      22438560u    // enc H / t-net TH
#define OFF_SLN     28838560u    // enc LN / t-net diff / select-phase emit buffers
#define OFF_EV      28838560u    // 128*8192 emitted values   (select phase only)
#define OFF_EI      29887136u    // 128*8192 emitted idx (int)
#define OFF_GCNT    30935712u    // 128 uint
#define OFF_GTHR    30935840u    // 128 float thresholds

// ---------------- weight transpose prep ----------------
__global__ void __launch_bounds__(256) k_transpose(
    const float* __restrict__ w0, const float* __restrict__ w1,
    const float* __restrict__ w2, const float* __restrict__ w3,
    const float* __restrict__ w4, const float* __restrict__ w5,
    const float* __restrict__ w6, const float* __restrict__ w7,
    float* __restrict__ dst)
{
  const float* src[8] = {w0,w1,w2,w3,w4,w5,w6,w7};
  const int nn[8]  = {128,256,128,128,256,128,256,128};
  const int kkv[8] = { 64,128,256,128,128,256,128,256};
  const int off[8] = {0,8192,40960,73728,90112,122880,155648,188416};
  int stride = gridDim.x*blockDim.x;
  int t0 = blockIdx.x*blockDim.x + threadIdx.x;
#pragma unroll
  for (int m = 0; m < 8; ++m) {
    int total = nn[m]*kkv[m];
    for (int i = t0; i < total; i += stride) {
      int k = i / nn[m];
      int n = i - k*nn[m];
      dst[off[m] + i] = src[m][n*kkv[m] + k];
    }
  }
}

// kb [1024][128] -> kbT [8 chunks][128 k][128 r]
__global__ void __launch_bounds__(256) k_transpose_kb(
    const float* __restrict__ kb, float* __restrict__ kbT)
{
  int i = blockIdx.x*256 + threadIdx.x;   // 131072 total
  int ch = i >> 14, rem = i & 16383;
  int k = rem >> 7, r = rem & 127;
  kbT[i] = kb[(size_t)(ch*128 + r)*128 + k];
}

// ---------------- generic fp32 GEMM ----------------
template<int N, bool RELU, bool RESID, bool NORM>
__global__ void __launch_bounds__(256) k_gemm(
    const float* __restrict__ A, const float* __restrict__ WT,
    const float* __restrict__ bias, const float* __restrict__ resid,
    float* __restrict__ C, float* __restrict__ nrm,
    int M, int K)
{
  constexpr int G = N/64;
  __shared__ __align__(16) float sA[64*33];
  __shared__ __align__(16) float sW[32*N];
  __shared__ float sNorm[64];
  const int tid = threadIdx.x;
  const int r0 = blockIdx.x*64;
  const int tr = tid >> 4, tc = tid & 15;
  float acc[4][G*4];
#pragma unroll
  for (int i = 0; i < 4; ++i)
#pragma unroll
    for (int j = 0; j < G*4; ++j) acc[i][j] = 0.f;

  for (int kc = 0; kc < K; kc += 32) {
    for (int i = tid; i < 64*32; i += 256) {
      int r = i >> 5, kk = i & 31;
      int gr = r0 + r;
      sA[r*33 + kk] = (gr < M) ? A[(size_t)gr*K + kc + kk] : 0.f;
    }
    for (int i = tid; i < 32*N; i += 256) sW[i] = WT[(size_t)kc*N + i];
    __syncthreads();
    for (int kk = 0; kk < 32; ++kk) {
      float a0 = sA[(tr*4+0)*33+kk];
      float a1 = sA[(tr*4+1)*33+kk];
      float a2 = sA[(tr*4+2)*33+kk];
      float a3 = sA[(tr*4+3)*33+kk];
#pragma unroll
      for (int g = 0; g < G; ++g) {
        float4 w = *(const float4*)&sW[kk*N + g*64 + tc*4];
        acc[0][g*4+0] += a0*w.x; acc[0][g*4+1] += a0*w.y; acc[0][g*4+2] += a0*w.z; acc[0][g*4+3] += a0*w.w;
        acc[1][g*4+0] += a1*w.x; acc[1][g*4+1] += a1*w.y; acc[1][g*4+2] += a1*w.z; acc[1][g*4+3] += a1*w.w;
        acc[2][g*4+0] += a2*w.x; acc[2][g*4+1] += a2*w.y; acc[2][g*4+2] += a2*w.z; acc[2][g*4+3] += a2*w.w;
        acc[3][g*4+0] += a3*w.x; acc[3][g*4+1] += a3*w.y; acc[3][g*4+2] += a3*w.z; acc[3][g*4+3] += a3*w.w;
      }
    }
    __syncthreads();
  }

  float rowsq[4] = {0.f,0.f,0.f,0.f};
#pragma unroll
  for (int i = 0; i < 4; ++i) {
    int r = r0 + tr*4 + i;
    if (r < M) {
#pragma unroll
      for (int g = 0; g < G; ++g) {
        int col = g*64 + tc*4;
        float v0 = acc[i][g*4+0], v1 = acc[i][g*4+1], v2 = acc[i][g*4+2], v3 = acc[i][g*4+3];
        if (bias) { v0 += bias[col+0]; v1 += bias[col+1]; v2 += bias[col+2]; v3 += bias[col+3]; }
        if constexpr (RELU) { v0 = fmaxf(v0,0.f); v1 = fmaxf(v1,0.f); v2 = fmaxf(v2,0.f); v3 = fmaxf(v3,0.f); }
        if constexpr (RESID) {
          float4 rv = *(const float4*)&resid[(size_t)r*N + col];
          v0 += rv.x; v1 += rv.y; v2 += rv.z; v3 += rv.w;
        }
        float4 o4; o4.x = v0; o4.y = v1; o4.z = v2; o4.w = v3;
        *(float4*)&C[(size_t)r*N + col] = o4;
        if constexpr (NORM) rowsq[i] += v0*v0 + v1*v1 + v2*v2 + v3*v3;
      }
    }
  }
  if constexpr (NORM) {
    if (tid < 64) sNorm[tid] = 0.f;
    __syncthreads();
#pragma unroll
    for (int i = 0; i < 4; ++i) atomicAdd(&sNorm[tr*4+i], rowsq[i]);
    __syncthreads();
    if (tid < 64 && r0 + tid < M) nrm[r0 + tid] = sNorm[tid];
  }
}

// ---------------- LayerNorm (wave-per-row) ----------------
__global__ void __launch_bounds__(256) k_ln(
    const float* __restrict__ x, const float* __restrict__ g, const float* __restrict__ b,
    float* __restrict__ o, int M)
{
  const int lane = threadIdx.x & 63, w = threadIdx.x >> 6;
  int rb = blockIdx.x*32 + w*8;
  for (int it = 0; it < 8; ++it) {
    int r = rb + it;
    if (r >= M) return;
    float a = x[(size_t)r*128 + lane];
    float c = x[(size_t)r*128 + 64 + lane];
    float s = a + c;
    for (int o2 = 32; o2; o2 >>= 1) s += __shfl_xor(s, o2);
    float mu = s * (1.f/128.f);
    float da = a - mu, dc = c - mu;
    float v = da*da + dc*dc;
    for (int o2 = 32; o2; o2 >>= 1) v += __shfl_xor(v, o2);
    float rs = rsqrtf(v*(1.f/128.f) + 1e-5f);
    o[(size_t)r*128 + lane]      = da*rs*g[lane]    + b[lane];
    o[(size_t)r*128 + 64 + lane] = dc*rs*g[lane+64] + b[lane+64];
  }
}

// ---------------- sims GEMM v3: 64 cands x 128 batch-rows per block ----------------
__global__ void __launch_bounds__(256) k_sims_gemm(
    const float* __restrict__ kbT,    // [128][128] (k-major) for this chunk
    const float* __restrict__ candk,  // [NCAND][128]
    const float* __restrict__ candn,  // [NCAND]
    float* __restrict__ sims)         // [128][NCAND]
{
  __shared__ __align__(16) float sA[64*33];   // [cand][k] padded
  __shared__ __align__(16) float sB[32*128];  // [k][batchrow]
  const int tid = threadIdx.x;
  const int c0 = blockIdx.x * 64;
  const int tr = tid & 15;    // cand quad
  const int tc = tid >> 4;    // batchrow group

  float acc[4][8];
#pragma unroll
  for (int i = 0; i < 4; ++i)
#pragma unroll
    for (int j = 0; j < 8; ++j) acc[i][j] = 0.f;

  for (int kc = 0; kc < 128; kc += 32) {
    for (int i = tid; i < 512; i += 256) {
      int r = i >> 3, k4 = i & 7;
      int gc = c0 + r;
      float4 a;
      if (gc < NCAND) a = *(const float4*)&candk[(size_t)gc*128 + kc + k4*4];
      else { a.x = a.y = a.z = a.w = 0.f; }
      sA[r*33 + k4*4 + 0] = a.x;
      sA[r*33 + k4*4 + 1] = a.y;
      sA[r*33 + k4*4 + 2] = a.z;
      sA[r*33 + k4*4 + 3] = a.w;
    }
    for (int i = tid; i < 1024; i += 256)
      *(float4*)&sB[i*4] = *(const float4*)&kbT[kc*128 + i*4];
    __syncthreads();
    for (int kk = 0; kk < 32; ++kk) {
      float a0 = sA[(tr*4+0)*33+kk];
      float a1 = sA[(tr*4+1)*33+kk];
      float a2 = sA[(tr*4+2)*33+kk];
      float a3 = sA[(tr*4+3)*33+kk];
      float4 b0 = *(const float4*)&sB[kk*128 + tc*4];
      float4 b1 = *(const float4*)&sB[kk*128 + 64 + tc*4];
      acc[0][0]+=a0*b0.x; acc[0][1]+=a0*b0.y; acc[0][2]+=a0*b0.z; acc[0][3]+=a0*b0.w;
      acc[0][4]+=a0*b1.x; acc[0][5]+=a0*b1.y; acc[0][6]+=a0*b1.z; acc[0][7]+=a0*b1.w;
      acc[1][0]+=a1*b0.x; acc[1][1]+=a1*b0.y; acc[1][2]+=a1*b0.z; acc[1][3]+=a1*b0.w;
      acc[1][4]+=a1*b1.x; acc[1][5]+=a1*b1.y; acc[1][6]+=a1*b1.z; acc[1][7]+=a1*b1.w;
      acc[2][0]+=a2*b0.x; acc[2][1]+=a2*b0.y; acc[2][2]+=a2*b0.z; acc[2][3]+=a2*b0.w;
      acc[2][4]+=a2*b1.x; acc[2][5]+=a2*b1.y; acc[2][6]+=a2*b1.z; acc[2][7]+=a2*b1.w;
      acc[3][0]+=a3*b0.x; acc[3][1]+=a3*b0.y; acc[3][2]+=a3*b0.z; acc[3][3]+=a3*b0.w;
      acc[3][4]+=a3*b1.x; acc[3][5]+=a3*b1.y; acc[3][6]+=a3*b1.z; acc[3][7]+=a3*b1.w;
    }
    __syncthreads();
  }

  const bool valid = (c0 + tr*4) < NCAND;
  float4 cn;
  cn.x = cn.y = cn.z = cn.w = 0.f;
  if (valid) cn = *(const float4*)&candn[c0 + tr*4];
#pragma unroll
  for (int j = 0; j < 8; ++j) {
    int b = (j >> 2)*64 + tc*4 + (j & 3);
    if (valid) {
      float4 o;
      o.x = 2.f*acc[0][j] - cn.x;
      o.y = 2.f*acc[1][j] - cn.y;
      o.z = 2.f*acc[2][j] - cn.z;
      o.w = 2.f*acc[3][j] - cn.w;
      *(float4*)&sims[(size_t)b*NCAND + c0 + tr*4] = o;
    }
  }
}

// ---------------- select stage 1: per-row threshold via sample histogram ----------------
// Sample 1562 (stride 64); threshold = lower edge of the bin holding the 24th-largest
// sample (<= exact 24th sample value => E[#emitted] >= ~1536, never starves).
__global__ void __launch_bounds__(256) k_sample(
    const float* __restrict__ sims, float* __restrict__ gthr, unsigned* __restrict__ gcnt)
{
  __shared__ float sv[1562];
  __shared__ unsigned hist[256];
  __shared__ float wmin[4], wmax[4];
  __shared__ float s_lo, s_inv, s_w;
  const int tid = threadIdx.x, row = blockIdx.x;
  const float* S = sims + (size_t)row*NCAND;
  float lmax = -__builtin_inff(), lmin = __builtin_inff();
  for (int i = tid; i < 1562; i += 256) {
    float v = S[i*64];
    sv[i] = v;
    lmax = fmaxf(lmax, v); lmin = fminf(lmin, v);
  }
  if (tid < 256) hist[tid] = 0;
  for (int o = 32; o; o >>= 1) {
    lmax = fmaxf(lmax, __shfl_xor(lmax, o));
    lmin = fminf(lmin, __shfl_xor(lmin, o));
  }
  if ((tid & 63) == 0) { wmax[tid>>6] = lmax; wmin[tid>>6] = lmin; }
  __syncthreads();
  if (tid == 0) {
    float hi = wmax[0], lo = wmin[0];
    for (int w = 1; w < 4; ++w) { hi = fmaxf(hi, wmax[w]); lo = fminf(lo, wmin[w]); }
    float rng = hi - lo;
    s_lo = lo;
    s_inv = (rng > 0.f) ? (256.f/rng) : 0.f;
    s_w   = (rng > 0.f) ? (rng/256.f) : 0.f;
  }
  __syncthreads();
  const float lo = s_lo, inv = s_inv;
  for (int i = tid; i < 1562; i += 256) {
    int b = min(max((int)((sv[i]-lo)*inv), 0), 255);
    atomicAdd(&hist[b], 1u);
  }
  __syncthreads();
  if (tid == 0) {
    unsigned cum = 0; int b = 255;
    for (; b >= 1; --b) { if (cum + hist[b] >= 24u) break; cum += hist[b]; }
    gthr[row] = lo + (float)b * s_w;   // lower edge of selected bin
    gcnt[row] = 0u;
  }
}

// ---------------- select stage 2: emit all v >= thr (LDS-aggregated) ----------------
__global__ void __launch_bounds__(256) k_emit(
    const float* __restrict__ sims, const float* __restrict__ gthr,
    unsigned* __restrict__ gcnt, float* __restrict__ ev, int* __restrict__ ei)
{
  __shared__ float lv[BCAP];
  __shared__ int   li[BCAP];
  __shared__ unsigned lcnt, lbase;
  const int tid = threadIdx.x;
  const int row = blockIdx.y;
  const int base = blockIdx.x * 12500;       // 8 blocks/row
  const float thr = gthr[row];
  const float* S = sims + (size_t)row*NCAND + base;
  if (tid == 0) lcnt = 0;
  __syncthreads();
  for (int i = tid; i < 3125; i += 256) {
    float4 v = *(const float4*)&S[i*4];
    if (v.x >= thr) { unsigned p = atomicAdd(&lcnt, 1u); if (p < BCAP) { lv[p] = v.x; li[p] = base + i*4 + 0; } }
    if (v.y >= thr) { unsigned p = atomicAdd(&lcnt, 1u); if (p < BCAP) { lv[p] = v.y; li[p] = base + i*4 + 1; } }
    if (v.z >= thr) { unsigned p = atomicAdd(&lcnt, 1u); if (p < BCAP) { lv[p] = v.z; li[p] = base + i*4 + 2; } }
    if (v.w >= thr) { unsigned p = atomicAdd(&lcnt, 1u); if (p < BCAP) { lv[p] = v.w; li[p] = base + i*4 + 3; } }
  }
  __syncthreads();
  const int n = (int)min(lcnt, (unsigned)BCAP);
  if (tid == 0) lbase = atomicAdd(&gcnt[row], (unsigned)n);
  __syncthreads();
  const unsigned gb = lbase;
  float* EV = ev + (size_t)row*EMCAP;
  int*   EI = ei + (size_t)row*EMCAP;
  for (int i = tid; i < n; i += 256) {
    unsigned p = gb + i;
    if (p < EMCAP) { EV[p] = lv[i]; EI[p] = li[i]; }
  }
}

// ---------------- select stage 3: exact top-96 of emitted + softmax + gathers ----------------
__global__ void __launch_bounds__(256) k_final(
    const float* __restrict__ ev, const int* __restrict__ ei,
    const unsigned* __restrict__ gcnt, const float* __restrict__ cand_y,
    float* __restrict__ probs, int* __restrict__ tidxg, float* __restrict__ ygath,
    int r0)
{
  __shared__ float sv[EMCAP];
  __shared__ unsigned hist[1024];
  __shared__ float tv[512]; __shared__ int ti[512];
  __shared__ float selv[96]; __shared__ int seli[96];
  __shared__ unsigned cnts[2];
  __shared__ float wv[4]; __shared__ int wp[4];
  __shared__ float wmin[4], wmax[4];
  __shared__ float s_lo, s_inv;
  __shared__ int sb_s, above_s;
  __shared__ float smax_s, ssum_s;

  const int tid = threadIdx.x, row = blockIdx.x;
  const int n = (int)min(gcnt[row], (unsigned)EMCAP);
  const float* EV = ev + (size_t)row*EMCAP;
  const int*   EI = ei + (size_t)row*EMCAP;

  if (tid < 96) { selv[tid] = -1e30f; seli[tid] = 0; }
  for (int i = tid; i < 1024; i += 256) hist[i] = 0;
  if (tid < 2) cnts[tid] = 0;

  float lmax = -__builtin_inff(), lmin = __builtin_inff();
  for (int i = tid; i < n; i += 256) {
    float v = EV[i]; sv[i] = v;
    lmax = fmaxf(lmax, v); lmin = fminf(lmin, v);
  }
  for (int o = 32; o; o >>= 1) {
    lmax = fmaxf(lmax, __shfl_xor(lmax, o));
    lmin = fminf(lmin, __shfl_xor(lmin, o));
  }
  if ((tid & 63) == 0) { wmax[tid>>6] = lmax; wmin[tid>>6] = lmin; }
  __syncthreads();
  if (tid == 0) {
    float hi = wmax[0], lo = wmin[0];
    for (int w2 = 1; w2 < 4; ++w2) { hi = fmaxf(hi, wmax[w2]); lo = fminf(lo, wmin[w2]); }
    float rng = hi - lo;
    s_lo = lo; s_inv = (rng > 0.f) ? (1024.f/rng) : 0.f;
  }
  __syncthreads();
  const float lo = s_lo, inv = s_inv;

  for (int i = tid; i < n; i += 256) {
    int b = min(max((int)((sv[i]-lo)*inv), 0), 1023);
    atomicAdd(&hist[b], 1u);
  }
  __syncthreads();
  if (tid == 0) {
    unsigned cum = 0; int b = 1023;
    for (; b >= 1; --b) { if (cum + hist[b] >= 96u) break; cum += hist[b]; }
    sb_s = b; above_s = (int)cum;
  }
  __syncthreads();
  const int sb = sb_s, above = above_s;

  for (int i = tid; i < n; i += 256) {
    float v = sv[i];
    int b = min(max((int)((v-lo)*inv), 0), 1023);
    if (b > sb) {
      unsigned p = atomicAdd(&cnts[0], 1u);
      if (p < 96u) { selv[p] = v; seli[p] = EI[i]; }
    } else if (b == sb) {
      unsigned p = atomicAdd(&cnts[1], 1u);
      if (p < 512u) { tv[p] = v; ti[p] = EI[i]; }
    }
  }
  __syncthreads();
  const int need = 96 - above;
  const int tcnt = (int)min(cnts[1], 512u);
  for (int rd = 0; rd < need; ++rd) {
    float best = -__builtin_inff(); int bp = -1;
    for (int t = tid; t < tcnt; t += 256) {
      float v = tv[t];
      if (v > best) { best = v; bp = t; }
    }
    for (int o = 32; o; o >>= 1) {
      float ob = __shfl_xor(best, o); int obp = __shfl_xor(bp, o);
      if (ob > best) { best = ob; bp = obp; }
    }
    if ((tid & 63) == 0) { wv[tid>>6] = best; wp[tid>>6] = bp; }
    __syncthreads();
    if (tid == 0) {
      float bb = wv[0]; int pp = wp[0];
      for (int w2 = 1; w2 < 4; ++w2) if (wv[w2] > bb) { bb = wv[w2]; pp = wp[w2]; }
      if (pp >= 0) { selv[above + rd] = bb; seli[above + rd] = ti[pp]; tv[pp] = -__builtin_inff(); }
    }
    __syncthreads();
  }

  if (tid == 0) {
    float m = selv[0];
    for (int i = 1; i < 96; ++i) m = fmaxf(m, selv[i]);
    smax_s = m;
  }
  __syncthreads();
  if (tid < 96) selv[tid] = expf(selv[tid] - smax_s);
  __syncthreads();
  if (tid == 0) {
    float s = 0.f;
    for (int i = 0; i < 96; ++i) s += selv[i];
    ssum_s = s;
  }
  __syncthreads();
  if (tid < 96) {
    int gr = r0 + row;
    int gi = seli[tid];
    probs[(size_t)gr*96 + tid] = selv[tid]/ssum_s;
    tidxg[(size_t)gr*96 + tid] = gi;
    ygath[(size_t)gr*96 + tid] = cand_y[gi];
  }
}

// ---------------- t-net gather: diff = k_b - cand_k[idx] ----------------
__global__ void __launch_bounds__(256) k_gather_diff(
    const float* __restrict__ kb, const float* __restrict__ candk,
    const int* __restrict__ tidxg, float* __restrict__ diff, int p0)
{
  int f = blockIdx.x*256 + threadIdx.x;
  int pl = f >> 7, d = f & 127;
  int gp = p0 + pl;
  int bb = gp / 96;
  int idx = tidxg[gp];
  diff[f] = kb[(size_t)bb*128 + d] - candk[(size_t)idx*128 + d];
}

// ---------------- context accumulation + residual add ----------------
__global__ void __launch_bounds__(128) k_ctx(
    const float* __restrict__ probs, const float* __restrict__ ygath,
    const float* __restrict__ t2, const float* __restrict__ x2b,
    const float* __restrict__ w_le, const float* __restrict__ b_le,
    float* __restrict__ xfinal, int b0)
{
  int bb = b0 + blockIdx.x;
  int d = threadIdx.x;
  float wle = w_le[d], ble = b_le[d];
  float acc = 0.f;
  int base = (bb - b0)*96;
  for (int c = 0; c < 96; ++c) {
    float p = probs[(size_t)bb*96 + c];
    float y = ygath[(size_t)bb*96 + c];
    acc += p*(y*wle + ble + t2[(size_t)(base + c)*128 + d]);
  }
  xfinal[(size_t)bb*128 + d] = x2b[(size_t)bb*128 + d] + acc;
}

// ---------------- head ----------------
__global__ void __launch_bounds__(256) k_head(
    const float* __restrict__ x, const float* __restrict__ g, const float* __restrict__ b,
    const float* __restrict__ Wh, const float* __restrict__ bh,
    float* __restrict__ out, int M)
{
  const int lane = threadIdx.x & 63, w = threadIdx.x >> 6;
  int rb = blockIdx.x*32 + w*8;
  for (int it = 0; it < 8; ++it) {
    int r = rb + it;
    if (r >= M) return;
    float a = x[(size_t)r*128 + lane];
    float c = x[(size_t)r*128 + 64 + lane];
    float s = a + c;
    for (int o = 32; o; o >>= 1) s += __shfl_xor(s, o);
    float mu = s*(1.f/128.f);
    float da = a - mu, dc = c - mu;
    float v = da*da + dc*dc;
    for (int o = 32; o; o >>= 1) v += __shfl_xor(v, o);
    float rs = rsqrtf(v*(1.f/128.f) + 1e-5f);
    float l0 = fmaxf(da*rs*g[lane]    + b[lane],    0.f);
    float l1 = fmaxf(dc*rs*g[lane+64] + b[lane+64], 0.f);
    float p0 = l0*Wh[lane]     + l1*Wh[64+lane];
    float p1 = l0*Wh[128+lane] + l1*Wh[192+lane];
    for (int o = 32; o; o >>= 1) { p0 += __shfl_xor(p0, o); p1 += __shfl_xor(p1, o); }
    if (lane == 0) { out[r*2 + 0] = p0 + bh[0]; out[r*2 + 1] = p1 + bh[1]; }
  }
}

// ---------------- launcher ----------------
extern "C" void kernel_launch(void* const* d_in, const int* in_sizes, int n_in,
                              void* d_out, int out_size, void* d_ws, size_t ws_size,
                              hipStream_t stream) {
  const float* x_num   = (const float*)d_in[0];
  const float* cand_x  = (const float*)d_in[1];
  const float* cand_y  = (const float*)d_in[2];
  const float* W_in    = (const float*)d_in[3];
  const float* b_in    = (const float*)d_in[4];
  const float* enc_W1  = (const float*)d_in[5];
  const float* enc_b1  = (const float*)d_in[6];
  const float* enc_W2  = (const float*)d_in[7];
  const float* enc_b2  = (const float*)d_in[8];
  const float* mix_g   = (const float*)d_in[9];
  const float* mix_b   = (const float*)d_in[10];
  const float* W_k     = (const float*)d_in[11];
  const float* b_k     = (const float*)d_in[12];
  const float* w_le    = (const float*)d_in[13];
  const float* b_le    = (const float*)d_in[14];
  const float* W_t1    = (const float*)d_in[15];
  const float* b_t1    = (const float*)d_in[16];
  const float* W_t2    = (const float*)d_in[17];
  const float* pred_g  = (const float*)d_in[18];
  const float* pred_b  = (const float*)d_in[19];
  const float* pred_W1 = (const float*)d_in[20];
  const float* pred_b1 = (const float*)d_in[21];
  const float* pred_W2 = (const float*)d_in[22];
  const float* pred_b2 = (const float*)d_in[23];
  const float* head_g  = (const float*)d_in[24];
  const float* head_b  = (const float*)d_in[25];
  const float* W_head  = (const float*)d_in[26];
  const float* b_head  = (const float*)d_in[27];

  float* ws  = (float*)d_ws;
  float* out = (float*)d_out;

  float*    wt     = ws;
  float*    candk  = ws + OFF_CANDK;
  float*    candn  = ws + OFF_CANDN;
  float*    kb     = ws + OFF_KB;
  float*    xb     = ws + OFF_XB;
  float*    x2b    = ws + OFF_X2B;
  float*    lnb    = ws + OFF_LNB;
  float*    hb     = ws + OFF_HB;
  float*    xpred  = ws + OFF_XPRED;
  float*    xfin   = ws + OFF_XFIN;
  float*    kbT    = ws + OFF_KBT;
  float*    probs  = ws + OFF_PROBS;
  int*      tidxg  = (int*)(ws + OFF_TIDX);
  float*    ygath  = ws + OFF_YG;
  float*    sx     = ws + OFF_SX;
  float*    sx2    = ws + OFF_SX2;
  float*    sh     = ws + OFF_SH;
  float*    sln    = ws + OFF_SLN;
  float*    simsbuf = ws + OFF_SX;     // 128*100000 floats (overlaps enc scratch)
  float*    ev     = ws + OFF_EV;      // select-phase only (overlaps sln region)
  int*      ei     = (int*)(ws + OFF_EI);
  unsigned* gcnt   = (unsigned*)(ws + OFF_GCNT);
  float*    gthr   = ws + OFF_GTHR;

  // 1) weight transposes
  k_transpose<<<256, 256, 0, stream>>>(W_in, enc_W1, enc_W2, W_k, W_t1, W_t2, pred_W1, pred_W2, wt);

  // 2) batch encoder
  k_gemm<128,false,false,false><<<16, 256, 0, stream>>>(x_num, wt+WT_IN, b_in,   nullptr, xb,  nullptr, BATCH, 64);
  k_gemm<256,true ,false,false><<<16, 256, 0, stream>>>(xb,    wt+WT_E1, enc_b1, nullptr, hb,  nullptr, BATCH, 128);
  k_gemm<128,false,true ,false><<<16, 256, 0, stream>>>(hb,    wt+WT_E2, enc_b2, xb,      x2b, nullptr, BATCH, 256);
  k_ln<<<(BATCH+31)/32, 256, 0, stream>>>(x2b, mix_g, mix_b, lnb, BATCH);
  k_gemm<128,false,false,false><<<16, 256, 0, stream>>>(lnb,   wt+WT_K,  b_k,    nullptr, kb,  nullptr, BATCH, 128);
  k_transpose_kb<<<512, 256, 0, stream>>>(kb, kbT);

  // 3) candidate encoder, 4 chunks of 25000
  for (int ch = 0; ch < 4; ++ch) {
    const float* a0 = cand_x + (size_t)ch*ECH*64;
    float* ck = candk + (size_t)ch*ECH*128;
    float* cn = candn + (size_t)ch*ECH;
    int grid = (ECH + 63)/64;
    k_gemm<128,false,false,false><<<grid, 256, 0, stream>>>(a0,  wt+WT_IN, b_in,   nullptr, sx,  nullptr, ECH, 64);
    k_gemm<256,true ,false,false><<<grid, 256, 0, stream>>>(sx,  wt+WT_E1, enc_b1, nullptr, sh,  nullptr, ECH, 128);
    k_gemm<128,false,true ,false><<<grid, 256, 0, stream>>>(sh,  wt+WT_E2, enc_b2, sx,      sx2, nullptr, ECH, 256);
    k_ln<<<(ECH+31)/32, 256, 0, stream>>>(sx2, mix_g, mix_b, sln, ECH);
    k_gemm<128,false,false,true ><<<grid, 256, 0, stream>>>(sln, wt+WT_K,  b_k,    nullptr, ck,  cn,      ECH, 128);
  }

  // 4) sims + exact top-96, 8 row chunks of 128
  for (int ch = 0; ch < 8; ++ch) {
    k_sims_gemm<<<(NCAND+63)/64, 256, 0, stream>>>(
        kbT + (size_t)ch*128*128, candk, candn, simsbuf);
    k_sample<<<RCH, 256, 0, stream>>>(simsbuf, gthr, gcnt);
    k_emit<<<dim3(8, RCH), 256, 0, stream>>>(simsbuf, gthr, gcnt, ev, ei);
    k_final<<<RCH, 256, 0, stream>>>(ev, ei, gcnt, cand_y, probs, tidxg, ygath, ch*RCH);
  }

  // 5) t-net, 4 chunks of 256 batch rows
  for (int tc = 0; tc < 4; ++tc) {
    int p0 = tc*TP, b0 = tc*TROWS;
    k_gather_diff<<<(TP*128)/256, 256, 0, stream>>>(kb, candk, tidxg, sln, p0);
    k_gemm<256,true ,false,false><<<TP/64, 256, 0, stream>>>(sln, wt+WT_T1, b_t1, nullptr, sh, nullptr, TP, 128);
    k_gemm<128,false,false,false><<<TP/64, 256, 0, stream>>>(sh,  wt+WT_T2, nullptr, nullptr, sx, nullptr, TP, 256);
    k_ctx<<<TROWS, 128, 0, stream>>>(probs, ygath, sx, x2b, w_le, b_le, xfin, b0);
  }

  // 6) predictor block + head
  k_ln<<<(BATCH+31)/32, 256, 0, stream>>>(xfin, pred_g, pred_b, lnb, BATCH);
  k_gemm<256,true ,false,false><<<16, 256, 0, stream>>>(lnb, wt+WT_P1, pred_b1, nullptr, hb,    nullptr, BATCH, 128);
  k_gemm<128,false,true ,false><<<16, 256, 0, stream>>>(hb,  wt+WT_P2, pred_b2, xfin,    xpred, nullptr, BATCH, 256);
  k_head<<<(BATCH+31)/32, 256, 0, stream>>>(xpred, head_g, head_b, W_head, b_head, out, BATCH);
}

// Round 6
// 2175.974 us; speedup vs baseline: 2.2013x; 1.0722x over previous
//
#include <hip/hip_runtime.h>
#include <math.h>

// ---------------- problem sizes ----------------
#define BATCH   1024
#define NCAND   100000
#define NCPAD   100032       // padded to 64
#define DM      128
#define DB      256
#define NNUM    64
#define CTXS    96
#define ECH     25000        // candidate-encoder M chunk (4 chunks)
#define TROWS   256          // t-net batch rows per chunk (4 chunks)
#define TP      (TROWS*CTXS) // 24576 pairs per t-net chunk
#define RCH     128          // sims row chunk (8 chunks)
#define EMCAP   8192         // emitted-candidate cap per row
#define BCAP    1024         // per-block emit cap

// ---------------- workspace offsets (in floats) ----------------
#define WT_IN       0u
#define WT_E1       8192u
#define WT_E2       40960u
#define WT_K        73728u
#define WT_T1       90112u
#define WT_T2       122880u
#define WT_P1       155648u
#define WT_P2       188416u
#define OFF_CKH     221184u      // 100032*128 bf16 (6,402,048 floats)
#define OFF_CKL     6623232u     // 100032*128 bf16
#define OFF_CANDN   13025280u    // 100000
#define OFF_KB      13125280u    // 1024*128
#define OFF_XB      13256352u    // 1024*128
#define OFF_X2B     13387424u    // 1024*128
#define OFF_LNB     13518496u    // 1024*128
#define OFF_HB      13649568u    // 1024*256
#define OFF_XPRED   13911712u    // 1024*128
#define OFF_XFIN    14042784u    // 1024*128
#define OFF_KBA     14173856u    // kbAh 131072 shorts + kbAl 131072 shorts
#define OFF_PROBS   15743648u    // 1024*96
#define OFF_TIDX    15841952u    // 1024*96 (int)
#define OFF_YG      15940256u    // 1024*96
#define OFF_SX      16038560u    // enc X (25000*128) / t-net T2 / sims buffer (12.8M)
#define OFF_SX2     19238560u    // enc X2
#define OFF_SH      22438560u    // enc H / t-net TH
#define OFF_SLN     28838560u    // enc LN / t-net diff / select emit buffers
#define OFF_EV      28838560u    // 128*8192 floats (select phase)
#define OFF_EI      29887136u    // 128*8192 int
#define OFF_GCNT    30935712u    // 128 uint
#define OFF_GTHR    30935840u    // 128 float

typedef __attribute__((ext_vector_type(8))) short bf16x8;
typedef __attribute__((ext_vector_type(4))) float f32x4;
#define MFMA16(A,B,C) C = __builtin_amdgcn_mfma_f32_16x16x32_bf16(A, B, C, 0, 0, 0)

__device__ __forceinline__ unsigned short f2bf(float x) {
  unsigned u = __float_as_uint(x);
  unsigned r = (u + 0x7FFFu + ((u >> 16) & 1u)) >> 16;
  return (unsigned short)r;
}
__device__ __forceinline__ float bf2f(unsigned short h) {
  return __uint_as_float(((unsigned)h) << 16);
}

// ---------------- weight transpose prep ----------------
__global__ void __launch_bounds__(256) k_transpose(
    const float* __restrict__ w0, const float* __restrict__ w1,
    const float* __restrict__ w2, const float* __restrict__ w3,
    const float* __restrict__ w4, const float* __restrict__ w5,
    const float* __restrict__ w6, const float* __restrict__ w7,
    float* __restrict__ dst)
{
  const float* src[8] = {w0,w1,w2,w3,w4,w5,w6,w7};
  const int nn[8]  = {128,256,128,128,256,128,256,128};
  const int kkv[8] = { 64,128,256,128,128,256,128,256};
  const int off[8] = {0,8192,40960,73728,90112,122880,155648,188416};
  int stride = gridDim.x*blockDim.x;
  int t0 = blockIdx.x*blockDim.x + threadIdx.x;
#pragma unroll
  for (int m = 0; m < 8; ++m) {
    int total = nn[m]*kkv[m];
    for (int i = t0; i < total; i += stride) {
      int k = i / nn[m];
      int n = i - k*nn[m];
      dst[off[m] + i] = src[m][n*kkv[m] + k];
    }
  }
}

// zero the pad rows of ckh/ckl (cands 100000..100031)
__global__ void __launch_bounds__(256) k_pad_ck(
    unsigned short* __restrict__ ckh, unsigned short* __restrict__ ckl)
{
  int i = blockIdx.x*256 + threadIdx.x;   // 4096
  if (i < 4096) {
    ckh[(size_t)NCAND*128 + i] = 0;
    ckl[(size_t)NCAND*128 + i] = 0;
  }
}

// kb [1024][128] fp32 -> A-fragment-ordered bf16 hi/lo buffers
// layout: [ch(8)][mt(8)][s(4)][lane(64)][j(8)] ; element = kb[ch*128+mt*16+(lane&15)][s*32+(lane>>4)*8+j]
__global__ void __launch_bounds__(256) k_cvt_kbA(
    const float* __restrict__ kb,
    unsigned short* __restrict__ kbAh, unsigned short* __restrict__ kbAl)
{
  int i = blockIdx.x*256 + threadIdx.x;   // 131072
  int j = i & 7, lane = (i >> 3) & 63, s = (i >> 9) & 3, mt = (i >> 11) & 7, ch = i >> 14;
  int row = ch*128 + mt*16 + (lane & 15);
  int k = s*32 + (lane >> 4)*8 + j;
  float x = kb[(size_t)row*128 + k];
  unsigned short h = f2bf(x);
  float lo = x - bf2f(h);
  kbAh[i] = h;
  kbAl[i] = f2bf(lo);
}

// ---------------- generic fp32 GEMM (optional bf16 hi/lo output) ----------------
template<int N, bool RELU, bool RESID, bool NORM, bool B16>
__global__ void __launch_bounds__(256) k_gemm(
    const float* __restrict__ A, const float* __restrict__ WT,
    const float* __restrict__ bias, const float* __restrict__ resid,
    float* __restrict__ C, float* __restrict__ nrm,
    unsigned short* __restrict__ Ch, unsigned short* __restrict__ Cl,
    int M, int K)
{
  constexpr int G = N/64;
  __shared__ __align__(16) float sA[64*33];
  __shared__ __align__(16) float sW[32*N];
  __shared__ float sNorm[64];
  const int tid = threadIdx.x;
  const int r0 = blockIdx.x*64;
  const int tr = tid >> 4, tc = tid & 15;
  float acc[4][G*4];
#pragma unroll
  for (int i = 0; i < 4; ++i)
#pragma unroll
    for (int j = 0; j < G*4; ++j) acc[i][j] = 0.f;

  for (int kc = 0; kc < K; kc += 32) {
    for (int i = tid; i < 64*32; i += 256) {
      int r = i >> 5, kk = i & 31;
      int gr = r0 + r;
      sA[r*33 + kk] = (gr < M) ? A[(size_t)gr*K + kc + kk] : 0.f;
    }
    for (int i = tid; i < 32*N; i += 256) sW[i] = WT[(size_t)kc*N + i];
    __syncthreads();
    for (int kk = 0; kk < 32; ++kk) {
      float a0 = sA[(tr*4+0)*33+kk];
      float a1 = sA[(tr*4+1)*33+kk];
      float a2 = sA[(tr*4+2)*33+kk];
      float a3 = sA[(tr*4+3)*33+kk];
#pragma unroll
      for (int g = 0; g < G; ++g) {
        float4 w = *(const float4*)&sW[kk*N + g*64 + tc*4];
        acc[0][g*4+0] += a0*w.x; acc[0][g*4+1] += a0*w.y; acc[0][g*4+2] += a0*w.z; acc[0][g*4+3] += a0*w.w;
        acc[1][g*4+0] += a1*w.x; acc[1][g*4+1] += a1*w.y; acc[1][g*4+2] += a1*w.z; acc[1][g*4+3] += a1*w.w;
        acc[2][g*4+0] += a2*w.x; acc[2][g*4+1] += a2*w.y; acc[2][g*4+2] += a2*w.z; acc[2][g*4+3] += a2*w.w;
        acc[3][g*4+0] += a3*w.x; acc[3][g*4+1] += a3*w.y; acc[3][g*4+2] += a3*w.z; acc[3][g*4+3] += a3*w.w;
      }
    }
    __syncthreads();
  }

  float rowsq[4] = {0.f,0.f,0.f,0.f};
#pragma unroll
  for (int i = 0; i < 4; ++i) {
    int r = r0 + tr*4 + i;
    if (r < M) {
#pragma unroll
      for (int g = 0; g < G; ++g) {
        int col = g*64 + tc*4;
        float v0 = acc[i][g*4+0], v1 = acc[i][g*4+1], v2 = acc[i][g*4+2], v3 = acc[i][g*4+3];
        if (bias) { v0 += bias[col+0]; v1 += bias[col+1]; v2 += bias[col+2]; v3 += bias[col+3]; }
        if constexpr (RELU) { v0 = fmaxf(v0,0.f); v1 = fmaxf(v1,0.f); v2 = fmaxf(v2,0.f); v3 = fmaxf(v3,0.f); }
        if constexpr (RESID) {
          float4 rv = *(const float4*)&resid[(size_t)r*N + col];
          v0 += rv.x; v1 += rv.y; v2 += rv.z; v3 += rv.w;
        }
        if constexpr (B16) {
          unsigned short h0 = f2bf(v0), h1 = f2bf(v1), h2 = f2bf(v2), h3 = f2bf(v3);
          unsigned short l0 = f2bf(v0 - bf2f(h0)), l1 = f2bf(v1 - bf2f(h1));
          unsigned short l2 = f2bf(v2 - bf2f(h2)), l3 = f2bf(v3 - bf2f(h3));
          uint2 hp; hp.x = (unsigned)h0 | ((unsigned)h1 << 16); hp.y = (unsigned)h2 | ((unsigned)h3 << 16);
          uint2 lp; lp.x = (unsigned)l0 | ((unsigned)l1 << 16); lp.y = (unsigned)l2 | ((unsigned)l3 << 16);
          *(uint2*)&Ch[(size_t)r*N + col] = hp;
          *(uint2*)&Cl[(size_t)r*N + col] = lp;
        } else {
          float4 o4; o4.x = v0; o4.y = v1; o4.z = v2; o4.w = v3;
          *(float4*)&C[(size_t)r*N + col] = o4;
        }
        if constexpr (NORM) rowsq[i] += v0*v0 + v1*v1 + v2*v2 + v3*v3;
      }
    }
  }
  if constexpr (NORM) {
    if (tid < 64) sNorm[tid] = 0.f;
    __syncthreads();
#pragma unroll
    for (int i = 0; i < 4; ++i) atomicAdd(&sNorm[tr*4+i], rowsq[i]);
    __syncthreads();
    if (tid < 64 && r0 + tid < M) nrm[r0 + tid] = sNorm[tid];
  }
}

// ---------------- LayerNorm (wave-per-row) ----------------
__global__ void __launch_bounds__(256) k_ln(
    const float* __restrict__ x, const float* __restrict__ g, const float* __restrict__ b,
    float* __restrict__ o, int M)
{
  const int lane = threadIdx.x & 63, w = threadIdx.x >> 6;
  int rb = blockIdx.x*32 + w*8;
  for (int it = 0; it < 8; ++it) {
    int r = rb + it;
    if (r >= M) return;
    float a = x[(size_t)r*128 + lane];
    float c = x[(size_t)r*128 + 64 + lane];
    float s = a + c;
    for (int o2 = 32; o2; o2 >>= 1) s += __shfl_xor(s, o2);
    float mu = s * (1.f/128.f);
    float da = a - mu, dc = c - mu;
    float v = da*da + dc*dc;
    for (int o2 = 32; o2; o2 >>= 1) v += __shfl_xor(v, o2);
    float rs = rsqrtf(v*(1.f/128.f) + 1e-5f);
    o[(size_t)r*128 + lane]      = da*rs*g[lane]    + b[lane];
    o[(size_t)r*128 + 64 + lane] = dc*rs*g[lane+64] + b[lane+64];
  }
}

// ---------------- sims via MFMA: 128 batch rows x 64 cands per block ----------------
// hi/lo bf16 split: acc = ah*bh + al*bh + ah*bl  (lo*lo ~2^-18, dropped)
// A-frag: A[m=lane&15][k=(lane>>4)*8+j] (pre-swizzled kbA buffers)
// B-frag: B[n=lane&15][k=(lane>>4)*8+j] (row-major bf16 candk)
// C/D   : col=lane&15, row=(lane>>4)*4+reg
__global__ void __launch_bounds__(256) k_sims_mfma(
    const unsigned short* __restrict__ kbAh, const unsigned short* __restrict__ kbAl,
    const unsigned short* __restrict__ ckh,  const unsigned short* __restrict__ ckl,
    const float* __restrict__ candn,
    float* __restrict__ sims, int ch)
{
  const int tid = threadIdx.x;
  const int wv = tid >> 6, lane = tid & 63;
  const int c0 = blockIdx.x * 64;
  const int q = lane >> 4, n16 = lane & 15;

  f32x4 acc00 = {0.f,0.f,0.f,0.f}, acc01 = {0.f,0.f,0.f,0.f};
  f32x4 acc02 = {0.f,0.f,0.f,0.f}, acc03 = {0.f,0.f,0.f,0.f};
  f32x4 acc10 = {0.f,0.f,0.f,0.f}, acc11 = {0.f,0.f,0.f,0.f};
  f32x4 acc12 = {0.f,0.f,0.f,0.f}, acc13 = {0.f,0.f,0.f,0.f};

  const int mt0 = wv*2, mt1 = wv*2 + 1;
  const size_t a0base = (size_t)(ch*8 + mt0)*2048;   // *4s*64lane*8j
  const size_t a1base = (size_t)(ch*8 + mt1)*2048;
  const size_t b0 = (size_t)(c0 + n16)*128;
  const size_t b1 = b0 + 16*128;
  const size_t b2 = b0 + 32*128;
  const size_t b3 = b0 + 48*128;

#pragma unroll
  for (int s = 0; s < 4; ++s) {
    const size_t ao = (size_t)s*512 + (size_t)lane*8;
    bf16x8 ah0 = *(const bf16x8*)(kbAh + a0base + ao);
    bf16x8 ah1 = *(const bf16x8*)(kbAh + a1base + ao);
    bf16x8 al0 = *(const bf16x8*)(kbAl + a0base + ao);
    bf16x8 al1 = *(const bf16x8*)(kbAl + a1base + ao);
    const int ko = s*32 + q*8;
    bf16x8 bh0v = *(const bf16x8*)(ckh + b0 + ko);
    bf16x8 bh1v = *(const bf16x8*)(ckh + b1 + ko);
    bf16x8 bh2v = *(const bf16x8*)(ckh + b2 + ko);
    bf16x8 bh3v = *(const bf16x8*)(ckh + b3 + ko);
    bf16x8 bl0v = *(const bf16x8*)(ckl + b0 + ko);
    bf16x8 bl1v = *(const bf16x8*)(ckl + b1 + ko);
    bf16x8 bl2v = *(const bf16x8*)(ckl + b2 + ko);
    bf16x8 bl3v = *(const bf16x8*)(ckl + b3 + ko);

    MFMA16(ah0, bh0v, acc00); MFMA16(ah0, bh1v, acc01);
    MFMA16(ah0, bh2v, acc02); MFMA16(ah0, bh3v, acc03);
    MFMA16(ah1, bh0v, acc10); MFMA16(ah1, bh1v, acc11);
    MFMA16(ah1, bh2v, acc12); MFMA16(ah1, bh3v, acc13);

    MFMA16(al0, bh0v, acc00); MFMA16(al0, bh1v, acc01);
    MFMA16(al0, bh2v, acc02); MFMA16(al0, bh3v, acc03);
    MFMA16(al1, bh0v, acc10); MFMA16(al1, bh1v, acc11);
    MFMA16(al1, bh2v, acc12); MFMA16(al1, bh3v, acc13);

    MFMA16(ah0, bl0v, acc00); MFMA16(ah0, bl1v, acc01);
    MFMA16(ah0, bl2v, acc02); MFMA16(ah0, bl3v, acc03);
    MFMA16(ah1, bl0v, acc10); MFMA16(ah1, bl1v, acc11);
    MFMA16(ah1, bl2v, acc12); MFMA16(ah1, bl3v, acc13);
  }

  const int rb0 = mt0*16 + q*4, rb1 = mt1*16 + q*4;
#define EPI(NT, A0, A1) { \
    int col = c0 + NT*16 + n16; \
    if (col < NCAND) { \
      float cn = candn[col]; \
      sims[(size_t)(rb0+0)*NCAND + col] = 2.f*A0[0] - cn; \
      sims[(size_t)(rb0+1)*NCAND + col] = 2.f*A0[1] - cn; \
      sims[(size_t)(rb0+2)*NCAND + col] = 2.f*A0[2] - cn; \
      sims[(size_t)(rb0+3)*NCAND + col] = 2.f*A0[3] - cn; \
      sims[(size_t)(rb1+0)*NCAND + col] = 2.f*A1[0] - cn; \
      sims[(size_t)(rb1+1)*NCAND + col] = 2.f*A1[1] - cn; \
      sims[(size_t)(rb1+2)*NCAND + col] = 2.f*A1[2] - cn; \
      sims[(size_t)(rb1+3)*NCAND + col] = 2.f*A1[3] - cn; \
    } }
  EPI(0, acc00, acc10)
  EPI(1, acc01, acc11)
  EPI(2, acc02, acc12)
  EPI(3, acc03, acc13)
#undef EPI
}

// ---------------- select stage 1: per-row threshold via sample histogram ----------------
__global__ void __launch_bounds__(256) k_sample(
    const float* __restrict__ sims, float* __restrict__ gthr, unsigned* __restrict__ gcnt)
{
  __shared__ float sv[1562];
  __shared__ unsigned hist[256];
  __shared__ float wmin[4], wmax[4];
  __shared__ float s_lo, s_inv, s_w;
  const int tid = threadIdx.x, row = blockIdx.x;
  const float* S = sims + (size_t)row*NCAND;
  float lmax = -__builtin_inff(), lmin = __builtin_inff();
  for (int i = tid; i < 1562; i += 256) {
    float v = S[i*64];
    sv[i] = v;
    lmax = fmaxf(lmax, v); lmin = fminf(lmin, v);
  }
  if (tid < 256) hist[tid] = 0;
  for (int o = 32; o; o >>= 1) {
    lmax = fmaxf(lmax, __shfl_xor(lmax, o));
    lmin = fminf(lmin, __shfl_xor(lmin, o));
  }
  if ((tid & 63) == 0) { wmax[tid>>6] = lmax; wmin[tid>>6] = lmin; }
  __syncthreads();
  if (tid == 0) {
    float hi = wmax[0], lo = wmin[0];
    for (int w = 1; w < 4; ++w) { hi = fmaxf(hi, wmax[w]); lo = fminf(lo, wmin[w]); }
    float rng = hi - lo;
    s_lo = lo;
    s_inv = (rng > 0.f) ? (256.f/rng) : 0.f;
    s_w   = (rng > 0.f) ? (rng/256.f) : 0.f;
  }
  __syncthreads();
  const float lo = s_lo, inv = s_inv;
  for (int i = tid; i < 1562; i += 256) {
    int b = min(max((int)((sv[i]-lo)*inv), 0), 255);
    atomicAdd(&hist[b], 1u);
  }
  __syncthreads();
  if (tid == 0) {
    unsigned cum = 0; int b = 255;
    for (; b >= 1; --b) { if (cum + hist[b] >= 24u) break; cum += hist[b]; }
    gthr[row] = lo + (float)b * s_w;
    gcnt[row] = 0u;
  }
}

// ---------------- select stage 2: emit all v >= thr (LDS-aggregated) ----------------
__global__ void __launch_bounds__(256) k_emit(
    const float* __restrict__ sims, const float* __restrict__ gthr,
    unsigned* __restrict__ gcnt, float* __restrict__ ev, int* __restrict__ ei)
{
  __shared__ float lv[BCAP];
  __shared__ int   li[BCAP];
  __shared__ unsigned lcnt, lbase;
  const int tid = threadIdx.x;
  const int row = blockIdx.y;
  const int base = blockIdx.x * 12500;
  const float thr = gthr[row];
  const float* S = sims + (size_t)row*NCAND + base;
  if (tid == 0) lcnt = 0;
  __syncthreads();
  for (int i = tid; i < 3125; i += 256) {
    float4 v = *(const float4*)&S[i*4];
    if (v.x >= thr) { unsigned p = atomicAdd(&lcnt, 1u); if (p < BCAP) { lv[p] = v.x; li[p] = base + i*4 + 0; } }
    if (v.y >= thr) { unsigned p = atomicAdd(&lcnt, 1u); if (p < BCAP) { lv[p] = v.y; li[p] = base + i*4 + 1; } }
    if (v.z >= thr) { unsigned p = atomicAdd(&lcnt, 1u); if (p < BCAP) { lv[p] = v.z; li[p] = base + i*4 + 2; } }
    if (v.w >= thr) { unsigned p = atomicAdd(&lcnt, 1u); if (p < BCAP) { lv[p] = v.w; li[p] = base + i*4 + 3; } }
  }
  __syncthreads();
  const int n = (int)min(lcnt, (unsigned)BCAP);
  if (tid == 0) lbase = atomicAdd(&gcnt[row], (unsigned)n);
  __syncthreads();
  const unsigned gb = lbase;
  float* EV = ev + (size_t)row*EMCAP;
  int*   EI = ei + (size_t)row*EMCAP;
  for (int i = tid; i < n; i += 256) {
    unsigned p = gb + i;
    if (p < EMCAP) { EV[p] = lv[i]; EI[p] = li[i]; }
  }
}

// ---------------- select stage 3: exact top-96 + softmax + gathers ----------------
__global__ void __launch_bounds__(256) k_final(
    const float* __restrict__ ev, const int* __restrict__ ei,
    const unsigned* __restrict__ gcnt, const float* __restrict__ cand_y,
    float* __restrict__ probs, int* __restrict__ tidxg, float* __restrict__ ygath,
    int r0)
{
  __shared__ float sv[EMCAP];
  __shared__ unsigned hist[1024];
  __shared__ float tv[512]; __shared__ int ti[512];
  __shared__ float selv[96]; __shared__ int seli[96];
  __shared__ unsigned cnts[2];
  __shared__ float wv[4]; __shared__ int wp[4];
  __shared__ float wmin[4], wmax[4];
  __shared__ float s_lo, s_inv;
  __shared__ int sb_s, above_s;
  __shared__ float smax_s, ssum_s;

  const int tid = threadIdx.x, row = blockIdx.x;
  const int n = (int)min(gcnt[row], (unsigned)EMCAP);
  const float* EV = ev + (size_t)row*EMCAP;
  const int*   EI = ei + (size_t)row*EMCAP;

  if (tid < 96) { selv[tid] = -1e30f; seli[tid] = 0; }
  for (int i = tid; i < 1024; i += 256) hist[i] = 0;
  if (tid < 2) cnts[tid] = 0;

  float lmax = -__builtin_inff(), lmin = __builtin_inff();
  for (int i = tid; i < n; i += 256) {
    float v = EV[i]; sv[i] = v;
    lmax = fmaxf(lmax, v); lmin = fminf(lmin, v);
  }
  for (int o = 32; o; o >>= 1) {
    lmax = fmaxf(lmax, __shfl_xor(lmax, o));
    lmin = fminf(lmin, __shfl_xor(lmin, o));
  }
  if ((tid & 63) == 0) { wmax[tid>>6] = lmax; wmin[tid>>6] = lmin; }
  __syncthreads();
  if (tid == 0) {
    float hi = wmax[0], lo = wmin[0];
    for (int w2 = 1; w2 < 4; ++w2) { hi = fmaxf(hi, wmax[w2]); lo = fminf(lo, wmin[w2]); }
    float rng = hi - lo;
    s_lo = lo; s_inv = (rng > 0.f) ? (1024.f/rng) : 0.f;
  }
  __syncthreads();
  const float lo = s_lo, inv = s_inv;

  for (int i = tid; i < n; i += 256) {
    int b = min(max((int)((sv[i]-lo)*inv), 0), 1023);
    atomicAdd(&hist[b], 1u);
  }
  __syncthreads();
  if (tid == 0) {
    unsigned cum = 0; int b = 1023;
    for (; b >= 1; --b) { if (cum + hist[b] >= 96u) break; cum += hist[b]; }
    sb_s = b; above_s = (int)cum;
  }
  __syncthreads();
  const int sb = sb_s, above = above_s;

  for (int i = tid; i < n; i += 256) {
    float v = sv[i];
    int b = min(max((int)((v-lo)*inv), 0), 1023);
    if (b > sb) {
      unsigned p = atomicAdd(&cnts[0], 1u);
      if (p < 96u) { selv[p] = v; seli[p] = EI[i]; }
    } else if (b == sb) {
      unsigned p = atomicAdd(&cnts[1], 1u);
      if (p < 512u) { tv[p] = v; ti[p] = EI[i]; }
    }
  }
  __syncthreads();
  const int need = 96 - above;
  const int tcnt = (int)min(cnts[1], 512u);
  for (int rd = 0; rd < need; ++rd) {
    float best = -__builtin_inff(); int bp = -1;
    for (int t = tid; t < tcnt; t += 256) {
      float v = tv[t];
      if (v > best) { best = v; bp = t; }
    }
    for (int o = 32; o; o >>= 1) {
      float ob = __shfl_xor(best, o); int obp = __shfl_xor(bp, o);
      if (ob > best) { best = ob; bp = obp; }
    }
    if ((tid & 63) == 0) { wv[tid>>6] = best; wp[tid>>6] = bp; }
    __syncthreads();
    if (tid == 0) {
      float bb = wv[0]; int pp = wp[0];
      for (int w2 = 1; w2 < 4; ++w2) if (wv[w2] > bb) { bb = wv[w2]; pp = wp[w2]; }
      if (pp >= 0) { selv[above + rd] = bb; seli[above + rd] = ti[pp]; tv[pp] = -__builtin_inff(); }
    }
    __syncthreads();
  }

  if (tid == 0) {
    float m = selv[0];
    for (int i = 1; i < 96; ++i) m = fmaxf(m, selv[i]);
    smax_s = m;
  }
  __syncthreads();
  if (tid < 96) selv[tid] = expf(selv[tid] - smax_s);
  __syncthreads();
  if (tid == 0) {
    float s = 0.f;
    for (int i = 0; i < 96; ++i) s += selv[i];
    ssum_s = s;
  }
  __syncthreads();
  if (tid < 96) {
    int gr = r0 + row;
    int gi = seli[tid];
    probs[(size_t)gr*96 + tid] = selv[tid]/ssum_s;
    tidxg[(size_t)gr*96 + tid] = gi;
    ygath[(size_t)gr*96 + tid] = cand_y[gi];
  }
}

// ---------------- t-net gather: diff = k_b - cand_k[idx] (bf16 hi/lo reconstruct) ----------------
__global__ void __launch_bounds__(256) k_gather_diff(
    const float* __restrict__ kb,
    const unsigned short* __restrict__ ckh, const unsigned short* __restrict__ ckl,
    const int* __restrict__ tidxg, float* __restrict__ diff, int p0)
{
  int f = blockIdx.x*256 + threadIdx.x;
  int pl = f >> 7, d = f & 127;
  int gp = p0 + pl;
  int bb = gp / 96;
  int idx = tidxg[gp];
  float cv = bf2f(ckh[(size_t)idx*128 + d]) + bf2f(ckl[(size_t)idx*128 + d]);
  diff[f] = kb[(size_t)bb*128 + d] - cv;
}

// ---------------- context accumulation + residual add ----------------
__global__ void __launch_bounds__(128) k_ctx(
    const float* __restrict__ probs, const float* __restrict__ ygath,
    const float* __restrict__ t2, const float* __restrict__ x2b,
    const float* __restrict__ w_le, const float* __restrict__ b_le,
    float* __restrict__ xfinal, int b0)
{
  int bb = b0 + blockIdx.x;
  int d = threadIdx.x;
  float wle = w_le[d], ble = b_le[d];
  float acc = 0.f;
  int base = (bb - b0)*96;
  for (int c = 0; c < 96; ++c) {
    float p = probs[(size_t)bb*96 + c];
    float y = ygath[(size_t)bb*96 + c];
    acc += p*(y*wle + ble + t2[(size_t)(base + c)*128 + d]);
  }
  xfinal[(size_t)bb*128 + d] = x2b[(size_t)bb*128 + d] + acc;
}

// ---------------- head ----------------
__global__ void __launch_bounds__(256) k_head(
    const float* __restrict__ x, const float* __restrict__ g, const float* __restrict__ b,
    const float* __restrict__ Wh, const float* __restrict__ bh,
    float* __restrict__ out, int M)
{
  const int lane = threadIdx.x & 63, w = threadIdx.x >> 6;
  int rb = blockIdx.x*32 + w*8;
  for (int it = 0; it < 8; ++it) {
    int r = rb + it;
    if (r >= M) return;
    float a = x[(size_t)r*128 + lane];
    float c = x[(size_t)r*128 + 64 + lane];
    float s = a + c;
    for (int o = 32; o; o >>= 1) s += __shfl_xor(s, o);
    float mu = s*(1.f/128.f);
    float da = a - mu, dc = c - mu;
    float v = da*da + dc*dc;
    for (int o = 32; o; o >>= 1) v += __shfl_xor(v, o);
    float rs = rsqrtf(v*(1.f/128.f) + 1e-5f);
    float l0 = fmaxf(da*rs*g[lane]    + b[lane],    0.f);
    float l1 = fmaxf(dc*rs*g[lane+64] + b[lane+64], 0.f);
    float p0 = l0*Wh[lane]     + l1*Wh[64+lane];
    float p1 = l0*Wh[128+lane] + l1*Wh[192+lane];
    for (int o = 32; o; o >>= 1) { p0 += __shfl_xor(p0, o); p1 += __shfl_xor(p1, o); }
    if (lane == 0) { out[r*2 + 0] = p0 + bh[0]; out[r*2 + 1] = p1 + bh[1]; }
  }
}

// ---------------- launcher ----------------
extern "C" void kernel_launch(void* const* d_in, const int* in_sizes, int n_in,
                              void* d_out, int out_size, void* d_ws, size_t ws_size,
                              hipStream_t stream) {
  const float* x_num   = (const float*)d_in[0];
  const float* cand_x  = (const float*)d_in[1];
  const float* cand_y  = (const float*)d_in[2];
  const float* W_in    = (const float*)d_in[3];
  const float* b_in    = (const float*)d_in[4];
  const float* enc_W1  = (const float*)d_in[5];
  const float* enc_b1  = (const float*)d_in[6];
  const float* enc_W2  = (const float*)d_in[7];
  const float* enc_b2  = (const float*)d_in[8];
  const float* mix_g   = (const float*)d_in[9];
  const float* mix_b   = (const float*)d_in[10];
  const float* W_k     = (const float*)d_in[11];
  const float* b_k     = (const float*)d_in[12];
  const float* w_le    = (const float*)d_in[13];
  const float* b_le    = (const float*)d_in[14];
  const float* W_t1    = (const float*)d_in[15];
  const float* b_t1    = (const float*)d_in[16];
  const float* W_t2    = (const float*)d_in[17];
  const float* pred_g  = (const float*)d_in[18];
  const float* pred_b  = (const float*)d_in[19];
  const float* pred_W1 = (const float*)d_in[20];
  const float* pred_b1 = (const float*)d_in[21];
  const float* pred_W2 = (const float*)d_in[22];
  const float* pred_b2 = (const float*)d_in[23];
  const float* head_g  = (const float*)d_in[24];
  const float* head_b  = (const float*)d_in[25];
  const float* W_head  = (const float*)d_in[26];
  const float* b_head  = (const float*)d_in[27];

  float* ws  = (float*)d_ws;
  float* out = (float*)d_out;

  float*          wt     = ws;
  unsigned short* ckh    = (unsigned short*)(ws + OFF_CKH);
  unsigned short* ckl    = (unsigned short*)(ws + OFF_CKL);
  float*          candn  = ws + OFF_CANDN;
  float*          kb     = ws + OFF_KB;
  float*          xb     = ws + OFF_XB;
  float*          x2b    = ws + OFF_X2B;
  float*          lnb    = ws + OFF_LNB;
  float*          hb     = ws + OFF_HB;
  float*          xpred  = ws + OFF_XPRED;
  float*          xfin   = ws + OFF_XFIN;
  unsigned short* kbAh   = (unsigned short*)(ws + OFF_KBA);
  unsigned short* kbAl   = kbAh + 131072;
  float*          probs  = ws + OFF_PROBS;
  int*            tidxg  = (int*)(ws + OFF_TIDX);
  float*          ygath  = ws + OFF_YG;
  float*          sx     = ws + OFF_SX;
  float*          sx2    = ws + OFF_SX2;
  float*          sh     = ws + OFF_SH;
  float*          sln    = ws + OFF_SLN;
  float*          simsbuf = ws + OFF_SX;   // 128*100000 floats (overlaps enc scratch)
  float*          ev     = ws + OFF_EV;
  int*            ei     = (int*)(ws + OFF_EI);
  unsigned*       gcnt   = (unsigned*)(ws + OFF_GCNT);
  float*          gthr   = ws + OFF_GTHR;

  // 1) weight transposes + pad bf16 candk
  k_transpose<<<256, 256, 0, stream>>>(W_in, enc_W1, enc_W2, W_k, W_t1, W_t2, pred_W1, pred_W2, wt);
  k_pad_ck<<<16, 256, 0, stream>>>(ckh, ckl);

  // 2) batch encoder
  k_gemm<128,false,false,false,false><<<16, 256, 0, stream>>>(x_num, wt+WT_IN, b_in,   nullptr, xb,  nullptr, nullptr, nullptr, BATCH, 64);
  k_gemm<256,true ,false,false,false><<<16, 256, 0, stream>>>(xb,    wt+WT_E1, enc_b1, nullptr, hb,  nullptr, nullptr, nullptr, BATCH, 128);
  k_gemm<128,false,true ,false,false><<<16, 256, 0, stream>>>(hb,    wt+WT_E2, enc_b2, xb,      x2b, nullptr, nullptr, nullptr, BATCH, 256);
  k_ln<<<(BATCH+31)/32, 256, 0, stream>>>(x2b, mix_g, mix_b, lnb, BATCH);
  k_gemm<128,false,false,false,false><<<16, 256, 0, stream>>>(lnb,   wt+WT_K,  b_k,    nullptr, kb,  nullptr, nullptr, nullptr, BATCH, 128);
  k_cvt_kbA<<<512, 256, 0, stream>>>(kb, kbAh, kbAl);

  // 3) candidate encoder, 4 chunks of 25000; K-projection emits bf16 hi/lo + norms
  for (int ch = 0; ch < 4; ++ch) {
    const float* a0 = cand_x + (size_t)ch*ECH*64;
    unsigned short* ckh_c = ckh + (size_t)ch*ECH*128;
    unsigned short* ckl_c = ckl + (size_t)ch*ECH*128;
    float* cn = candn + (size_t)ch*ECH;
    int grid = (ECH + 63)/64;
    k_gemm<128,false,false,false,false><<<grid, 256, 0, stream>>>(a0,  wt+WT_IN, b_in,   nullptr, sx,  nullptr, nullptr, nullptr, ECH, 64);
    k_gemm<256,true ,false,false,false><<<grid, 256, 0, stream>>>(sx,  wt+WT_E1, enc_b1, nullptr, sh,  nullptr, nullptr, nullptr, ECH, 128);
    k_gemm<128,false,true ,false,false><<<grid, 256, 0, stream>>>(sh,  wt+WT_E2, enc_b2, sx,      sx2, nullptr, nullptr, nullptr, ECH, 256);
    k_ln<<<(ECH+31)/32, 256, 0, stream>>>(sx2, mix_g, mix_b, sln, ECH);
    k_gemm<128,false,false,true ,true ><<<grid, 256, 0, stream>>>(sln, wt+WT_K,  b_k,    nullptr, nullptr, cn, ckh_c, ckl_c, ECH, 128);
  }

  // 4) sims (MFMA) + exact top-96, 8 row chunks of 128
  for (int ch = 0; ch < 8; ++ch) {
    k_sims_mfma<<<NCPAD/64, 256, 0, stream>>>(kbAh, kbAl, ckh, ckl, candn, simsbuf, ch);
    k_sample<<<RCH, 256, 0, stream>>>(simsbuf, gthr, gcnt);
    k_emit<<<dim3(8, RCH), 256, 0, stream>>>(simsbuf, gthr, gcnt, ev, ei);
    k_final<<<RCH, 256, 0, stream>>>(ev, ei, gcnt, cand_y, probs, tidxg, ygath, ch*RCH);
  }

  // 5) t-net, 4 chunks of 256 batch rows
  for (int tc = 0; tc < 4; ++tc) {
    int p0 = tc*TP, b0 = tc*TROWS;
    k_gather_diff<<<(TP*128)/256, 256, 0, stream>>>(kb, ckh, ckl, tidxg, sln, p0);
    k_gemm<256,true ,false,false,false><<<TP/64, 256, 0, stream>>>(sln, wt+WT_T1, b_t1, nullptr, sh, nullptr, nullptr, nullptr, TP, 128);
    k_gemm<128,false,false,false,false><<<TP/64, 256, 0, stream>>>(sh,  wt+WT_T2, nullptr, nullptr, sx, nullptr, nullptr, nullptr, TP, 256);
    k_ctx<<<TROWS, 128, 0, stream>>>(probs, ygath, sx, x2b, w_le, b_le, xfin, b0);
  }

  // 6) predictor block + head
  k_ln<<<(BATCH+31)/32, 256, 0, stream>>>(xfin, pred_g, pred_b, lnb, BATCH);
  k_gemm<256,true ,false,false,false><<<16, 256, 0, stream>>>(lnb, wt+WT_P1, pred_b1, nullptr, hb,    nullptr, nullptr, nullptr, BATCH, 128);
  k_gemm<128,false,true ,false,false><<<16, 256, 0, stream>>>(hb,  wt+WT_P2, pred_b2, xfin,    xpred, nullptr, nullptr, nullptr, BATCH, 256);
  k_head<<<(BATCH+31)/32, 256, 0, stream>>>(xpred, head_g, head_b, W_head, b_head, out, BATCH);
}

// Round 7
// 1700.824 us; speedup vs baseline: 2.8163x; 1.2794x over previous
//
#include <hip/hip_runtime.h>
#include <math.h>

// ---------------- problem sizes ----------------
#define BATCH   1024
#define NCAND   100000
#define NCPAD   100032
#define DM      128
#define DB      256
#define NNUM    64
#define CTXS    96
#define TROWS   256
#define TP      (TROWS*CTXS)
#define RCH     128
#define EMCAP   8192
#define BCAP    1024

// ---------------- workspace offsets (in floats) ----------------
// bf16 hi/lo encoder weights (native [N][K] layout): Wh = shorts [0..90112), Wl follows.
// Together they span float offsets [0, 90112).
#define WB_IN       0u        // element offsets inside Wh/Wl (shorts)
#define WB_E1       8192u
#define WB_E2       40960u
#define WB_K        73728u
#define WT_T1       90112u    // fp32 transposed [K][N] for t-net / predictor
#define WT_T2       122880u
#define WT_P1       155648u
#define WT_P2       188416u
#define OFF_CKH     221184u      // 100032*128 bf16 hi
#define OFF_CKL     6623232u     // 100032*128 bf16 lo
#define OFF_CANDN   13025280u    // 100000
#define OFF_KB      13125280u    // 1024*128
#define OFF_XB      13256352u
#define OFF_X2B     13387424u    // 1024*128
#define OFF_LNB     13518496u    // 1024*128
#define OFF_HB      13649568u    // 1024*256
#define OFF_XPRED   13911712u
#define OFF_XFIN    14042784u
#define OFF_KBA     14173856u    // kbAh 131072 shorts + kbAl 131072 shorts
#define OFF_PROBS   15743648u
#define OFF_TIDX    15841952u
#define OFF_YG      15940256u
#define OFF_SX      16038560u    // t-net T2 out / sims buffer (12.8M)
#define OFF_SX2     19238560u
#define OFF_SH      22438560u    // t-net H
#define OFF_SLN     28838560u    // t-net diff / select emit buffers
#define OFF_EV      28838560u
#define OFF_EI      29887136u
#define OFF_GCNT    30935712u
#define OFF_GTHR    30935840u

typedef __attribute__((ext_vector_type(8))) short bf16x8;
typedef __attribute__((ext_vector_type(4))) float f32x4;
#define MFMA16(A,B,C) C = __builtin_amdgcn_mfma_f32_16x16x32_bf16(A, B, C, 0, 0, 0)

__device__ __forceinline__ unsigned short f2bf(float x) {
  unsigned u = __float_as_uint(x);
  unsigned r = (u + 0x7FFFu + ((u >> 16) & 1u)) >> 16;
  return (unsigned short)r;
}
__device__ __forceinline__ float bf2f(unsigned short h) {
  return __uint_as_float(((unsigned)h) << 16);
}

// ---------------- prep: fp32 transposes for t-net/predictor ----------------
__global__ void __launch_bounds__(256) k_transpose(
    const float* __restrict__ w0, const float* __restrict__ w1,
    const float* __restrict__ w2, const float* __restrict__ w3,
    float* __restrict__ dst)
{
  const float* src[4] = {w0,w1,w2,w3};
  const int nn[4]  = {256,128,256,128};
  const int kkv[4] = {128,256,128,256};
  const int off[4] = {90112,122880,155648,188416};
  int stride = gridDim.x*blockDim.x;
  int t0 = blockIdx.x*blockDim.x + threadIdx.x;
#pragma unroll
  for (int m = 0; m < 4; ++m) {
    int total = nn[m]*kkv[m];
    for (int i = t0; i < total; i += stride) {
      int k = i / nn[m];
      int n = i - k*nn[m];
      dst[off[m] + i] = src[m][n*kkv[m] + k];
    }
  }
}

// ---------------- prep: encoder weights -> bf16 hi/lo, native [N][K] ----------------
__global__ void __launch_bounds__(256) k_cvt_w(
    const float* __restrict__ w_in, const float* __restrict__ e1,
    const float* __restrict__ e2, const float* __restrict__ wk,
    unsigned short* __restrict__ Wh, unsigned short* __restrict__ Wl)
{
  const float* src[4] = {w_in, e1, e2, wk};
  const int tot[4] = {8192, 32768, 32768, 16384};
  const int off[4] = {WB_IN, WB_E1, WB_E2, WB_K};
  int stride = gridDim.x*blockDim.x;
  int t0 = blockIdx.x*blockDim.x + threadIdx.x;
#pragma unroll
  for (int m = 0; m < 4; ++m) {
    for (int i = t0; i < tot[m]; i += stride) {
      float x = src[m][i];
      unsigned short h = f2bf(x);
      Wh[off[m]+i] = h;
      Wl[off[m]+i] = f2bf(x - bf2f(h));
    }
  }
}

// zero pad rows of ckh/ckl (cands 100000..100031)
__global__ void __launch_bounds__(256) k_pad_ck(
    unsigned short* __restrict__ ckh, unsigned short* __restrict__ ckl)
{
  int i = blockIdx.x*256 + threadIdx.x;
  if (i < 4096) {
    ckh[(size_t)NCAND*128 + i] = 0;
    ckl[(size_t)NCAND*128 + i] = 0;
  }
}

// kb [1024][128] fp32 -> A-fragment-ordered bf16 hi/lo
__global__ void __launch_bounds__(256) k_cvt_kbA(
    const float* __restrict__ kb,
    unsigned short* __restrict__ kbAh, unsigned short* __restrict__ kbAl)
{
  int i = blockIdx.x*256 + threadIdx.x;
  int j = i & 7, lane = (i >> 3) & 63, s = (i >> 9) & 3, mt = (i >> 11) & 7, ch = i >> 14;
  int row = ch*128 + mt*16 + (lane & 15);
  int k = s*32 + (lane >> 4)*8 + j;
  float x = kb[(size_t)row*128 + k];
  unsigned short h = f2bf(x);
  kbAh[i] = h;
  kbAl[i] = f2bf(x - bf2f(h));
}

// ---------------- FUSED ENCODER (MFMA) ----------------
// Per block: 128 rows. x=W_in@xnum+b; H=relu(E1@x+b1); x2=x+E2@H+b2; ln=LN(x2); k=W_k@ln+bk.
// Fragments: A[m=lane&15][k=q*8+j], B[n=lane&15][k=q*8+j], C col=lane&15,row=q*4+reg.
template<bool BATCHOUT>
__global__ void __launch_bounds__(256) k_enc_fused(
    const float* __restrict__ xnum,
    const unsigned short* __restrict__ Wh, const unsigned short* __restrict__ Wl,
    const float* __restrict__ b_in, const float* __restrict__ b1,
    const float* __restrict__ b2, const float* __restrict__ mix_g,
    const float* __restrict__ mix_b, const float* __restrict__ b_k,
    unsigned short* __restrict__ ckh, unsigned short* __restrict__ ckl,
    float* __restrict__ candn,
    float* __restrict__ x2out, float* __restrict__ kout,
    int M)
{
  __shared__ __align__(16) unsigned short sXaH[16384]; // x A-frag hi [mt4? no: mt8][ks4][lane64][j8]
  __shared__ __align__(16) unsigned short sXaL[16384];
  __shared__ __align__(16) unsigned short sHb[32768];  // xnum tile (fp32) -> H bf16 A-frag -> ln hi/lo
  const int tid = threadIdx.x;
  const int wv = tid >> 6, lane = tid & 63;
  const int q = lane >> 4, n16 = lane & 15;
  const int r0 = blockIdx.x * 128;

  // ---- phase 0: stage xnum tile [128][68] fp32 into sHb
  float* xt = (float*)sHb;
  for (int i = tid; i < 2048; i += 256) {          // 128 rows x 16 float4-cols
    int r = i >> 4, c4 = i & 15;
    float4 v = {0.f,0.f,0.f,0.f};
    if (r0 + r < M) v = *(const float4*)&xnum[(size_t)(r0+r)*64 + c4*4];
    float* d = &xt[r*68 + c4*4];
    d[0]=v.x; d[1]=v.y; d[2]=v.z; d[3]=v.w;
  }
  __syncthreads();

  // ---- phase 1: x = xnum @ W_in^T + b_in    (K=64: 2 k-slices)
  float binv[8];
#pragma unroll
  for (int nt = 0; nt < 8; ++nt) binv[nt] = b_in[nt*16 + n16];
  f32x4 xc[2][8];
#pragma unroll
  for (int mi = 0; mi < 2; ++mi)
#pragma unroll
    for (int nt = 0; nt < 8; ++nt) { xc[mi][nt][0]=binv[nt]; xc[mi][nt][1]=binv[nt]; xc[mi][nt][2]=binv[nt]; xc[mi][nt][3]=binv[nt]; }

#pragma unroll
  for (int ks = 0; ks < 2; ++ks) {
    bf16x8 ah[2], al[2];
#pragma unroll
    for (int mi = 0; mi < 2; ++mi) {
      int mt = wv*2 + mi;
      const float* p = &xt[(mt*16 + n16)*68 + ks*32 + q*8];
      float4 p0 = *(const float4*)p;
      float4 p1 = *(const float4*)(p+4);
#define CV(dst_i, val) { unsigned short hh = f2bf(val); ah[mi][dst_i] = (short)hh; al[mi][dst_i] = (short)f2bf((val) - bf2f(hh)); }
      CV(0,p0.x) CV(1,p0.y) CV(2,p0.z) CV(3,p0.w) CV(4,p1.x) CV(5,p1.y) CV(6,p1.z) CV(7,p1.w)
#undef CV
    }
#pragma unroll
    for (int nt = 0; nt < 8; ++nt) {
      size_t wo = WB_IN + (size_t)(nt*16 + n16)*64 + ks*32 + q*8;
      bf16x8 bh = *(const bf16x8*)(Wh + wo);
      bf16x8 bl = *(const bf16x8*)(Wl + wo);
      MFMA16(ah[0], bh, xc[0][nt]); MFMA16(al[0], bh, xc[0][nt]); MFMA16(ah[0], bl, xc[0][nt]);
      MFMA16(ah[1], bh, xc[1][nt]); MFMA16(al[1], bh, xc[1][nt]); MFMA16(ah[1], bl, xc[1][nt]);
    }
  }

  // ---- phase 2: write x to sXa (A-frag hi/lo)
#pragma unroll
  for (int mi = 0; mi < 2; ++mi) {
    int mt = wv*2 + mi;
#pragma unroll
    for (int nt = 0; nt < 8; ++nt) {
      int col = nt*16 + n16;
      int ks2 = col >> 5, q2 = (col >> 3) & 3, j2 = col & 7;
#pragma unroll
      for (int i = 0; i < 4; ++i) {
        int idx = ((mt*4 + ks2)*64 + q2*16 + q*4 + i)*8 + j2;
        float v = xc[mi][nt][i];
        unsigned short hh = f2bf(v);
        sXaH[idx] = hh;
        sXaL[idx] = f2bf(v - bf2f(hh));
      }
    }
  }
  __syncthreads();   // sXa ready; xt consumed

  // ---- phase 3: H = relu(x @ E1^T + b1)   (K=128: 4 slices, N=256: 16 nt)
  float b1v[16];
#pragma unroll
  for (int nt = 0; nt < 16; ++nt) b1v[nt] = b1[nt*16 + n16];
  f32x4 hc[2][16];
#pragma unroll
  for (int mi = 0; mi < 2; ++mi)
#pragma unroll
    for (int nt = 0; nt < 16; ++nt) { hc[mi][nt][0]=0.f; hc[mi][nt][1]=0.f; hc[mi][nt][2]=0.f; hc[mi][nt][3]=0.f; }

#pragma unroll
  for (int ks = 0; ks < 4; ++ks) {
    bf16x8 ah[2], al[2];
#pragma unroll
    for (int mi = 0; mi < 2; ++mi) {
      int mt = wv*2 + mi;
      int base = ((mt*4 + ks)*64 + lane)*8;
      ah[mi] = *(const bf16x8*)(sXaH + base);
      al[mi] = *(const bf16x8*)(sXaL + base);
    }
#pragma unroll
    for (int nt = 0; nt < 16; ++nt) {
      size_t wo = WB_E1 + (size_t)(nt*16 + n16)*128 + ks*32 + q*8;
      bf16x8 bh = *(const bf16x8*)(Wh + wo);
      bf16x8 bl = *(const bf16x8*)(Wl + wo);
      MFMA16(ah[0], bh, hc[0][nt]); MFMA16(al[0], bh, hc[0][nt]); MFMA16(ah[0], bl, hc[0][nt]);
      MFMA16(ah[1], bh, hc[1][nt]); MFMA16(al[1], bh, hc[1][nt]); MFMA16(ah[1], bl, hc[1][nt]);
    }
  }
  __syncthreads();   // xt fully dead (was already), safe to write H into sHb

  // bias+relu, write H (single bf16) A-frag into sHb: [mt8][ks2(8)][lane][j]
#pragma unroll
  for (int mi = 0; mi < 2; ++mi) {
    int mt = wv*2 + mi;
#pragma unroll
    for (int nt = 0; nt < 16; ++nt) {
      int col = nt*16 + n16;
      int ks2 = col >> 5, q2 = (col >> 3) & 3, j2 = col & 7;
#pragma unroll
      for (int i = 0; i < 4; ++i) {
        float v = fmaxf(hc[mi][nt][i] + b1v[nt], 0.f);
        int idx = ((mt*8 + ks2)*64 + q2*16 + q*4 + i)*8 + j2;
        sHb[idx] = f2bf(v);
      }
    }
  }
  __syncthreads();

  // ---- phase 4: x2 = x + H @ E2^T + b2   (K=256: 8 slices, N=128: 8 nt)
  float b2v[8];
#pragma unroll
  for (int nt = 0; nt < 8; ++nt) b2v[nt] = b2[nt*16 + n16];
  f32x4 x2c[2][8];
#pragma unroll
  for (int mi = 0; mi < 2; ++mi)
#pragma unroll
    for (int nt = 0; nt < 8; ++nt) { x2c[mi][nt][0]=0.f; x2c[mi][nt][1]=0.f; x2c[mi][nt][2]=0.f; x2c[mi][nt][3]=0.f; }

#pragma unroll
  for (int ks = 0; ks < 8; ++ks) {
    bf16x8 ha[2];
#pragma unroll
    for (int mi = 0; mi < 2; ++mi) {
      int mt = wv*2 + mi;
      ha[mi] = *(const bf16x8*)(sHb + ((mt*8 + ks)*64 + lane)*8);
    }
#pragma unroll
    for (int nt = 0; nt < 8; ++nt) {
      size_t wo = WB_E2 + (size_t)(nt*16 + n16)*256 + ks*32 + q*8;
      bf16x8 bh = *(const bf16x8*)(Wh + wo);
      bf16x8 bl = *(const bf16x8*)(Wl + wo);
      MFMA16(ha[0], bh, x2c[0][nt]); MFMA16(ha[0], bl, x2c[0][nt]);
      MFMA16(ha[1], bh, x2c[1][nt]); MFMA16(ha[1], bl, x2c[1][nt]);
    }
  }

  // add bias + residual x (from sXa hi/lo)
#pragma unroll
  for (int mi = 0; mi < 2; ++mi) {
    int mt = wv*2 + mi;
#pragma unroll
    for (int nt = 0; nt < 8; ++nt) {
      int col = nt*16 + n16;
      int ks2 = col >> 5, q2 = (col >> 3) & 3, j2 = col & 7;
#pragma unroll
      for (int i = 0; i < 4; ++i) {
        int idx = ((mt*4 + ks2)*64 + q2*16 + q*4 + i)*8 + j2;
        float xv = bf2f(sXaH[idx]) + bf2f(sXaL[idx]);
        x2c[mi][nt][i] += b2v[nt] + xv;
      }
    }
  }

  if constexpr (BATCHOUT) {
#pragma unroll
    for (int mi = 0; mi < 2; ++mi) {
      int mt = wv*2 + mi;
#pragma unroll
      for (int nt = 0; nt < 8; ++nt) {
        int col = nt*16 + n16;
#pragma unroll
        for (int i = 0; i < 4; ++i) {
          int row = r0 + mt*16 + q*4 + i;
          if (row < M) x2out[(size_t)row*128 + col] = x2c[mi][nt][i];
        }
      }
    }
  }

  // ---- phase 5: LayerNorm over cols (in C-layout, 16-lane shuffle reduce)
  float gv[8], bvv[8];
#pragma unroll
  for (int nt = 0; nt < 8; ++nt) { gv[nt] = mix_g[nt*16 + n16]; bvv[nt] = mix_b[nt*16 + n16]; }

  float lnv[2][8][4];
#pragma unroll
  for (int mi = 0; mi < 2; ++mi) {
#pragma unroll
    for (int i = 0; i < 4; ++i) {
      float s = 0.f;
#pragma unroll
      for (int nt = 0; nt < 8; ++nt) s += x2c[mi][nt][i];
      s += __shfl_xor(s, 1); s += __shfl_xor(s, 2); s += __shfl_xor(s, 4); s += __shfl_xor(s, 8);
      float mu = s * (1.f/128.f);
      float v = 0.f;
#pragma unroll
      for (int nt = 0; nt < 8; ++nt) { float d = x2c[mi][nt][i] - mu; v += d*d; }
      v += __shfl_xor(v, 1); v += __shfl_xor(v, 2); v += __shfl_xor(v, 4); v += __shfl_xor(v, 8);
      float rs = rsqrtf(v*(1.f/128.f) + 1e-5f);
#pragma unroll
      for (int nt = 0; nt < 8; ++nt)
        lnv[mi][nt][i] = (x2c[mi][nt][i] - mu)*rs*gv[nt] + bvv[nt];
    }
  }
  __syncthreads();   // done reading sHb (H)

  // write ln hi/lo A-frags into sHb: lnh = sHb[0..16383], lnl = sHb[16384..]
  unsigned short* lnh = sHb;
  unsigned short* lnl = sHb + 16384;
#pragma unroll
  for (int mi = 0; mi < 2; ++mi) {
    int mt = wv*2 + mi;
#pragma unroll
    for (int nt = 0; nt < 8; ++nt) {
      int col = nt*16 + n16;
      int ks2 = col >> 5, q2 = (col >> 3) & 3, j2 = col & 7;
#pragma unroll
      for (int i = 0; i < 4; ++i) {
        int idx = ((mt*4 + ks2)*64 + q2*16 + q*4 + i)*8 + j2;
        float v = lnv[mi][nt][i];
        unsigned short hh = f2bf(v);
        lnh[idx] = hh;
        lnl[idx] = f2bf(v - bf2f(hh));
      }
    }
  }
  __syncthreads();

  // ---- phase 6: k = ln @ W_k^T + b_k   (K=128: 4 slices, N=128: 8 nt)
  float bkv[8];
#pragma unroll
  for (int nt = 0; nt < 8; ++nt) bkv[nt] = b_k[nt*16 + n16];
  f32x4 kc[2][8];
#pragma unroll
  for (int mi = 0; mi < 2; ++mi)
#pragma unroll
    for (int nt = 0; nt < 8; ++nt) { kc[mi][nt][0]=bkv[nt]; kc[mi][nt][1]=bkv[nt]; kc[mi][nt][2]=bkv[nt]; kc[mi][nt][3]=bkv[nt]; }

#pragma unroll
  for (int ks = 0; ks < 4; ++ks) {
    bf16x8 ah[2], al[2];
#pragma unroll
    for (int mi = 0; mi < 2; ++mi) {
      int mt = wv*2 + mi;
      int base = ((mt*4 + ks)*64 + lane)*8;
      ah[mi] = *(const bf16x8*)(lnh + base);
      al[mi] = *(const bf16x8*)(lnl + base);
    }
#pragma unroll
    for (int nt = 0; nt < 8; ++nt) {
      size_t wo = WB_K + (size_t)(nt*16 + n16)*128 + ks*32 + q*8;
      bf16x8 bh = *(const bf16x8*)(Wh + wo);
      bf16x8 bl = *(const bf16x8*)(Wl + wo);
      MFMA16(ah[0], bh, kc[0][nt]); MFMA16(al[0], bh, kc[0][nt]); MFMA16(ah[0], bl, kc[0][nt]);
      MFMA16(ah[1], bh, kc[1][nt]); MFMA16(al[1], bh, kc[1][nt]); MFMA16(ah[1], bl, kc[1][nt]);
    }
  }

  // ---- phase 7: outputs — candn (row |k|^2), ck bf16 hi/lo  (or kb fp32 for batch)
#pragma unroll
  for (int mi = 0; mi < 2; ++mi) {
    int mt = wv*2 + mi;
#pragma unroll
    for (int i = 0; i < 4; ++i) {
      int row = r0 + mt*16 + q*4 + i;
      if constexpr (!BATCHOUT) {
        float s2 = 0.f;
#pragma unroll
        for (int nt = 0; nt < 8; ++nt) { float kv = kc[mi][nt][i]; s2 += kv*kv; }
        s2 += __shfl_xor(s2, 1); s2 += __shfl_xor(s2, 2); s2 += __shfl_xor(s2, 4); s2 += __shfl_xor(s2, 8);
        if (n16 == 0 && row < M) candn[row] = s2;
      }
#pragma unroll
      for (int nt = 0; nt < 8; ++nt) {
        int col = nt*16 + n16;
        float kv = kc[mi][nt][i];
        if (row < M) {
          if constexpr (BATCHOUT) {
            kout[(size_t)row*128 + col] = kv;
          } else {
            unsigned short hh = f2bf(kv);
            ckh[(size_t)row*128 + col] = hh;
            ckl[(size_t)row*128 + col] = f2bf(kv - bf2f(hh));
          }
        }
      }
    }
  }
}

// ---------------- generic fp32 GEMM (t-net / predictor) ----------------
template<int N, bool RELU, bool RESID>
__global__ void __launch_bounds__(256) k_gemm(
    const float* __restrict__ A, const float* __restrict__ WT,
    const float* __restrict__ bias, const float* __restrict__ resid,
    float* __restrict__ C, int M, int K)
{
  constexpr int G = N/64;
  __shared__ __align__(16) float sA[64*33];
  __shared__ __align__(16) float sW[32*N];
  const int tid = threadIdx.x;
  const int r0 = blockIdx.x*64;
  const int tr = tid >> 4, tc = tid & 15;
  float acc[4][G*4];
#pragma unroll
  for (int i = 0; i < 4; ++i)
#pragma unroll
    for (int j = 0; j < G*4; ++j) acc[i][j] = 0.f;

  for (int kc = 0; kc < K; kc += 32) {
    for (int i = tid; i < 64*32; i += 256) {
      int r = i >> 5, kk = i & 31;
      int gr = r0 + r;
      sA[r*33 + kk] = (gr < M) ? A[(size_t)gr*K + kc + kk] : 0.f;
    }
    for (int i = tid; i < 32*N; i += 256) sW[i] = WT[(size_t)kc*N + i];
    __syncthreads();
    for (int kk = 0; kk < 32; ++kk) {
      float a0 = sA[(tr*4+0)*33+kk];
      float a1 = sA[(tr*4+1)*33+kk];
      float a2 = sA[(tr*4+2)*33+kk];
      float a3 = sA[(tr*4+3)*33+kk];
#pragma unroll
      for (int g = 0; g < G; ++g) {
        float4 w = *(const float4*)&sW[kk*N + g*64 + tc*4];
        acc[0][g*4+0] += a0*w.x; acc[0][g*4+1] += a0*w.y; acc[0][g*4+2] += a0*w.z; acc[0][g*4+3] += a0*w.w;
        acc[1][g*4+0] += a1*w.x; acc[1][g*4+1] += a1*w.y; acc[1][g*4+2] += a1*w.z; acc[1][g*4+3] += a1*w.w;
        acc[2][g*4+0] += a2*w.x; acc[2][g*4+1] += a2*w.y; acc[2][g*4+2] += a2*w.z; acc[2][g*4+3] += a2*w.w;
        acc[3][g*4+0] += a3*w.x; acc[3][g*4+1] += a3*w.y; acc[3][g*4+2] += a3*w.z; acc[3][g*4+3] += a3*w.w;
      }
    }
    __syncthreads();
  }

#pragma unroll
  for (int i = 0; i < 4; ++i) {
    int r = r0 + tr*4 + i;
    if (r < M) {
#pragma unroll
      for (int g = 0; g < G; ++g) {
        int col = g*64 + tc*4;
        float v0 = acc[i][g*4+0], v1 = acc[i][g*4+1], v2 = acc[i][g*4+2], v3 = acc[i][g*4+3];
        if (bias) { v0 += bias[col+0]; v1 += bias[col+1]; v2 += bias[col+2]; v3 += bias[col+3]; }
        if constexpr (RELU) { v0 = fmaxf(v0,0.f); v1 = fmaxf(v1,0.f); v2 = fmaxf(v2,0.f); v3 = fmaxf(v3,0.f); }
        if constexpr (RESID) {
          float4 rv = *(const float4*)&resid[(size_t)r*N + col];
          v0 += rv.x; v1 += rv.y; v2 += rv.z; v3 += rv.w;
        }
        float4 o4; o4.x = v0; o4.y = v1; o4.z = v2; o4.w = v3;
        *(float4*)&C[(size_t)r*N + col] = o4;
      }
    }
  }
}

// ---------------- LayerNorm (predictor prenorm) ----------------
__global__ void __launch_bounds__(256) k_ln(
    const float* __restrict__ x, const float* __restrict__ g, const float* __restrict__ b,
    float* __restrict__ o, int M)
{
  const int lane = threadIdx.x & 63, w = threadIdx.x >> 6;
  int rb = blockIdx.x*32 + w*8;
  for (int it = 0; it < 8; ++it) {
    int r = rb + it;
    if (r >= M) return;
    float a = x[(size_t)r*128 + lane];
    float c = x[(size_t)r*128 + 64 + lane];
    float s = a + c;
    for (int o2 = 32; o2; o2 >>= 1) s += __shfl_xor(s, o2);
    float mu = s * (1.f/128.f);
    float da = a - mu, dc = c - mu;
    float v = da*da + dc*dc;
    for (int o2 = 32; o2; o2 >>= 1) v += __shfl_xor(v, o2);
    float rs = rsqrtf(v*(1.f/128.f) + 1e-5f);
    o[(size_t)r*128 + lane]      = da*rs*g[lane]    + b[lane];
    o[(size_t)r*128 + 64 + lane] = dc*rs*g[lane+64] + b[lane+64];
  }
}

// ---------------- sims via MFMA ----------------
__global__ void __launch_bounds__(256) k_sims_mfma(
    const unsigned short* __restrict__ kbAh, const unsigned short* __restrict__ kbAl,
    const unsigned short* __restrict__ ckh,  const unsigned short* __restrict__ ckl,
    const float* __restrict__ candn,
    float* __restrict__ sims, int ch)
{
  const int tid = threadIdx.x;
  const int wv = tid >> 6, lane = tid & 63;
  const int c0 = blockIdx.x * 64;
  const int q = lane >> 4, n16 = lane & 15;

  f32x4 acc00 = {0.f,0.f,0.f,0.f}, acc01 = {0.f,0.f,0.f,0.f};
  f32x4 acc02 = {0.f,0.f,0.f,0.f}, acc03 = {0.f,0.f,0.f,0.f};
  f32x4 acc10 = {0.f,0.f,0.f,0.f}, acc11 = {0.f,0.f,0.f,0.f};
  f32x4 acc12 = {0.f,0.f,0.f,0.f}, acc13 = {0.f,0.f,0.f,0.f};

  const int mt0 = wv*2, mt1 = wv*2 + 1;
  const size_t a0base = (size_t)(ch*8 + mt0)*2048;
  const size_t a1base = (size_t)(ch*8 + mt1)*2048;
  const size_t b0 = (size_t)(c0 + n16)*128;
  const size_t b1 = b0 + 16*128;
  const size_t b2 = b0 + 32*128;
  const size_t b3 = b0 + 48*128;

#pragma unroll
  for (int s = 0; s < 4; ++s) {
    const size_t ao = (size_t)s*512 + (size_t)lane*8;
    bf16x8 ah0 = *(const bf16x8*)(kbAh + a0base + ao);
    bf16x8 ah1 = *(const bf16x8*)(kbAh + a1base + ao);
    bf16x8 al0 = *(const bf16x8*)(kbAl + a0base + ao);
    bf16x8 al1 = *(const bf16x8*)(kbAl + a1base + ao);
    const int ko = s*32 + q*8;
    bf16x8 bh0v = *(const bf16x8*)(ckh + b0 + ko);
    bf16x8 bh1v = *(const bf16x8*)(ckh + b1 + ko);
    bf16x8 bh2v = *(const bf16x8*)(ckh + b2 + ko);
    bf16x8 bh3v = *(const bf16x8*)(ckh + b3 + ko);
    bf16x8 bl0v = *(const bf16x8*)(ckl + b0 + ko);
    bf16x8 bl1v = *(const bf16x8*)(ckl + b1 + ko);
    bf16x8 bl2v = *(const bf16x8*)(ckl + b2 + ko);
    bf16x8 bl3v = *(const bf16x8*)(ckl + b3 + ko);

    MFMA16(ah0, bh0v, acc00); MFMA16(ah0, bh1v, acc01);
    MFMA16(ah0, bh2v, acc02); MFMA16(ah0, bh3v, acc03);
    MFMA16(ah1, bh0v, acc10); MFMA16(ah1, bh1v, acc11);
    MFMA16(ah1, bh2v, acc12); MFMA16(ah1, bh3v, acc13);

    MFMA16(al0, bh0v, acc00); MFMA16(al0, bh1v, acc01);
    MFMA16(al0, bh2v, acc02); MFMA16(al0, bh3v, acc03);
    MFMA16(al1, bh0v, acc10); MFMA16(al1, bh1v, acc11);
    MFMA16(al1, bh2v, acc12); MFMA16(al1, bh3v, acc13);

    MFMA16(ah0, bl0v, acc00); MFMA16(ah0, bl1v, acc01);
    MFMA16(ah0, bl2v, acc02); MFMA16(ah0, bl3v, acc03);
    MFMA16(ah1, bl0v, acc10); MFMA16(ah1, bl1v, acc11);
    MFMA16(ah1, bl2v, acc12); MFMA16(ah1, bl3v, acc13);
  }

  const int rb0 = mt0*16 + q*4, rb1 = mt1*16 + q*4;
#define EPI(NT, A0, A1) { \
    int col = c0 + NT*16 + n16; \
    if (col < NCAND) { \
      float cn = candn[col]; \
      sims[(size_t)(rb0+0)*NCAND + col] = 2.f*A0[0] - cn; \
      sims[(size_t)(rb0+1)*NCAND + col] = 2.f*A0[1] - cn; \
      sims[(size_t)(rb0+2)*NCAND + col] = 2.f*A0[2] - cn; \
      sims[(size_t)(rb0+3)*NCAND + col] = 2.f*A0[3] - cn; \
      sims[(size_t)(rb1+0)*NCAND + col] = 2.f*A1[0] - cn; \
      sims[(size_t)(rb1+1)*NCAND + col] = 2.f*A1[1] - cn; \
      sims[(size_t)(rb1+2)*NCAND + col] = 2.f*A1[2] - cn; \
      sims[(size_t)(rb1+3)*NCAND + col] = 2.f*A1[3] - cn; \
    } }
  EPI(0, acc00, acc10)
  EPI(1, acc01, acc11)
  EPI(2, acc02, acc12)
  EPI(3, acc03, acc13)
#undef EPI
}

// ---------------- select stage 1 ----------------
__global__ void __launch_bounds__(256) k_sample(
    const float* __restrict__ sims, float* __restrict__ gthr, unsigned* __restrict__ gcnt)
{
  __shared__ float sv[1562];
  __shared__ unsigned hist[256];
  __shared__ float wmin[4], wmax[4];
  __shared__ float s_lo, s_inv, s_w;
  const int tid = threadIdx.x, row = blockIdx.x;
  const float* S = sims + (size_t)row*NCAND;
  float lmax = -__builtin_inff(), lmin = __builtin_inff();
  for (int i = tid; i < 1562; i += 256) {
    float v = S[i*64];
    sv[i] = v;
    lmax = fmaxf(lmax, v); lmin = fminf(lmin, v);
  }
  if (tid < 256) hist[tid] = 0;
  for (int o = 32; o; o >>= 1) {
    lmax = fmaxf(lmax, __shfl_xor(lmax, o));
    lmin = fminf(lmin, __shfl_xor(lmin, o));
  }
  if ((tid & 63) == 0) { wmax[tid>>6] = lmax; wmin[tid>>6] = lmin; }
  __syncthreads();
  if (tid == 0) {
    float hi = wmax[0], lo = wmin[0];
    for (int w = 1; w < 4; ++w) { hi = fmaxf(hi, wmax[w]); lo = fminf(lo, wmin[w]); }
    float rng = hi - lo;
    s_lo = lo;
    s_inv = (rng > 0.f) ? (256.f/rng) : 0.f;
    s_w   = (rng > 0.f) ? (rng/256.f) : 0.f;
  }
  __syncthreads();
  const float lo = s_lo, inv = s_inv;
  for (int i = tid; i < 1562; i += 256) {
    int b = min(max((int)((sv[i]-lo)*inv), 0), 255);
    atomicAdd(&hist[b], 1u);
  }
  __syncthreads();
  if (tid == 0) {
    unsigned cum = 0; int b = 255;
    for (; b >= 1; --b) { if (cum + hist[b] >= 24u) break; cum += hist[b]; }
    gthr[row] = lo + (float)b * s_w;
    gcnt[row] = 0u;
  }
}

// ---------------- select stage 2 ----------------
__global__ void __launch_bounds__(256) k_emit(
    const float* __restrict__ sims, const float* __restrict__ gthr,
    unsigned* __restrict__ gcnt, float* __restrict__ ev, int* __restrict__ ei)
{
  __shared__ float lv[BCAP];
  __shared__ int   li[BCAP];
  __shared__ unsigned lcnt, lbase;
  const int tid = threadIdx.x;
  const int row = blockIdx.y;
  const int base = blockIdx.x * 12500;
  const float thr = gthr[row];
  const float* S = sims + (size_t)row*NCAND + base;
  if (tid == 0) lcnt = 0;
  __syncthreads();
  for (int i = tid; i < 3125; i += 256) {
    float4 v = *(const float4*)&S[i*4];
    if (v.x >= thr) { unsigned p = atomicAdd(&lcnt, 1u); if (p < BCAP) { lv[p] = v.x; li[p] = base + i*4 + 0; } }
    if (v.y >= thr) { unsigned p = atomicAdd(&lcnt, 1u); if (p < BCAP) { lv[p] = v.y; li[p] = base + i*4 + 1; } }
    if (v.z >= thr) { unsigned p = atomicAdd(&lcnt, 1u); if (p < BCAP) { lv[p] = v.z; li[p] = base + i*4 + 2; } }
    if (v.w >= thr) { unsigned p = atomicAdd(&lcnt, 1u); if (p < BCAP) { lv[p] = v.w; li[p] = base + i*4 + 3; } }
  }
  __syncthreads();
  const int n = (int)min(lcnt, (unsigned)BCAP);
  if (tid == 0) lbase = atomicAdd(&gcnt[row], (unsigned)n);
  __syncthreads();
  const unsigned gb = lbase;
  float* EV = ev + (size_t)row*EMCAP;
  int*   EI = ei + (size_t)row*EMCAP;
  for (int i = tid; i < n; i += 256) {
    unsigned p = gb + i;
    if (p < EMCAP) { EV[p] = lv[i]; EI[p] = li[i]; }
  }
}

// ---------------- select stage 3 ----------------
__global__ void __launch_bounds__(256) k_final(
    const float* __restrict__ ev, const int* __restrict__ ei,
    const unsigned* __restrict__ gcnt, const float* __restrict__ cand_y,
    float* __restrict__ probs, int* __restrict__ tidxg, float* __restrict__ ygath,
    int r0)
{
  __shared__ float sv[EMCAP];
  __shared__ unsigned hist[1024];
  __shared__ float tv[512]; __shared__ int ti[512];
  __shared__ float selv[96]; __shared__ int seli[96];
  __shared__ unsigned cnts[2];
  __shared__ float wv[4]; __shared__ int wp[4];
  __shared__ float wmin[4], wmax[4];
  __shared__ float s_lo, s_inv;
  __shared__ int sb_s, above_s;
  __shared__ float smax_s, ssum_s;

  const int tid = threadIdx.x, row = blockIdx.x;
  const int n = (int)min(gcnt[row], (unsigned)EMCAP);
  const float* EV = ev + (size_t)row*EMCAP;
  const int*   EI = ei + (size_t)row*EMCAP;

  if (tid < 96) { selv[tid] = -1e30f; seli[tid] = 0; }
  for (int i = tid; i < 1024; i += 256) hist[i] = 0;
  if (tid < 2) cnts[tid] = 0;

  float lmax = -__builtin_inff(), lmin = __builtin_inff();
  for (int i = tid; i < n; i += 256) {
    float v = EV[i]; sv[i] = v;
    lmax = fmaxf(lmax, v); lmin = fminf(lmin, v);
  }
  for (int o = 32; o; o >>= 1) {
    lmax = fmaxf(lmax, __shfl_xor(lmax, o));
    lmin = fminf(lmin, __shfl_xor(lmin, o));
  }
  if ((tid & 63) == 0) { wmax[tid>>6] = lmax; wmin[tid>>6] = lmin; }
  __syncthreads();
  if (tid == 0) {
    float hi = wmax[0], lo = wmin[0];
    for (int w2 = 1; w2 < 4; ++w2) { hi = fmaxf(hi, wmax[w2]); lo = fminf(lo, wmin[w2]); }
    float rng = hi - lo;
    s_lo = lo; s_inv = (rng > 0.f) ? (1024.f/rng) : 0.f;
  }
  __syncthreads();
  const float lo = s_lo, inv = s_inv;

  for (int i = tid; i < n; i += 256) {
    int b = min(max((int)((sv[i]-lo)*inv), 0), 1023);
    atomicAdd(&hist[b], 1u);
  }
  __syncthreads();
  if (tid == 0) {
    unsigned cum = 0; int b = 1023;
    for (; b >= 1; --b) { if (cum + hist[b] >= 96u) break; cum += hist[b]; }
    sb_s = b; above_s = (int)cum;
  }
  __syncthreads();
  const int sb = sb_s, above = above_s;

  for (int i = tid; i < n; i += 256) {
    float v = sv[i];
    int b = min(max((int)((v-lo)*inv), 0), 1023);
    if (b > sb) {
      unsigned p = atomicAdd(&cnts[0], 1u);
      if (p < 96u) { selv[p] = v; seli[p] = EI[i]; }
    } else if (b == sb) {
      unsigned p = atomicAdd(&cnts[1], 1u);
      if (p < 512u) { tv[p] = v; ti[p] = EI[i]; }
    }
  }
  __syncthreads();
  const int need = 96 - above;
  const int tcnt = (int)min(cnts[1], 512u);
  for (int rd = 0; rd < need; ++rd) {
    float best = -__builtin_inff(); int bp = -1;
    for (int t = tid; t < tcnt; t += 256) {
      float v = tv[t];
      if (v > best) { best = v; bp = t; }
    }
    for (int o = 32; o; o >>= 1) {
      float ob = __shfl_xor(best, o); int obp = __shfl_xor(bp, o);
      if (ob > best) { best = ob; bp = obp; }
    }
    if ((tid & 63) == 0) { wv[tid>>6] = best; wp[tid>>6] = bp; }
    __syncthreads();
    if (tid == 0) {
      float bb = wv[0]; int pp = wp[0];
      for (int w2 = 1; w2 < 4; ++w2) if (wv[w2] > bb) { bb = wv[w2]; pp = wp[w2]; }
      if (pp >= 0) { selv[above + rd] = bb; seli[above + rd] = ti[pp]; tv[pp] = -__builtin_inff(); }
    }
    __syncthreads();
  }

  if (tid == 0) {
    float m = selv[0];
    for (int i = 1; i < 96; ++i) m = fmaxf(m, selv[i]);
    smax_s = m;
  }
  __syncthreads();
  if (tid < 96) selv[tid] = expf(selv[tid] - smax_s);
  __syncthreads();
  if (tid == 0) {
    float s = 0.f;
    for (int i = 0; i < 96; ++i) s += selv[i];
    ssum_s = s;
  }
  __syncthreads();
  if (tid < 96) {
    int gr = r0 + row;
    int gi = seli[tid];
    probs[(size_t)gr*96 + tid] = selv[tid]/ssum_s;
    tidxg[(size_t)gr*96 + tid] = gi;
    ygath[(size_t)gr*96 + tid] = cand_y[gi];
  }
}

// ---------------- t-net gather ----------------
__global__ void __launch_bounds__(256) k_gather_diff(
    const float* __restrict__ kb,
    const unsigned short* __restrict__ ckh, const unsigned short* __restrict__ ckl,
    const int* __restrict__ tidxg, float* __restrict__ diff, int p0)
{
  int f = blockIdx.x*256 + threadIdx.x;
  int pl = f >> 7, d = f & 127;
  int gp = p0 + pl;
  int bb = gp / 96;
  int idx = tidxg[gp];
  float cv = bf2f(ckh[(size_t)idx*128 + d]) + bf2f(ckl[(size_t)idx*128 + d]);
  diff[f] = kb[(size_t)bb*128 + d] - cv;
}

// ---------------- context accumulation ----------------
__global__ void __launch_bounds__(128) k_ctx(
    const float* __restrict__ probs, const float* __restrict__ ygath,
    const float* __restrict__ t2, const float* __restrict__ x2b,
    const float* __restrict__ w_le, const float* __restrict__ b_le,
    float* __restrict__ xfinal, int b0)
{
  int bb = b0 + blockIdx.x;
  int d = threadIdx.x;
  float wle = w_le[d], ble = b_le[d];
  float acc = 0.f;
  int base = (bb - b0)*96;
  for (int c = 0; c < 96; ++c) {
    float p = probs[(size_t)bb*96 + c];
    float y = ygath[(size_t)bb*96 + c];
    acc += p*(y*wle + ble + t2[(size_t)(base + c)*128 + d]);
  }
  xfinal[(size_t)bb*128 + d] = x2b[(size_t)bb*128 + d] + acc;
}

// ---------------- head ----------------
__global__ void __launch_bounds__(256) k_head(
    const float* __restrict__ x, const float* __restrict__ g, const float* __restrict__ b,
    const float* __restrict__ Wh, const float* __restrict__ bh,
    float* __restrict__ out, int M)
{
  const int lane = threadIdx.x & 63, w = threadIdx.x >> 6;
  int rb = blockIdx.x*32 + w*8;
  for (int it = 0; it < 8; ++it) {
    int r = rb + it;
    if (r >= M) return;
    float a = x[(size_t)r*128 + lane];
    float c = x[(size_t)r*128 + 64 + lane];
    float s = a + c;
    for (int o = 32; o; o >>= 1) s += __shfl_xor(s, o);
    float mu = s*(1.f/128.f);
    float da = a - mu, dc = c - mu;
    float v = da*da + dc*dc;
    for (int o = 32; o; o >>= 1) v += __shfl_xor(v, o);
    float rs = rsqrtf(v*(1.f/128.f) + 1e-5f);
    float l0 = fmaxf(da*rs*g[lane]    + b[lane],    0.f);
    float l1 = fmaxf(dc*rs*g[lane+64] + b[lane+64], 0.f);
    float p0 = l0*Wh[lane]     + l1*Wh[64+lane];
    float p1 = l0*Wh[128+lane] + l1*Wh[192+lane];
    for (int o = 32; o; o >>= 1) { p0 += __shfl_xor(p0, o); p1 += __shfl_xor(p1, o); }
    if (lane == 0) { out[r*2 + 0] = p0 + bh[0]; out[r*2 + 1] = p1 + bh[1]; }
  }
}

// ---------------- launcher ----------------
extern "C" void kernel_launch(void* const* d_in, const int* in_sizes, int n_in,
                              void* d_out, int out_size, void* d_ws, size_t ws_size,
                              hipStream_t stream) {
  const float* x_num   = (const float*)d_in[0];
  const float* cand_x  = (const float*)d_in[1];
  const float* cand_y  = (const float*)d_in[2];
  const float* W_in    = (const float*)d_in[3];
  const float* b_in    = (const float*)d_in[4];
  const float* enc_W1  = (const float*)d_in[5];
  const float* enc_b1  = (const float*)d_in[6];
  const float* enc_W2  = (const float*)d_in[7];
  const float* enc_b2  = (const float*)d_in[8];
  const float* mix_g   = (const float*)d_in[9];
  const float* mix_b   = (const float*)d_in[10];
  const float* W_k     = (const float*)d_in[11];
  const float* b_k     = (const float*)d_in[12];
  const float* w_le    = (const float*)d_in[13];
  const float* b_le    = (const float*)d_in[14];
  const float* W_t1    = (const float*)d_in[15];
  const float* b_t1    = (const float*)d_in[16];
  const float* W_t2    = (const float*)d_in[17];
  const float* pred_g  = (const float*)d_in[18];
  const float* pred_b  = (const float*)d_in[19];
  const float* pred_W1 = (const float*)d_in[20];
  const float* pred_b1 = (const float*)d_in[21];
  const float* pred_W2 = (const float*)d_in[22];
  const float* pred_b2 = (const float*)d_in[23];
  const float* head_g  = (const float*)d_in[24];
  const float* head_b  = (const float*)d_in[25];
  const float* W_head  = (const float*)d_in[26];
  const float* b_head  = (const float*)d_in[27];

  float* ws  = (float*)d_ws;
  float* out = (float*)d_out;

  float*          wt     = ws;
  unsigned short* Wh     = (unsigned short*)ws;       // 90112 shorts
  unsigned short* Wl     = Wh + 90112;                // 90112 shorts (ends at float 90112)
  unsigned short* ckh    = (unsigned short*)(ws + OFF_CKH);
  unsigned short* ckl    = (unsigned short*)(ws + OFF_CKL);
  float*          candn  = ws + OFF_CANDN;
  float*          kb     = ws + OFF_KB;
  float*          x2b    = ws + OFF_X2B;
  float*          lnb    = ws + OFF_LNB;
  float*          hb     = ws + OFF_HB;
  float*          xpred  = ws + OFF_XPRED;
  float*          xfin   = ws + OFF_XFIN;
  unsigned short* kbAh   = (unsigned short*)(ws + OFF_KBA);
  unsigned short* kbAl   = kbAh + 131072;
  float*          probs  = ws + OFF_PROBS;
  int*            tidxg  = (int*)(ws + OFF_TIDX);
  float*          ygath  = ws + OFF_YG;
  float*          sx     = ws + OFF_SX;
  float*          sh     = ws + OFF_SH;
  float*          sln    = ws + OFF_SLN;
  float*          simsbuf = ws + OFF_SX;
  float*          ev     = ws + OFF_EV;
  int*            ei     = (int*)(ws + OFF_EI);
  unsigned*       gcnt   = (unsigned*)(ws + OFF_GCNT);
  float*          gthr   = ws + OFF_GTHR;

  // 1) weight prep
  k_cvt_w<<<64, 256, 0, stream>>>(W_in, enc_W1, enc_W2, W_k, Wh, Wl);
  k_transpose<<<128, 256, 0, stream>>>(W_t1, W_t2, pred_W1, pred_W2, wt);
  k_pad_ck<<<16, 256, 0, stream>>>(ckh, ckl);

  // 2) batch encoder (fused) -> x2b, kb; then kb -> A-frags
  k_enc_fused<true><<<BATCH/128, 256, 0, stream>>>(
      x_num, Wh, Wl, b_in, enc_b1, enc_b2, mix_g, mix_b, b_k,
      nullptr, nullptr, nullptr, x2b, kb, BATCH);
  k_cvt_kbA<<<512, 256, 0, stream>>>(kb, kbAh, kbAl);

  // 3) candidate encoder (fused) -> ckh/ckl, candn
  k_enc_fused<false><<<(NCAND+127)/128, 256, 0, stream>>>(
      cand_x, Wh, Wl, b_in, enc_b1, enc_b2, mix_g, mix_b, b_k,
      ckh, ckl, candn, nullptr, nullptr, NCAND);

  // 4) sims (MFMA) + exact top-96, 8 row chunks of 128
  for (int ch = 0; ch < 8; ++ch) {
    k_sims_mfma<<<NCPAD/64, 256, 0, stream>>>(kbAh, kbAl, ckh, ckl, candn, simsbuf, ch);
    k_sample<<<RCH, 256, 0, stream>>>(simsbuf, gthr, gcnt);
    k_emit<<<dim3(8, RCH), 256, 0, stream>>>(simsbuf, gthr, gcnt, ev, ei);
    k_final<<<RCH, 256, 0, stream>>>(ev, ei, gcnt, cand_y, probs, tidxg, ygath, ch*RCH);
  }

  // 5) t-net, 4 chunks of 256 batch rows
  for (int tc = 0; tc < 4; ++tc) {
    int p0 = tc*TP, b0 = tc*TROWS;
    k_gather_diff<<<(TP*128)/256, 256, 0, stream>>>(kb, ckh, ckl, tidxg, sln, p0);
    k_gemm<256,true ,false><<<TP/64, 256, 0, stream>>>(sln, wt+WT_T1, b_t1, nullptr, sh, TP, 128);
    k_gemm<128,false,false><<<TP/64, 256, 0, stream>>>(sh,  wt+WT_T2, nullptr, nullptr, sx, TP, 256);
    k_ctx<<<TROWS, 128, 0, stream>>>(probs, ygath, sx, x2b, w_le, b_le, xfin, b0);
  }

  // 6) predictor block + head
  k_ln<<<(BATCH+31)/32, 256, 0, stream>>>(xfin, pred_g, pred_b, lnb, BATCH);
  k_gemm<256,true ,false><<<16, 256, 0, stream>>>(lnb, wt+WT_P1, pred_b1, nullptr, hb,    BATCH, 128);
  k_gemm<128,false,true ><<<16, 256, 0, stream>>>(hb,  wt+WT_P2, pred_b2, xfin,    xpred, BATCH, 256);
  k_head<<<(BATCH+31)/32, 256, 0, stream>>>(xpred, head_g, head_b, W_head, b_head, out, BATCH);
}

// Round 8
// 1534.208 us; speedup vs baseline: 3.1221x; 1.1086x over previous
//
#include <hip/hip_runtime.h>
#include <math.h>

// ---------------- problem sizes ----------------
#define BATCH   1024
#define NCAND   100000
#define NCPAD   100032
#define DM      128
#define DB      256
#define NNUM    64
#define CTXS    96
#define NPAIR   (BATCH*CTXS)   // 98304
#define RCH     128
#define EMCAP   8192
#define BCAP    1024

// ---------------- workspace offsets (in floats) ----------------
// Wh/Wl: bf16 hi/lo weights, native [N][K]; short offsets below. Wh spans float
// [0,77824), Wl [77824,155648).
#define WB_IN       0u
#define WB_E1       8192u
#define WB_E2       40960u
#define WB_K        73728u
#define WB_T1       90112u
#define WB_T2       122880u
#define WT_P1       155648u    // fp32 transposed [K][N] predictor weights
#define WT_P2       188416u
#define OFF_CKH     221184u      // 100032*128 bf16 hi
#define OFF_CKL     6623232u     // 100032*128 bf16 lo
#define OFF_CANDN   13025280u    // 100000
#define OFF_KB      13125280u    // 1024*128
#define OFF_X2B     13387424u    // 1024*128
#define OFF_LNB     13518496u    // 1024*128
#define OFF_HB      13649568u    // 1024*256
#define OFF_XPRED   13911712u
#define OFF_XFIN    14042784u
#define OFF_KBA     14173856u    // kbAh 131072 shorts + kbAl 131072 shorts
#define OFF_PROBS   15743648u
#define OFF_TIDX    15841952u
#define OFF_YG      15940256u
#define OFF_SX      16038560u    // sims buffer (12.8M) / t-net t2 (12.58M)
#define OFF_EV      28838560u
#define OFF_EI      29887136u
#define OFF_GCNT    30935712u
#define OFF_GTHR    30935840u

typedef __attribute__((ext_vector_type(8))) short bf16x8;
typedef __attribute__((ext_vector_type(4))) float f32x4;
#define MFMA16(A,B,C) C = __builtin_amdgcn_mfma_f32_16x16x32_bf16(A, B, C, 0, 0, 0)

__device__ __forceinline__ unsigned short f2bf(float x) {
  unsigned u = __float_as_uint(x);
  unsigned r = (u + 0x7FFFu + ((u >> 16) & 1u)) >> 16;
  return (unsigned short)r;
}
__device__ __forceinline__ float bf2f(unsigned short h) {
  return __uint_as_float(((unsigned)h) << 16);
}

// ---------------- prep: fp32 transposes for predictor ----------------
__global__ void __launch_bounds__(256) k_transpose(
    const float* __restrict__ w0, const float* __restrict__ w1,
    float* __restrict__ dst)
{
  const float* src[2] = {w0,w1};
  const int nn[2]  = {256,128};
  const int kkv[2] = {128,256};
  const int off[2] = {155648,188416};
  int stride = gridDim.x*blockDim.x;
  int t0 = blockIdx.x*blockDim.x + threadIdx.x;
#pragma unroll
  for (int m = 0; m < 2; ++m) {
    int total = nn[m]*kkv[m];
    for (int i = t0; i < total; i += stride) {
      int k = i / nn[m];
      int n = i - k*nn[m];
      dst[off[m] + i] = src[m][n*kkv[m] + k];
    }
  }
}

// ---------------- prep: encoder + t-net weights -> bf16 hi/lo, native [N][K] ----------------
__global__ void __launch_bounds__(256) k_cvt_w(
    const float* __restrict__ w_in, const float* __restrict__ e1,
    const float* __restrict__ e2, const float* __restrict__ wk,
    const float* __restrict__ t1, const float* __restrict__ t2,
    unsigned short* __restrict__ Wh, unsigned short* __restrict__ Wl)
{
  const float* src[6] = {w_in, e1, e2, wk, t1, t2};
  const int tot[6] = {8192, 32768, 32768, 16384, 32768, 32768};
  const int off[6] = {WB_IN, WB_E1, WB_E2, WB_K, WB_T1, WB_T2};
  int stride = gridDim.x*blockDim.x;
  int t0 = blockIdx.x*blockDim.x + threadIdx.x;
#pragma unroll
  for (int m = 0; m < 6; ++m) {
    for (int i = t0; i < tot[m]; i += stride) {
      float x = src[m][i];
      unsigned short h = f2bf(x);
      Wh[off[m]+i] = h;
      Wl[off[m]+i] = f2bf(x - bf2f(h));
    }
  }
}

__global__ void __launch_bounds__(256) k_pad_ck(
    unsigned short* __restrict__ ckh, unsigned short* __restrict__ ckl)
{
  int i = blockIdx.x*256 + threadIdx.x;
  if (i < 4096) {
    ckh[(size_t)NCAND*128 + i] = 0;
    ckl[(size_t)NCAND*128 + i] = 0;
  }
}

// kb [1024][128] fp32 -> A-fragment-ordered bf16 hi/lo
__global__ void __launch_bounds__(256) k_cvt_kbA(
    const float* __restrict__ kb,
    unsigned short* __restrict__ kbAh, unsigned short* __restrict__ kbAl)
{
  int i = blockIdx.x*256 + threadIdx.x;
  int j = i & 7, lane = (i >> 3) & 63, s = (i >> 9) & 3, mt = (i >> 11) & 7, ch = i >> 14;
  int row = ch*128 + mt*16 + (lane & 15);
  int k = s*32 + (lane >> 4)*8 + j;
  float x = kb[(size_t)row*128 + k];
  unsigned short h = f2bf(x);
  kbAh[i] = h;
  kbAl[i] = f2bf(x - bf2f(h));
}

// ---------------- FUSED ENCODER v2: 64 rows/block, 64KB LDS (2 blocks/CU) ----------------
// Each of 4 waves owns mt = wv (16 rows). sXa/sHb regions are wave-private.
template<bool BATCHOUT>
__global__ void __launch_bounds__(256) k_enc_fused(
    const float* __restrict__ xnum,
    const unsigned short* __restrict__ Wh, const unsigned short* __restrict__ Wl,
    const float* __restrict__ b_in, const float* __restrict__ b1,
    const float* __restrict__ b2, const float* __restrict__ mix_g,
    const float* __restrict__ mix_b, const float* __restrict__ b_k,
    unsigned short* __restrict__ ckh, unsigned short* __restrict__ ckl,
    float* __restrict__ candn,
    float* __restrict__ x2out, float* __restrict__ kout,
    int M)
{
  __shared__ __align__(16) unsigned short sXaH[8192];  // x / ln A-frag hi [4mt][4ks][64][8]
  __shared__ __align__(16) unsigned short sXaL[8192];
  __shared__ __align__(16) unsigned short sHb[16384];  // xnum fp32 staging -> H bf16 A-frag
  const int tid = threadIdx.x;
  const int wv = tid >> 6, lane = tid & 63;
  const int q = lane >> 4, n16 = lane & 15;
  const int r0 = blockIdx.x * 64;

  // phase 0: stage xnum [64][68] fp32
  float* xt = (float*)sHb;
  for (int i = tid; i < 1024; i += 256) {
    int r = i >> 4, c4 = i & 15;
    float4 v = {0.f,0.f,0.f,0.f};
    if (r0 + r < M) v = *(const float4*)&xnum[(size_t)(r0+r)*64 + c4*4];
    float* d = &xt[r*68 + c4*4];
    d[0]=v.x; d[1]=v.y; d[2]=v.z; d[3]=v.w;
  }
  __syncthreads();

  // phase 1: x = xnum @ W_in^T + b_in  (hi/lo x, hi/lo W: 3 MFMA)
  f32x4 xc[8];
#pragma unroll
  for (int nt = 0; nt < 8; ++nt) {
    float b = b_in[nt*16 + n16];
    xc[nt][0]=b; xc[nt][1]=b; xc[nt][2]=b; xc[nt][3]=b;
  }
#pragma unroll
  for (int ks = 0; ks < 2; ++ks) {
    bf16x8 ah, al;
    {
      const float* p = &xt[(wv*16 + n16)*68 + ks*32 + q*8];
      float4 p0 = *(const float4*)p;
      float4 p1 = *(const float4*)(p+4);
#define CV(di, val) { unsigned short hh = f2bf(val); ah[di] = (short)hh; al[di] = (short)f2bf((val) - bf2f(hh)); }
      CV(0,p0.x) CV(1,p0.y) CV(2,p0.z) CV(3,p0.w) CV(4,p1.x) CV(5,p1.y) CV(6,p1.z) CV(7,p1.w)
#undef CV
    }
#pragma unroll
    for (int nt = 0; nt < 8; ++nt) {
      size_t wo = WB_IN + (size_t)(nt*16 + n16)*64 + ks*32 + q*8;
      bf16x8 bh = *(const bf16x8*)(Wh + wo);
      bf16x8 bl = *(const bf16x8*)(Wl + wo);
      MFMA16(ah, bh, xc[nt]); MFMA16(al, bh, xc[nt]); MFMA16(ah, bl, xc[nt]);
    }
  }

  // phase 2: x -> sXa A-frags (wave-private region mt=wv)
#pragma unroll
  for (int nt = 0; nt < 8; ++nt) {
    int col = nt*16 + n16;
    int ks2 = col >> 5, q2 = (col >> 3) & 3, j2 = col & 7;
#pragma unroll
    for (int i = 0; i < 4; ++i) {
      int idx = ((wv*4 + ks2)*64 + q2*16 + q*4 + i)*8 + j2;
      float v = xc[nt][i];
      unsigned short hh = f2bf(v);
      sXaH[idx] = hh;
      sXaL[idx] = f2bf(v - bf2f(hh));
    }
  }
  __syncthreads();   // all waves done with xt before H overwrites sHb

  // phase 3: H = relu(x @ E1^T + b1)
  f32x4 hc[16];
#pragma unroll
  for (int nt = 0; nt < 16; ++nt) { hc[nt][0]=0.f; hc[nt][1]=0.f; hc[nt][2]=0.f; hc[nt][3]=0.f; }
#pragma unroll
  for (int ks = 0; ks < 4; ++ks) {
    int base = ((wv*4 + ks)*64 + lane)*8;
    bf16x8 ah = *(const bf16x8*)(sXaH + base);
    bf16x8 al = *(const bf16x8*)(sXaL + base);
#pragma unroll
    for (int nt = 0; nt < 16; ++nt) {
      size_t wo = WB_E1 + (size_t)(nt*16 + n16)*128 + ks*32 + q*8;
      bf16x8 bh = *(const bf16x8*)(Wh + wo);
      bf16x8 bl = *(const bf16x8*)(Wl + wo);
      MFMA16(ah, bh, hc[nt]); MFMA16(al, bh, hc[nt]); MFMA16(ah, bl, hc[nt]);
    }
  }
  // H -> sHb A-frag (single bf16, wave-private)
#pragma unroll
  for (int nt = 0; nt < 16; ++nt) {
    float b = b1[nt*16 + n16];
    int col = nt*16 + n16;
    int ks2 = col >> 5, q2 = (col >> 3) & 3, j2 = col & 7;
#pragma unroll
    for (int i = 0; i < 4; ++i) {
      float v = fmaxf(hc[nt][i] + b, 0.f);
      sHb[((wv*8 + ks2)*64 + q2*16 + q*4 + i)*8 + j2] = f2bf(v);
    }
  }

  // phase 4: x2 = x + H @ E2^T + b2  (H single, W hi/lo: 2 MFMA)
  f32x4 x2c[8];
#pragma unroll
  for (int nt = 0; nt < 8; ++nt) { x2c[nt][0]=0.f; x2c[nt][1]=0.f; x2c[nt][2]=0.f; x2c[nt][3]=0.f; }
#pragma unroll
  for (int ks = 0; ks < 8; ++ks) {
    bf16x8 ha = *(const bf16x8*)(sHb + ((wv*8 + ks)*64 + lane)*8);
#pragma unroll
    for (int nt = 0; nt < 8; ++nt) {
      size_t wo = WB_E2 + (size_t)(nt*16 + n16)*256 + ks*32 + q*8;
      bf16x8 bh = *(const bf16x8*)(Wh + wo);
      bf16x8 bl = *(const bf16x8*)(Wl + wo);
      MFMA16(ha, bh, x2c[nt]); MFMA16(ha, bl, x2c[nt]);
    }
  }
#pragma unroll
  for (int nt = 0; nt < 8; ++nt) {
    float b = b2[nt*16 + n16];
    int col = nt*16 + n16;
    int ks2 = col >> 5, q2 = (col >> 3) & 3, j2 = col & 7;
#pragma unroll
    for (int i = 0; i < 4; ++i) {
      int idx = ((wv*4 + ks2)*64 + q2*16 + q*4 + i)*8 + j2;
      x2c[nt][i] += b + bf2f(sXaH[idx]) + bf2f(sXaL[idx]);
    }
  }
  if constexpr (BATCHOUT) {
#pragma unroll
    for (int nt = 0; nt < 8; ++nt) {
      int col = nt*16 + n16;
#pragma unroll
      for (int i = 0; i < 4; ++i) {
        int row = r0 + wv*16 + q*4 + i;
        if (row < M) x2out[(size_t)row*128 + col] = x2c[nt][i];
      }
    }
  }

  // phase 5: LayerNorm (16-lane shuffle reduce per row)
  float lnv[8][4];
#pragma unroll
  for (int i = 0; i < 4; ++i) {
    float s = 0.f;
#pragma unroll
    for (int nt = 0; nt < 8; ++nt) s += x2c[nt][i];
    s += __shfl_xor(s, 1); s += __shfl_xor(s, 2); s += __shfl_xor(s, 4); s += __shfl_xor(s, 8);
    float mu = s * (1.f/128.f);
    float v = 0.f;
#pragma unroll
    for (int nt = 0; nt < 8; ++nt) { float d = x2c[nt][i] - mu; v += d*d; }
    v += __shfl_xor(v, 1); v += __shfl_xor(v, 2); v += __shfl_xor(v, 4); v += __shfl_xor(v, 8);
    float rs = rsqrtf(v*(1.f/128.f) + 1e-5f);
#pragma unroll
    for (int nt = 0; nt < 8; ++nt)
      lnv[nt][i] = (x2c[nt][i] - mu)*rs*mix_g[nt*16 + n16] + mix_b[nt*16 + n16];
  }

  // ln -> sXa (reuse, wave-private; phase-4 reads are done in program order)
#pragma unroll
  for (int nt = 0; nt < 8; ++nt) {
    int col = nt*16 + n16;
    int ks2 = col >> 5, q2 = (col >> 3) & 3, j2 = col & 7;
#pragma unroll
    for (int i = 0; i < 4; ++i) {
      int idx = ((wv*4 + ks2)*64 + q2*16 + q*4 + i)*8 + j2;
      float v = lnv[nt][i];
      unsigned short hh = f2bf(v);
      sXaH[idx] = hh;
      sXaL[idx] = f2bf(v - bf2f(hh));
    }
  }

  // phase 6: k = ln @ W_k^T + b_k
  f32x4 kc[8];
#pragma unroll
  for (int nt = 0; nt < 8; ++nt) {
    float b = b_k[nt*16 + n16];
    kc[nt][0]=b; kc[nt][1]=b; kc[nt][2]=b; kc[nt][3]=b;
  }
#pragma unroll
  for (int ks = 0; ks < 4; ++ks) {
    int base = ((wv*4 + ks)*64 + lane)*8;
    bf16x8 ah = *(const bf16x8*)(sXaH + base);
    bf16x8 al = *(const bf16x8*)(sXaL + base);
#pragma unroll
    for (int nt = 0; nt < 8; ++nt) {
      size_t wo = WB_K + (size_t)(nt*16 + n16)*128 + ks*32 + q*8;
      bf16x8 bh = *(const bf16x8*)(Wh + wo);
      bf16x8 bl = *(const bf16x8*)(Wl + wo);
      MFMA16(ah, bh, kc[nt]); MFMA16(al, bh, kc[nt]); MFMA16(ah, bl, kc[nt]);
    }
  }

  // phase 7: outputs
#pragma unroll
  for (int i = 0; i < 4; ++i) {
    int row = r0 + wv*16 + q*4 + i;
    if constexpr (!BATCHOUT) {
      float s2 = 0.f;
#pragma unroll
      for (int nt = 0; nt < 8; ++nt) { float kv = kc[nt][i]; s2 += kv*kv; }
      s2 += __shfl_xor(s2, 1); s2 += __shfl_xor(s2, 2); s2 += __shfl_xor(s2, 4); s2 += __shfl_xor(s2, 8);
      if (n16 == 0 && row < M) candn[row] = s2;
    }
#pragma unroll
    for (int nt = 0; nt < 8; ++nt) {
      int col = nt*16 + n16;
      float kv = kc[nt][i];
      if (row < M) {
        if constexpr (BATCHOUT) {
          kout[(size_t)row*128 + col] = kv;
        } else {
          unsigned short hh = f2bf(kv);
          ckh[(size_t)row*128 + col] = hh;
          ckl[(size_t)row*128 + col] = f2bf(kv - bf2f(hh));
        }
      }
    }
  }
}

// ---------------- FUSED T-NET (MFMA): 64 pairs/block, 48KB LDS ----------------
// diff = kb[b] - ck[idx] (single bf16 A-frag); H = relu(diff@T1^T+b1) (single bf16);
// t2 = H@T2^T (fp32 out). Weights hi/lo.
__global__ void __launch_bounds__(256) k_tnet(
    const float* __restrict__ kb,
    const unsigned short* __restrict__ ckh, const unsigned short* __restrict__ ckl,
    const int* __restrict__ tidxg,
    const unsigned short* __restrict__ Wh, const unsigned short* __restrict__ Wl,
    const float* __restrict__ b_t1, float* __restrict__ t2out)
{
  __shared__ __align__(16) unsigned short sD[8192];   // diff A-frag [4mt][4ks][64][8]
  __shared__ __align__(16) unsigned short sH[16384];  // H A-frag [4mt][8ks][64][8]
  const int tid = threadIdx.x;
  const int wv = tid >> 6, lane = tid & 63;
  const int q = lane >> 4, n16 = lane & 15;
  const int p0 = blockIdx.x * 64;

  // gather + diff directly into A-frag order (16B LDS stores, no conflicts)
  for (int li = tid; li < 1024; li += 256) {
    int fr = li >> 6;              // mt*4+ks
    int sl = li & 63;              // qq*16+m
    int mt = fr >> 2, ks = fr & 3;
    int qq = sl >> 4, m = sl & 15;
    int p  = mt*16 + m;
    int gp = p0 + p;
    int d  = ks*32 + qq*8;
    int idx = tidxg[gp];
    int bb  = gp / 96;
    bf16x8 h8 = *(const bf16x8*)(ckh + (size_t)idx*128 + d);
    bf16x8 l8 = *(const bf16x8*)(ckl + (size_t)idx*128 + d);
    float4 k0 = *(const float4*)&kb[(size_t)bb*128 + d];
    float4 k1 = *(const float4*)&kb[(size_t)bb*128 + d + 4];
    bf16x8 df;
    df[0] = (short)f2bf(k0.x - (bf2f(h8[0]) + bf2f(l8[0])));
    df[1] = (short)f2bf(k0.y - (bf2f(h8[1]) + bf2f(l8[1])));
    df[2] = (short)f2bf(k0.z - (bf2f(h8[2]) + bf2f(l8[2])));
    df[3] = (short)f2bf(k0.w - (bf2f(h8[3]) + bf2f(l8[3])));
    df[4] = (short)f2bf(k1.x - (bf2f(h8[4]) + bf2f(l8[4])));
    df[5] = (short)f2bf(k1.y - (bf2f(h8[5]) + bf2f(l8[5])));
    df[6] = (short)f2bf(k1.z - (bf2f(h8[6]) + bf2f(l8[6])));
    df[7] = (short)f2bf(k1.w - (bf2f(h8[7]) + bf2f(l8[7])));
    *(bf16x8*)(sD + li*8) = df;
  }
  __syncthreads();

  // T1
  f32x4 hc[16];
#pragma unroll
  for (int nt = 0; nt < 16; ++nt) { hc[nt][0]=0.f; hc[nt][1]=0.f; hc[nt][2]=0.f; hc[nt][3]=0.f; }
#pragma unroll
  for (int ks = 0; ks < 4; ++ks) {
    bf16x8 ad = *(const bf16x8*)(sD + ((wv*4 + ks)*64 + lane)*8);
#pragma unroll
    for (int nt = 0; nt < 16; ++nt) {
      size_t wo = WB_T1 + (size_t)(nt*16 + n16)*128 + ks*32 + q*8;
      bf16x8 bh = *(const bf16x8*)(Wh + wo);
      bf16x8 bl = *(const bf16x8*)(Wl + wo);
      MFMA16(ad, bh, hc[nt]); MFMA16(ad, bl, hc[nt]);
    }
  }
  // bias + relu -> sH (wave-private)
#pragma unroll
  for (int nt = 0; nt < 16; ++nt) {
    float b = b_t1[nt*16 + n16];
    int col = nt*16 + n16;
    int ks2 = col >> 5, q2 = (col >> 3) & 3, j2 = col & 7;
#pragma unroll
    for (int i = 0; i < 4; ++i) {
      float v = fmaxf(hc[nt][i] + b, 0.f);
      sH[((wv*8 + ks2)*64 + q2*16 + q*4 + i)*8 + j2] = f2bf(v);
    }
  }

  // T2
  f32x4 tc[8];
#pragma unroll
  for (int nt = 0; nt < 8; ++nt) { tc[nt][0]=0.f; tc[nt][1]=0.f; tc[nt][2]=0.f; tc[nt][3]=0.f; }
#pragma unroll
  for (int ks = 0; ks < 8; ++ks) {
    bf16x8 ha = *(const bf16x8*)(sH + ((wv*8 + ks)*64 + lane)*8);
#pragma unroll
    for (int nt = 0; nt < 8; ++nt) {
      size_t wo = WB_T2 + (size_t)(nt*16 + n16)*256 + ks*32 + q*8;
      bf16x8 bh = *(const bf16x8*)(Wh + wo);
      bf16x8 bl = *(const bf16x8*)(Wl + wo);
      MFMA16(ha, bh, tc[nt]); MFMA16(ha, bl, tc[nt]);
    }
  }
#pragma unroll
  for (int nt = 0; nt < 8; ++nt) {
    int col = nt*16 + n16;
#pragma unroll
    for (int i = 0; i < 4; ++i) {
      int pr = p0 + wv*16 + q*4 + i;
      t2out[(size_t)pr*128 + col] = tc[nt][i];
    }
  }
}

// ---------------- generic fp32 GEMM (predictor) ----------------
template<int N, bool RELU, bool RESID>
__global__ void __launch_bounds__(256) k_gemm(
    const float* __restrict__ A, const float* __restrict__ WT,
    const float* __restrict__ bias, const float* __restrict__ resid,
    float* __restrict__ C, int M, int K)
{
  constexpr int G = N/64;
  __shared__ __align__(16) float sA[64*33];
  __shared__ __align__(16) float sW[32*N];
  const int tid = threadIdx.x;
  const int r0 = blockIdx.x*64;
  const int tr = tid >> 4, tc = tid & 15;
  float acc[4][G*4];
#pragma unroll
  for (int i = 0; i < 4; ++i)
#pragma unroll
    for (int j = 0; j < G*4; ++j) acc[i][j] = 0.f;

  for (int kc = 0; kc < K; kc += 32) {
    for (int i = tid; i < 64*32; i += 256) {
      int r = i >> 5, kk = i & 31;
      int gr = r0 + r;
      sA[r*33 + kk] = (gr < M) ? A[(size_t)gr*K + kc + kk] : 0.f;
    }
    for (int i = tid; i < 32*N; i += 256) sW[i] = WT[(size_t)kc*N + i];
    __syncthreads();
    for (int kk = 0; kk < 32; ++kk) {
      float a0 = sA[(tr*4+0)*33+kk];
      float a1 = sA[(tr*4+1)*33+kk];
      float a2 = sA[(tr*4+2)*33+kk];
      float a3 = sA[(tr*4+3)*33+kk];
#pragma unroll
      for (int g = 0; g < G; ++g) {
        float4 w = *(const float4*)&sW[kk*N + g*64 + tc*4];
        acc[0][g*4+0] += a0*w.x; acc[0][g*4+1] += a0*w.y; acc[0][g*4+2] += a0*w.z; acc[0][g*4+3] += a0*w.w;
        acc[1][g*4+0] += a1*w.x; acc[1][g*4+1] += a1*w.y; acc[1][g*4+2] += a1*w.z; acc[1][g*4+3] += a1*w.w;
        acc[2][g*4+0] += a2*w.x; acc[2][g*4+1] += a2*w.y; acc[2][g*4+2] += a2*w.z; acc[2][g*4+3] += a2*w.w;
        acc[3][g*4+0] += a3*w.x; acc[3][g*4+1] += a3*w.y; acc[3][g*4+2] += a3*w.z; acc[3][g*4+3] += a3*w.w;
      }
    }
    __syncthreads();
  }

#pragma unroll
  for (int i = 0; i < 4; ++i) {
    int r = r0 + tr*4 + i;
    if (r < M) {
#pragma unroll
      for (int g = 0; g < G; ++g) {
        int col = g*64 + tc*4;
        float v0 = acc[i][g*4+0], v1 = acc[i][g*4+1], v2 = acc[i][g*4+2], v3 = acc[i][g*4+3];
        if (bias) { v0 += bias[col+0]; v1 += bias[col+1]; v2 += bias[col+2]; v3 += bias[col+3]; }
        if constexpr (RELU) { v0 = fmaxf(v0,0.f); v1 = fmaxf(v1,0.f); v2 = fmaxf(v2,0.f); v3 = fmaxf(v3,0.f); }
        if constexpr (RESID) {
          float4 rv = *(const float4*)&resid[(size_t)r*N + col];
          v0 += rv.x; v1 += rv.y; v2 += rv.z; v3 += rv.w;
        }
        float4 o4; o4.x = v0; o4.y = v1; o4.z = v2; o4.w = v3;
        *(float4*)&C[(size_t)r*N + col] = o4;
      }
    }
  }
}

// ---------------- LayerNorm (predictor prenorm) ----------------
__global__ void __launch_bounds__(256) k_ln(
    const float* __restrict__ x, const float* __restrict__ g, const float* __restrict__ b,
    float* __restrict__ o, int M)
{
  const int lane = threadIdx.x & 63, w = threadIdx.x >> 6;
  int rb = blockIdx.x*32 + w*8;
  for (int it = 0; it < 8; ++it) {
    int r = rb + it;
    if (r >= M) return;
    float a = x[(size_t)r*128 + lane];
    float c = x[(size_t)r*128 + 64 + lane];
    float s = a + c;
    for (int o2 = 32; o2; o2 >>= 1) s += __shfl_xor(s, o2);
    float mu = s * (1.f/128.f);
    float da = a - mu, dc = c - mu;
    float v = da*da + dc*dc;
    for (int o2 = 32; o2; o2 >>= 1) v += __shfl_xor(v, o2);
    float rs = rsqrtf(v*(1.f/128.f) + 1e-5f);
    o[(size_t)r*128 + lane]      = da*rs*g[lane]    + b[lane];
    o[(size_t)r*128 + 64 + lane] = dc*rs*g[lane+64] + b[lane+64];
  }
}

// ---------------- sims via MFMA ----------------
__global__ void __launch_bounds__(256) k_sims_mfma(
    const unsigned short* __restrict__ kbAh, const unsigned short* __restrict__ kbAl,
    const unsigned short* __restrict__ ckh,  const unsigned short* __restrict__ ckl,
    const float* __restrict__ candn,
    float* __restrict__ sims, int ch)
{
  const int tid = threadIdx.x;
  const int wv = tid >> 6, lane = tid & 63;
  const int c0 = blockIdx.x * 64;
  const int q = lane >> 4, n16 = lane & 15;

  f32x4 acc00 = {0.f,0.f,0.f,0.f}, acc01 = {0.f,0.f,0.f,0.f};
  f32x4 acc02 = {0.f,0.f,0.f,0.f}, acc03 = {0.f,0.f,0.f,0.f};
  f32x4 acc10 = {0.f,0.f,0.f,0.f}, acc11 = {0.f,0.f,0.f,0.f};
  f32x4 acc12 = {0.f,0.f,0.f,0.f}, acc13 = {0.f,0.f,0.f,0.f};

  const int mt0 = wv*2, mt1 = wv*2 + 1;
  const size_t a0base = (size_t)(ch*8 + mt0)*2048;
  const size_t a1base = (size_t)(ch*8 + mt1)*2048;
  const size_t b0 = (size_t)(c0 + n16)*128;
  const size_t b1 = b0 + 16*128;
  const size_t b2 = b0 + 32*128;
  const size_t b3 = b0 + 48*128;

#pragma unroll
  for (int s = 0; s < 4; ++s) {
    const size_t ao = (size_t)s*512 + (size_t)lane*8;
    bf16x8 ah0 = *(const bf16x8*)(kbAh + a0base + ao);
    bf16x8 ah1 = *(const bf16x8*)(kbAh + a1base + ao);
    bf16x8 al0 = *(const bf16x8*)(kbAl + a0base + ao);
    bf16x8 al1 = *(const bf16x8*)(kbAl + a1base + ao);
    const int ko = s*32 + q*8;
    bf16x8 bh0v = *(const bf16x8*)(ckh + b0 + ko);
    bf16x8 bh1v = *(const bf16x8*)(ckh + b1 + ko);
    bf16x8 bh2v = *(const bf16x8*)(ckh + b2 + ko);
    bf16x8 bh3v = *(const bf16x8*)(ckh + b3 + ko);
    bf16x8 bl0v = *(const bf16x8*)(ckl + b0 + ko);
    bf16x8 bl1v = *(const bf16x8*)(ckl + b1 + ko);
    bf16x8 bl2v = *(const bf16x8*)(ckl + b2 + ko);
    bf16x8 bl3v = *(const bf16x8*)(ckl + b3 + ko);

    MFMA16(ah0, bh0v, acc00); MFMA16(ah0, bh1v, acc01);
    MFMA16(ah0, bh2v, acc02); MFMA16(ah0, bh3v, acc03);
    MFMA16(ah1, bh0v, acc10); MFMA16(ah1, bh1v, acc11);
    MFMA16(ah1, bh2v, acc12); MFMA16(ah1, bh3v, acc13);

    MFMA16(al0, bh0v, acc00); MFMA16(al0, bh1v, acc01);
    MFMA16(al0, bh2v, acc02); MFMA16(al0, bh3v, acc03);
    MFMA16(al1, bh0v, acc10); MFMA16(al1, bh1v, acc11);
    MFMA16(al1, bh2v, acc12); MFMA16(al1, bh3v, acc13);

    MFMA16(ah0, bl0v, acc00); MFMA16(ah0, bl1v, acc01);
    MFMA16(ah0, bl2v, acc02); MFMA16(ah0, bl3v, acc03);
    MFMA16(ah1, bl0v, acc10); MFMA16(ah1, bl1v, acc11);
    MFMA16(ah1, bl2v, acc12); MFMA16(ah1, bl3v, acc13);
  }

  const int rb0 = mt0*16 + q*4, rb1 = mt1*16 + q*4;
#define EPI(NT, A0, A1) { \
    int col = c0 + NT*16 + n16; \
    if (col < NCAND) { \
      float cn = candn[col]; \
      sims[(size_t)(rb0+0)*NCAND + col] = 2.f*A0[0] - cn; \
      sims[(size_t)(rb0+1)*NCAND + col] = 2.f*A0[1] - cn; \
      sims[(size_t)(rb0+2)*NCAND + col] = 2.f*A0[2] - cn; \
      sims[(size_t)(rb0+3)*NCAND + col] = 2.f*A0[3] - cn; \
      sims[(size_t)(rb1+0)*NCAND + col] = 2.f*A1[0] - cn; \
      sims[(size_t)(rb1+1)*NCAND + col] = 2.f*A1[1] - cn; \
      sims[(size_t)(rb1+2)*NCAND + col] = 2.f*A1[2] - cn; \
      sims[(size_t)(rb1+3)*NCAND + col] = 2.f*A1[3] - cn; \
    } }
  EPI(0, acc00, acc10)
  EPI(1, acc01, acc11)
  EPI(2, acc02, acc12)
  EPI(3, acc03, acc13)
#undef EPI
}

// ---------------- select stage 1 ----------------
__global__ void __launch_bounds__(256) k_sample(
    const float* __restrict__ sims, float* __restrict__ gthr, unsigned* __restrict__ gcnt)
{
  __shared__ float sv[1562];
  __shared__ unsigned hist[256];
  __shared__ float wmin[4], wmax[4];
  __shared__ float s_lo, s_inv, s_w;
  const int tid = threadIdx.x, row = blockIdx.x;
  const float* S = sims + (size_t)row*NCAND;
  float lmax = -__builtin_inff(), lmin = __builtin_inff();
  for (int i = tid; i < 1562; i += 256) {
    float v = S[i*64];
    sv[i] = v;
    lmax = fmaxf(lmax, v); lmin = fminf(lmin, v);
  }
  if (tid < 256) hist[tid] = 0;
  for (int o = 32; o; o >>= 1) {
    lmax = fmaxf(lmax, __shfl_xor(lmax, o));
    lmin = fminf(lmin, __shfl_xor(lmin, o));
  }
  if ((tid & 63) == 0) { wmax[tid>>6] = lmax; wmin[tid>>6] = lmin; }
  __syncthreads();
  if (tid == 0) {
    float hi = wmax[0], lo = wmin[0];
    for (int w = 1; w < 4; ++w) { hi = fmaxf(hi, wmax[w]); lo = fminf(lo, wmin[w]); }
    float rng = hi - lo;
    s_lo = lo;
    s_inv = (rng > 0.f) ? (256.f/rng) : 0.f;
    s_w   = (rng > 0.f) ? (rng/256.f) : 0.f;
  }
  __syncthreads();
  const float lo = s_lo, inv = s_inv;
  for (int i = tid; i < 1562; i += 256) {
    int b = min(max((int)((sv[i]-lo)*inv), 0), 255);
    atomicAdd(&hist[b], 1u);
  }
  __syncthreads();
  if (tid == 0) {
    unsigned cum = 0; int b = 255;
    for (; b >= 1; --b) { if (cum + hist[b] >= 24u) break; cum += hist[b]; }
    gthr[row] = lo + (float)b * s_w;
    gcnt[row] = 0u;
  }
}

// ---------------- select stage 2 ----------------
__global__ void __launch_bounds__(256) k_emit(
    const float* __restrict__ sims, const float* __restrict__ gthr,
    unsigned* __restrict__ gcnt, float* __restrict__ ev, int* __restrict__ ei)
{
  __shared__ float lv[BCAP];
  __shared__ int   li[BCAP];
  __shared__ unsigned lcnt, lbase;
  const int tid = threadIdx.x;
  const int row = blockIdx.y;
  const int base = blockIdx.x * 12500;
  const float thr = gthr[row];
  const float* S = sims + (size_t)row*NCAND + base;
  if (tid == 0) lcnt = 0;
  __syncthreads();
  for (int i = tid; i < 3125; i += 256) {
    float4 v = *(const float4*)&S[i*4];
    if (v.x >= thr) { unsigned p = atomicAdd(&lcnt, 1u); if (p < BCAP) { lv[p] = v.x; li[p] = base + i*4 + 0; } }
    if (v.y >= thr) { unsigned p = atomicAdd(&lcnt, 1u); if (p < BCAP) { lv[p] = v.y; li[p] = base + i*4 + 1; } }
    if (v.z >= thr) { unsigned p = atomicAdd(&lcnt, 1u); if (p < BCAP) { lv[p] = v.z; li[p] = base + i*4 + 2; } }
    if (v.w >= thr) { unsigned p = atomicAdd(&lcnt, 1u); if (p < BCAP) { lv[p] = v.w; li[p] = base + i*4 + 3; } }
  }
  __syncthreads();
  const int n = (int)min(lcnt, (unsigned)BCAP);
  if (tid == 0) lbase = atomicAdd(&gcnt[row], (unsigned)n);
  __syncthreads();
  const unsigned gb = lbase;
  float* EV = ev + (size_t)row*EMCAP;
  int*   EI = ei + (size_t)row*EMCAP;
  for (int i = tid; i < n; i += 256) {
    unsigned p = gb + i;
    if (p < EMCAP) { EV[p] = lv[i]; EI[p] = li[i]; }
  }
}

// ---------------- select stage 3 ----------------
__global__ void __launch_bounds__(256) k_final(
    const float* __restrict__ ev, const int* __restrict__ ei,
    const unsigned* __restrict__ gcnt, const float* __restrict__ cand_y,
    float* __restrict__ probs, int* __restrict__ tidxg, float* __restrict__ ygath,
    int r0)
{
  __shared__ float sv[EMCAP];
  __shared__ unsigned hist[1024];
  __shared__ float tv[512]; __shared__ int ti[512];
  __shared__ float selv[96]; __shared__ int seli[96];
  __shared__ unsigned cnts[2];
  __shared__ float wv[4]; __shared__ int wp[4];
  __shared__ float wmin[4], wmax[4];
  __shared__ float s_lo, s_inv;
  __shared__ int sb_s, above_s;
  __shared__ float smax_s, ssum_s;

  const int tid = threadIdx.x, row = blockIdx.x;
  const int n = (int)min(gcnt[row], (unsigned)EMCAP);
  const float* EV = ev + (size_t)row*EMCAP;
  const int*   EI = ei + (size_t)row*EMCAP;

  if (tid < 96) { selv[tid] = -1e30f; seli[tid] = 0; }
  for (int i = tid; i < 1024; i += 256) hist[i] = 0;
  if (tid < 2) cnts[tid] = 0;

  float lmax = -__builtin_inff(), lmin = __builtin_inff();
  for (int i = tid; i < n; i += 256) {
    float v = EV[i]; sv[i] = v;
    lmax = fmaxf(lmax, v); lmin = fminf(lmin, v);
  }
  for (int o = 32; o; o >>= 1) {
    lmax = fmaxf(lmax, __shfl_xor(lmax, o));
    lmin = fminf(lmin, __shfl_xor(lmin, o));
  }
  if ((tid & 63) == 0) { wmax[tid>>6] = lmax; wmin[tid>>6] = lmin; }
  __syncthreads();
  if (tid == 0) {
    float hi = wmax[0], lo = wmin[0];
    for (int w2 = 1; w2 < 4; ++w2) { hi = fmaxf(hi, wmax[w2]); lo = fminf(lo, wmin[w2]); }
    float rng = hi - lo;
    s_lo = lo; s_inv = (rng > 0.f) ? (1024.f/rng) : 0.f;
  }
  __syncthreads();
  const float lo = s_lo, inv = s_inv;

  for (int i = tid; i < n; i += 256) {
    int b = min(max((int)((sv[i]-lo)*inv), 0), 1023);
    atomicAdd(&hist[b], 1u);
  }
  __syncthreads();
  if (tid == 0) {
    unsigned cum = 0; int b = 1023;
    for (; b >= 1; --b) { if (cum + hist[b] >= 96u) break; cum += hist[b]; }
    sb_s = b; above_s = (int)cum;
  }
  __syncthreads();
  const int sb = sb_s, above = above_s;

  for (int i = tid; i < n; i += 256) {
    float v = sv[i];
    int b = min(max((int)((v-lo)*inv), 0), 1023);
    if (b > sb) {
      unsigned p = atomicAdd(&cnts[0], 1u);
      if (p < 96u) { selv[p] = v; seli[p] = EI[i]; }
    } else if (b == sb) {
      unsigned p = atomicAdd(&cnts[1], 1u);
      if (p < 512u) { tv[p] = v; ti[p] = EI[i]; }
    }
  }
  __syncthreads();
  const int need = 96 - above;
  const int tcnt = (int)min(cnts[1], 512u);
  for (int rd = 0; rd < need; ++rd) {
    float best = -__builtin_inff(); int bp = -1;
    for (int t = tid; t < tcnt; t += 256) {
      float v = tv[t];
      if (v > best) { best = v; bp = t; }
    }
    for (int o = 32; o; o >>= 1) {
      float ob = __shfl_xor(best, o); int obp = __shfl_xor(bp, o);
      if (ob > best) { best = ob; bp = obp; }
    }
    if ((tid & 63) == 0) { wv[tid>>6] = best; wp[tid>>6] = bp; }
    __syncthreads();
    if (tid == 0) {
      float bb = wv[0]; int pp = wp[0];
      for (int w2 = 1; w2 < 4; ++w2) if (wv[w2] > bb) { bb = wv[w2]; pp = wp[w2]; }
      if (pp >= 0) { selv[above + rd] = bb; seli[above + rd] = ti[pp]; tv[pp] = -__builtin_inff(); }
    }
    __syncthreads();
  }

  if (tid == 0) {
    float m = selv[0];
    for (int i = 1; i < 96; ++i) m = fmaxf(m, selv[i]);
    smax_s = m;
  }
  __syncthreads();
  if (tid < 96) selv[tid] = expf(selv[tid] - smax_s);
  __syncthreads();
  if (tid == 0) {
    float s = 0.f;
    for (int i = 0; i < 96; ++i) s += selv[i];
    ssum_s = s;
  }
  __syncthreads();
  if (tid < 96) {
    int gr = r0 + row;
    int gi = seli[tid];
    probs[(size_t)gr*96 + tid] = selv[tid]/ssum_s;
    tidxg[(size_t)gr*96 + tid] = gi;
    ygath[(size_t)gr*96 + tid] = cand_y[gi];
  }
}

// ---------------- context accumulation ----------------
__global__ void __launch_bounds__(128) k_ctx(
    const float* __restrict__ probs, const float* __restrict__ ygath,
    const float* __restrict__ t2, const float* __restrict__ x2b,
    const float* __restrict__ w_le, const float* __restrict__ b_le,
    float* __restrict__ xfinal)
{
  int bb = blockIdx.x;
  int d = threadIdx.x;
  float wle = w_le[d], ble = b_le[d];
  float acc = 0.f;
  for (int c = 0; c < 96; ++c) {
    float p = probs[(size_t)bb*96 + c];
    float y = ygath[(size_t)bb*96 + c];
    acc += p*(y*wle + ble + t2[(size_t)(bb*96 + c)*128 + d]);
  }
  xfinal[(size_t)bb*128 + d] = x2b[(size_t)bb*128 + d] + acc;
}

// ---------------- head ----------------
__global__ void __launch_bounds__(256) k_head(
    const float* __restrict__ x, const float* __restrict__ g, const float* __restrict__ b,
    const float* __restrict__ Wh, const float* __restrict__ bh,
    float* __restrict__ out, int M)
{
  const int lane = threadIdx.x & 63, w = threadIdx.x >> 6;
  int rb = blockIdx.x*32 + w*8;
  for (int it = 0; it < 8; ++it) {
    int r = rb + it;
    if (r >= M) return;
    float a = x[(size_t)r*128 + lane];
    float c = x[(size_t)r*128 + 64 + lane];
    float s = a + c;
    for (int o = 32; o; o >>= 1) s += __shfl_xor(s, o);
    float mu = s*(1.f/128.f);
    float da = a - mu, dc = c - mu;
    float v = da*da + dc*dc;
    for (int o = 32; o; o >>= 1) v += __shfl_xor(v, o);
    float rs = rsqrtf(v*(1.f/128.f) + 1e-5f);
    float l0 = fmaxf(da*rs*g[lane]    + b[lane],    0.f);
    float l1 = fmaxf(dc*rs*g[lane+64] + b[lane+64], 0.f);
    float p0 = l0*Wh[lane]     + l1*Wh[64+lane];
    float p1 = l0*Wh[128+lane] + l1*Wh[192+lane];
    for (int o = 32; o; o >>= 1) { p0 += __shfl_xor(p0, o); p1 += __shfl_xor(p1, o); }
    if (lane == 0) { out[r*2 + 0] = p0 + bh[0]; out[r*2 + 1] = p1 + bh[1]; }
  }
}

// ---------------- launcher ----------------
extern "C" void kernel_launch(void* const* d_in, const int* in_sizes, int n_in,
                              void* d_out, int out_size, void* d_ws, size_t ws_size,
                              hipStream_t stream) {
  const float* x_num   = (const float*)d_in[0];
  const float* cand_x  = (const float*)d_in[1];
  const float* cand_y  = (const float*)d_in[2];
  const float* W_in    = (const float*)d_in[3];
  const float* b_in    = (const float*)d_in[4];
  const float* enc_W1  = (const float*)d_in[5];
  const float* enc_b1  = (const float*)d_in[6];
  const float* enc_W2  = (const float*)d_in[7];
  const float* enc_b2  = (const float*)d_in[8];
  const float* mix_g   = (const float*)d_in[9];
  const float* mix_b   = (const float*)d_in[10];
  const float* W_k     = (const float*)d_in[11];
  const float* b_k     = (const float*)d_in[12];
  const float* w_le    = (const float*)d_in[13];
  const float* b_le    = (const float*)d_in[14];
  const float* W_t1    = (const float*)d_in[15];
  const float* b_t1    = (const float*)d_in[16];
  const float* W_t2    = (const float*)d_in[17];
  const float* pred_g  = (const float*)d_in[18];
  const float* pred_b  = (const float*)d_in[19];
  const float* pred_W1 = (const float*)d_in[20];
  const float* pred_b1 = (const float*)d_in[21];
  const float* pred_W2 = (const float*)d_in[22];
  const float* pred_b2 = (const float*)d_in[23];
  const float* head_g  = (const float*)d_in[24];
  const float* head_b  = (const float*)d_in[25];
  const float* W_head  = (const float*)d_in[26];
  const float* b_head  = (const float*)d_in[27];

  float* ws  = (float*)d_ws;
  float* out = (float*)d_out;

  float*          wt     = ws;
  unsigned short* Wh     = (unsigned short*)ws;        // 155648 shorts
  unsigned short* Wl     = Wh + 155648;                // ends at float 155648
  unsigned short* ckh    = (unsigned short*)(ws + OFF_CKH);
  unsigned short* ckl    = (unsigned short*)(ws + OFF_CKL);
  float*          candn  = ws + OFF_CANDN;
  float*          kb     = ws + OFF_KB;
  float*          x2b    = ws + OFF_X2B;
  float*          lnb    = ws + OFF_LNB;
  float*          hb     = ws + OFF_HB;
  float*          xpred  = ws + OFF_XPRED;
  float*          xfin   = ws + OFF_XFIN;
  unsigned short* kbAh   = (unsigned short*)(ws + OFF_KBA);
  unsigned short* kbAl   = kbAh + 131072;
  float*          probs  = ws + OFF_PROBS;
  int*            tidxg  = (int*)(ws + OFF_TIDX);
  float*          ygath  = ws + OFF_YG;
  float*          simsbuf = ws + OFF_SX;   // sims (sims phase) / t2 (t-net phase)
  float*          t2buf  = ws + OFF_SX;
  float*          ev     = ws + OFF_EV;
  int*            ei     = (int*)(ws + OFF_EI);
  unsigned*       gcnt   = (unsigned*)(ws + OFF_GCNT);
  float*          gthr   = ws + OFF_GTHR;

  // 1) weight prep
  k_cvt_w<<<96, 256, 0, stream>>>(W_in, enc_W1, enc_W2, W_k, W_t1, W_t2, Wh, Wl);
  k_transpose<<<64, 256, 0, stream>>>(pred_W1, pred_W2, wt);
  k_pad_ck<<<16, 256, 0, stream>>>(ckh, ckl);

  // 2) batch encoder (fused) -> x2b, kb; then kb -> A-frags
  k_enc_fused<true><<<BATCH/64, 256, 0, stream>>>(
      x_num, Wh, Wl, b_in, enc_b1, enc_b2, mix_g, mix_b, b_k,
      nullptr, nullptr, nullptr, x2b, kb, BATCH);
  k_cvt_kbA<<<512, 256, 0, stream>>>(kb, kbAh, kbAl);

  // 3) candidate encoder (fused) -> ckh/ckl, candn
  k_enc_fused<false><<<(NCAND+63)/64, 256, 0, stream>>>(
      cand_x, Wh, Wl, b_in, enc_b1, enc_b2, mix_g, mix_b, b_k,
      ckh, ckl, candn, nullptr, nullptr, NCAND);

  // 4) sims (MFMA) + exact top-96, 8 row chunks of 128
  for (int ch = 0; ch < 8; ++ch) {
    k_sims_mfma<<<NCPAD/64, 256, 0, stream>>>(kbAh, kbAl, ckh, ckl, candn, simsbuf, ch);
    k_sample<<<RCH, 256, 0, stream>>>(simsbuf, gthr, gcnt);
    k_emit<<<dim3(8, RCH), 256, 0, stream>>>(simsbuf, gthr, gcnt, ev, ei);
    k_final<<<RCH, 256, 0, stream>>>(ev, ei, gcnt, cand_y, probs, tidxg, ygath, ch*RCH);
  }

  // 5) t-net (fused MFMA, one launch) + context
  k_tnet<<<NPAIR/64, 256, 0, stream>>>(kb, ckh, ckl, tidxg, Wh, Wl, b_t1, t2buf);
  k_ctx<<<BATCH, 128, 0, stream>>>(probs, ygath, t2buf, x2b, w_le, b_le, xfin);

  // 6) predictor block + head
  k_ln<<<(BATCH+31)/32, 256, 0, stream>>>(xfin, pred_g, pred_b, lnb, BATCH);
  k_gemm<256,true ,false><<<16, 256, 0, stream>>>(lnb, wt+WT_P1, pred_b1, nullptr, hb,    BATCH, 128);
  k_gemm<128,false,true ><<<16, 256, 0, stream>>>(hb,  wt+WT_P2, pred_b2, xfin,    xpred, BATCH, 256);
  k_head<<<(BATCH+31)/32, 256, 0, stream>>>(xpred, head_g, head_b, W_head, b_head, out, BATCH);
}